// Round 14
// baseline (286.671 us; speedup 1.0000x reference)
//
#include <hip/hip_runtime.h>
#include <hip/hip_bf16.h>
#include <stdint.h>

// Problem constants
constexpr int Bb  = 16;
constexpr int Ll  = 100;
constexpr int DIN = 6144;
constexpr int Hh  = 1024;
constexpr int DI  = 2048;
constexpr int Nst = 16;
constexpr int DTR = 64;
constexpr int Kc  = 4;
constexpr int NC  = 16;
constexpr int M   = Bb * Ll;   // 1600 tokens
constexpr int NCH = 4;         // scan L-chunks
constexpr int CL  = Ll / NCH;  // 25

typedef __attribute__((ext_vector_type(8))) short short8;
typedef __attribute__((ext_vector_type(4))) float floatx4;

__device__ __forceinline__ float bf2f(unsigned short u) {
    union { uint32_t b; float f; } x; x.b = ((uint32_t)u) << 16; return x.f;
}
__device__ __forceinline__ unsigned short f2bf(float f) {
    union { float f; uint32_t b; } x; x.f = f;
    uint32_t r = x.b + 0x7FFF + ((x.b >> 16) & 1);   // RNE
    return (unsigned short)(r >> 16);
}
__device__ __forceinline__ float fast_silu(float x) {
    return x / (1.f + __expf(-x));
}

// ---------------------------------------------------------------------------
// Fused prologue: one kernel, sectioned grid.
// ---------------------------------------------------------------------------
__global__ __launch_bounds__(256) void prep_kernel(
    const float* __restrict__ x, unsigned short* __restrict__ x_bf,
    const float* __restrict__ W_in, unsigned short* __restrict__ Wt_in,
    const float* __restrict__ W_ip, unsigned short* __restrict__ Wt_ip,
    const float* __restrict__ W_op, unsigned short* __restrict__ Wt_op,
    const float* __restrict__ xpw,  unsigned short* __restrict__ xpw_t,
    const float* __restrict__ dtw,  unsigned short* __restrict__ dtw_t)
{
    __shared__ float t[32][33];
    int b = blockIdx.x;

    if (b < 9600) {                       // convert x
        int i = (b * 256 + threadIdx.x) * 4;
        float4 v = *(const float4*)&x[i];
        x_bf[i + 0] = f2bf(v.x);
        x_bf[i + 1] = f2bf(v.y);
        x_bf[i + 2] = f2bf(v.z);
        x_bf[i + 3] = f2bf(v.w);
        return;
    }
    const float* in; unsigned short* out; int K, N, bid;
    if      (b < 15744) { in = W_in; out = Wt_in; K = DIN; N = Hh;     bid = b - 9600;  }
    else if (b < 19840) { in = W_ip; out = Wt_ip; K = Hh;  N = 2 * DI; bid = b - 15744; }
    else if (b < 21888) { in = W_op; out = Wt_op; K = DI;  N = Hh;     bid = b - 19840; }
    else if (b < 22080) { in = xpw;  out = xpw_t; K = DI;  N = 96;     bid = b - 21888; }
    else                { in = dtw;  out = dtw_t; K = DTR; N = DI;     bid = b - 22080; }

    int kx = bid % (K / 32), ny = bid / (K / 32);
    int k0 = kx * 32, n0 = ny * 32;
    int tx = threadIdx.x & 31, ty = threadIdx.x >> 5;
    #pragma unroll
    for (int i = 0; i < 4; i++)
        t[ty + i * 8][tx] = in[(size_t)(k0 + ty + i * 8) * N + n0 + tx];
    __syncthreads();
    #pragma unroll
    for (int i = 0; i < 4; i++)
        out[(size_t)(n0 + ty + i * 8) * K + k0 + tx] = f2bf(t[tx][ty + i * 8]);
}

// ---------------------------------------------------------------------------
// Deep-pipelined bf16 MFMA GEMM (big GEMMs 1/2/7): BM=256, BN=128, BK=64;
// 512 thr = 8 waves (4m x 2n), wave tile 64x64. 3-buffer LDS ring (144 KB),
// 2-deep counted-vmcnt prefetch, swizzled staging, LDS-staged coalesced
// epilogue, early buffer release. R14: intra-step lgkm split — kk=0's 8
// ds_reads pinned first (sched_barrier), lgkmcnt(8) -> MFMA(kk=0) overlaps
// kk=1's in-flight reads; lgkmcnt(0) + release barrier -> MFMA(kk=1).
// ---------------------------------------------------------------------------
template<bool SPLIT, bool BIAS, bool W16>
__global__ __launch_bounds__(512) void gemm_deep(
    const unsigned short* __restrict__ A, int lda,    // [Md x lda]
    const unsigned short* __restrict__ Bt, int ldb,   // [Nd x ldb]
    const float* __restrict__ bias,                   // [Nd]
    unsigned short* __restrict__ C16,                 // final bf16 out
    unsigned short* __restrict__ Cpart,               // bf16 partials
    int Md, int Nd, int Kslab)
{
    __shared__ short As[3 * 256 * 64];   // 96 KB
    __shared__ short Bs[3 * 128 * 64];   // 48 KB

    // XCD-aware block remap
    const int nx = gridDim.x, ny = gridDim.y, nz = gridDim.z;
    const int nb = nx * ny * nz;
    int id = blockIdx.x + nx * (blockIdx.y + ny * blockIdx.z);
    int bx, by, bz;
    if ((nb & 7) == 0) {
        int swz = (id & 7) * (nb >> 3) + (id >> 3);
        bx = swz % nx;
        int rem = swz / nx;
        by = rem % ny;
        bz = rem / ny;
    } else {
        bx = blockIdx.x; by = blockIdx.y; bz = blockIdx.z;
    }

    const int tid  = threadIdx.x;
    const int lane = tid & 63;
    const int wid  = tid >> 6;      // 0..7
    const int wr   = wid >> 1;      // 0..3 (m)
    const int wc   = wid & 1;       // 0..1 (n)
    const int l15  = lane & 15;
    const int kg   = lane >> 4;
    const int gsw  = l15 & 7;       // ds_read swizzle term
    const int m0   = bx * 256;
    const int n0   = by * 128;
    const int kbeg = SPLIT ? bz * Kslab : 0;

    floatx4 acc[4][4];
    #pragma unroll
    for (int m = 0; m < 4; m++)
        #pragma unroll
        for (int n = 0; n < 4; n++)
            acc[m][n] = (floatx4){0.f, 0.f, 0.f, 0.f};

    auto stage = [&](int buf, int k0) {
        // A: 2048 cells (256 rows x 8 g-chunks of 16B), swizzled source
        #pragma unroll
        for (int j = 0; j < 4; j++) {
            int c = j * 512 + tid;
            int row = c >> 3, gl = c & 7;
            int gg = gl ^ (row & 7);
            int grow = m0 + row; grow = grow < Md ? grow : Md - 1;
            const __attribute__((address_space(1))) short* src =
                (const __attribute__((address_space(1))) short*)(A + (size_t)grow * lda + k0 + gg * 8);
            __builtin_amdgcn_global_load_lds(
                (const __attribute__((address_space(1))) void*)src,
                (__attribute__((address_space(3))) void*)&As[(buf * 2048 + c) * 8], 16, 0, 0);
        }
        // B: 1024 cells (128 rows x 8 g-chunks)
        #pragma unroll
        for (int j = 0; j < 2; j++) {
            int c = j * 512 + tid;
            int row = c >> 3, gl = c & 7;
            int gg = gl ^ (row & 7);
            int brow = n0 + row; brow = brow < Nd ? brow : Nd - 1;
            const __attribute__((address_space(1))) short* src =
                (const __attribute__((address_space(1))) short*)(Bt + (size_t)brow * ldb + k0 + gg * 8);
            __builtin_amdgcn_global_load_lds(
                (const __attribute__((address_space(1))) void*)src,
                (__attribute__((address_space(3))) void*)&Bs[(buf * 1024 + c) * 8], 16, 0, 0);
        }
    };

    const int nt = Kslab >> 6;
    stage(0, kbeg);
    stage(1, kbeg + 64);

    for (int t = 0; t < nt; t++) {
        const int cur = t % 3;
        if (t + 2 < nt) {
            stage((t + 2) % 3, kbeg + (t + 2) * 64);
            asm volatile("s_waitcnt vmcnt(12)" ::: "memory");  // tile t landed
        } else if (t + 1 < nt) {
            asm volatile("s_waitcnt vmcnt(6)" ::: "memory");
        } else {
            asm volatile("s_waitcnt vmcnt(0)" ::: "memory");
        }
        __builtin_amdgcn_s_barrier();       // tile t staged (all waves)
        __builtin_amdgcn_sched_barrier(0);

        short8 a[2][4], bfr[2][4];
        // kk=0 reads first (order pinned for lgkmcnt(8))
        #pragma unroll
        for (int m = 0; m < 4; m++) {
            int row = wr * 64 + m * 16 + l15;
            int gs  = kg ^ gsw;
            a[0][m] = *(const short8*)&As[(cur * 2048 + row * 8 + gs) * 8];
        }
        #pragma unroll
        for (int n = 0; n < 4; n++) {
            int row = wc * 64 + n * 16 + l15;
            int gs  = kg ^ gsw;
            bfr[0][n] = *(const short8*)&Bs[(cur * 1024 + row * 8 + gs) * 8];
        }
        __builtin_amdgcn_sched_barrier(0);
        // kk=1 reads
        #pragma unroll
        for (int m = 0; m < 4; m++) {
            int row = wr * 64 + m * 16 + l15;
            int gs  = (4 + kg) ^ gsw;
            a[1][m] = *(const short8*)&As[(cur * 2048 + row * 8 + gs) * 8];
        }
        #pragma unroll
        for (int n = 0; n < 4; n++) {
            int row = wc * 64 + n * 16 + l15;
            int gs  = (4 + kg) ^ gsw;
            bfr[1][n] = *(const short8*)&Bs[(cur * 1024 + row * 8 + gs) * 8];
        }
        __builtin_amdgcn_sched_barrier(0);
        asm volatile("s_waitcnt lgkmcnt(8)" ::: "memory");   // kk=0 in regs
        __builtin_amdgcn_sched_barrier(0);

        __builtin_amdgcn_s_setprio(1);
        #pragma unroll
        for (int m = 0; m < 4; m++)
            #pragma unroll
            for (int n = 0; n < 4; n++)
                acc[m][n] = __builtin_amdgcn_mfma_f32_16x16x32_bf16(a[0][m], bfr[0][n], acc[m][n], 0, 0, 0);
        __builtin_amdgcn_s_setprio(0);
        __builtin_amdgcn_sched_barrier(0);
        asm volatile("s_waitcnt lgkmcnt(0)" ::: "memory");   // all reads in regs
        __builtin_amdgcn_sched_barrier(0);
        __builtin_amdgcn_s_barrier();       // buffer cur free for stage(t+3)
        __builtin_amdgcn_sched_barrier(0);

        __builtin_amdgcn_s_setprio(1);
        #pragma unroll
        for (int m = 0; m < 4; m++)
            #pragma unroll
            for (int n = 0; n < 4; n++)
                acc[m][n] = __builtin_amdgcn_mfma_f32_16x16x32_bf16(a[1][m], bfr[1][n], acc[m][n], 0, 0, 0);
        __builtin_amdgcn_s_setprio(0);
    }

    // ---- LDS-staged coalesced epilogue ----
    unsigned short* Cs = (unsigned short*)As;   // [256][136] bf16 = 69.6 KB
    #pragma unroll
    for (int n = 0; n < 4; n++) {
        int col = wc * 64 + n * 16 + l15;
        float bv = BIAS ? bias[n0 + col] : 0.f;
        #pragma unroll
        for (int m = 0; m < 4; m++) {
            #pragma unroll
            for (int q = 0; q < 4; q++) {
                int row = wr * 64 + m * 16 + kg * 4 + q;
                Cs[row * 136 + col] = f2bf(acc[m][n][q] + bv);
            }
        }
    }
    __syncthreads();
    #pragma unroll
    for (int j = 0; j < 8; j++) {
        int c = j * 512 + tid;          // 16B cell; 16 cells/row
        int row = c >> 4, cc = c & 15;
        int grow = m0 + row;
        if (grow >= Md) continue;
        short8 v = *(const short8*)&Cs[row * 136 + cc * 8];
        if (SPLIT)
            *(short8*)&Cpart[(size_t)bz * Md * Nd + (size_t)grow * Nd + n0 + cc * 8] = v;
        else if (W16)
            *(short8*)&C16[(size_t)grow * Nd + n0 + cc * 8] = v;
    }
}

// ---------------------------------------------------------------------------
// Swizzled 128x128 BK=64 dbuf MFMA GEMM — small GEMMs (proj, delta).
// ---------------------------------------------------------------------------
template<bool SPLIT, bool PARTBF, bool BIAS, int ACT, bool W32, bool W16>
__global__ __launch_bounds__(256) void gemm_mfma(
    const unsigned short* __restrict__ A, int lda,
    const unsigned short* __restrict__ Bt, int ldb,
    const float* __restrict__ bias,
    float* __restrict__ C32,
    unsigned short* __restrict__ C16,
    void* __restrict__ Cpart,
    int Md, int Nd, int Kslab)
{
    __shared__ short As[2][128 * 64];
    __shared__ short Bs[2][128 * 64];

    const int nx = gridDim.x, ny = gridDim.y, nz = gridDim.z;
    const int nb = nx * ny * nz;
    int id = blockIdx.x + nx * (blockIdx.y + ny * blockIdx.z);
    int bx, by, bz;
    if ((nb & 7) == 0) {
        int swz = (id & 7) * (nb >> 3) + (id >> 3);
        bx = swz % nx;
        int rem = swz / nx;
        by = rem % ny;
        bz = rem / ny;
    } else {
        bx = blockIdx.x; by = blockIdx.y; bz = blockIdx.z;
    }

    const int tid  = threadIdx.x;
    const int lane = tid & 63;
    const int wid  = tid >> 6;
    const int wr   = wid >> 1;
    const int wc   = wid & 1;
    const int l15  = lane & 15;
    const int kg   = lane >> 4;
    const int gsw  = l15 & 7;
    const int m0   = bx * 128;
    const int n0   = by * 128;
    const int kbeg = SPLIT ? bz * Kslab : 0;

    floatx4 acc[4][4];
    #pragma unroll
    for (int m = 0; m < 4; m++)
        #pragma unroll
        for (int n = 0; n < 4; n++)
            acc[m][n] = (floatx4){0.f, 0.f, 0.f, 0.f};

    auto stage = [&](int buf, int k0) {
        #pragma unroll
        for (int j = 0; j < 4; j++) {
            int c = j * 256 + tid;
            int row = c >> 3, gl = c & 7;
            int gg = gl ^ (row & 7);
            int grow = m0 + row; grow = grow < Md ? grow : Md - 1;
            const __attribute__((address_space(1))) short* src =
                (const __attribute__((address_space(1))) short*)(A + (size_t)grow * lda + k0 + gg * 8);
            __builtin_amdgcn_global_load_lds(
                (const __attribute__((address_space(1))) void*)src,
                (__attribute__((address_space(3))) void*)&As[buf][c * 8], 16, 0, 0);
        }
        #pragma unroll
        for (int j = 0; j < 4; j++) {
            int c = j * 256 + tid;
            int row = c >> 3, gl = c & 7;
            int gg = gl ^ (row & 7);
            int brow = n0 + row; brow = brow < Nd ? brow : Nd - 1;
            const __attribute__((address_space(1))) short* src =
                (const __attribute__((address_space(1))) short*)(Bt + (size_t)brow * ldb + k0 + gg * 8);
            __builtin_amdgcn_global_load_lds(
                (const __attribute__((address_space(1))) void*)src,
                (__attribute__((address_space(3))) void*)&Bs[buf][c * 8], 16, 0, 0);
        }
    };

    stage(0, kbeg);
    asm volatile("s_waitcnt vmcnt(0)" ::: "memory");
    __builtin_amdgcn_s_barrier();
    __builtin_amdgcn_sched_barrier(0);

    const int nt = Kslab >> 6;
    for (int t = 0; t < nt; t++) {
        const int cur = t & 1;
        if (t + 1 < nt) {
            stage(cur ^ 1, kbeg + (t + 1) * 64);
            asm volatile("s_waitcnt vmcnt(8)" ::: "memory");
        } else {
            asm volatile("s_waitcnt vmcnt(0)" ::: "memory");
        }
        __builtin_amdgcn_s_barrier();
        __builtin_amdgcn_sched_barrier(0);

        short8 a[2][4], bfr[2][4];
        #pragma unroll
        for (int kk = 0; kk < 2; kk++) {
            #pragma unroll
            for (int m = 0; m < 4; m++) {
                int row = wr * 64 + m * 16 + l15;
                int gs  = (kk * 4 + kg) ^ gsw;
                a[kk][m] = *(const short8*)&As[cur][(row * 8 + gs) * 8];
            }
            #pragma unroll
            for (int n = 0; n < 4; n++) {
                int row = wc * 64 + n * 16 + l15;
                int gs  = (kk * 4 + kg) ^ gsw;
                bfr[kk][n] = *(const short8*)&Bs[cur][(row * 8 + gs) * 8];
            }
        }
        __builtin_amdgcn_s_setprio(1);
        #pragma unroll
        for (int kk = 0; kk < 2; kk++)
            #pragma unroll
            for (int m = 0; m < 4; m++)
                #pragma unroll
                for (int n = 0; n < 4; n++)
                    acc[m][n] = __builtin_amdgcn_mfma_f32_16x16x32_bf16(a[kk][m], bfr[kk][n], acc[m][n], 0, 0, 0);
        __builtin_amdgcn_s_setprio(0);
        __builtin_amdgcn_sched_barrier(0);
        __builtin_amdgcn_s_barrier();
    }

    if (SPLIT) {
        #pragma unroll
        for (int n = 0; n < 4; n++) {
            int col = n0 + wc * 64 + n * 16 + l15;
            if (col >= Nd) continue;
            #pragma unroll
            for (int m = 0; m < 4; m++)
                #pragma unroll
                for (int q = 0; q < 4; q++) {
                    int row = m0 + wr * 64 + m * 16 + kg * 4 + q;
                    if (row >= Md) continue;
                    size_t ix = (size_t)bz * Md * Nd + (size_t)row * Nd + col;
                    if (PARTBF) ((unsigned short*)Cpart)[ix] = f2bf(acc[m][n][q]);
                    else        ((float*)Cpart)[ix] = acc[m][n][q];
                }
        }
    } else {
        #pragma unroll
        for (int n = 0; n < 4; n++) {
            int col = n0 + wc * 64 + n * 16 + l15;
            if (col >= Nd) continue;
            float bv = BIAS ? bias[col] : 0.f;
            #pragma unroll
            for (int m = 0; m < 4; m++)
                #pragma unroll
                for (int q = 0; q < 4; q++) {
                    int row = m0 + wr * 64 + m * 16 + kg * 4 + q;
                    if (row >= Md) continue;
                    float v = acc[m][n][q] + bv;
                    if (ACT == 1) v = fmaxf(v, 0.f) + log1pf(expf(-fabsf(v)));  // softplus
                    if (W32) C32[(size_t)row * Nd + col] = v;
                    if (W16) C16[(size_t)row * Nd + col] = f2bf(v);
                }
        }
    }
}

// ---------------------------------------------------------------------------
// Sum S fp32 split-K partials + bias/act -> fp32/bf16. total % 1024 == 0.
// ---------------------------------------------------------------------------
template<int S, bool BIAS, int ACT, bool W32, bool W16>
__global__ __launch_bounds__(256) void reduce_split(
    const float* __restrict__ P, const float* __restrict__ bias,
    float* __restrict__ C32, unsigned short* __restrict__ C16,
    int total, int nmask)
{
    int i = (blockIdx.x * 256 + threadIdx.x) * 4;
    float4 v = *(const float4*)&P[i];
    #pragma unroll
    for (int s = 1; s < S; s++) {
        float4 p = *(const float4*)&P[(size_t)s * total + i];
        v.x += p.x; v.y += p.y; v.z += p.z; v.w += p.w;
    }
    float r[4] = {v.x, v.y, v.z, v.w};
    #pragma unroll
    for (int j = 0; j < 4; j++) {
        float t = r[j];
        if (BIAS) t += bias[(i + j) & nmask];
        if (ACT == 1) t = fmaxf(t, 0.f) + log1pf(expf(-fabsf(t)));
        if (W32) C32[i + j] = t;
        if (W16) C16[i + j] = f2bf(t);
    }
}

// ---------------------------------------------------------------------------
// Sum S bf16 split-K partials + bias -> bf16. total % 2048 == 0.
// ---------------------------------------------------------------------------
template<int S, bool BIAS>
__global__ __launch_bounds__(256) void reduce_split_bf(
    const unsigned short* __restrict__ P, const float* __restrict__ bias,
    unsigned short* __restrict__ C16, int total, int nmask)
{
    int i = (blockIdx.x * 256 + threadIdx.x) * 8;
    float r[8] = {};
    #pragma unroll
    for (int s = 0; s < S; s++) {
        short8 p = *(const short8*)&P[(size_t)s * total + i];
        #pragma unroll
        for (int j = 0; j < 8; j++) r[j] += bf2f((unsigned short)p[j]);
    }
    short8 o;
    #pragma unroll
    for (int j = 0; j < 8; j++) {
        float t = r[j];
        if (BIAS) t += bias[(i + j) & nmask];
        o[j] = (short)f2bf(t);
    }
    *(short8*)&C16[i] = o;
}

// ---------------------------------------------------------------------------
// Causal depthwise conv (K=4) + bias + SiLU; xz is bf16 with row stride 2*DI.
// ---------------------------------------------------------------------------
__global__ __launch_bounds__(256) void conv_silu_kernel(
    const unsigned short* __restrict__ xz, const float* __restrict__ conv_w,
    const float* __restrict__ conv_b, float* __restrict__ xc,
    unsigned short* __restrict__ xc_bf)
{
    int idx = blockIdx.x * 256 + threadIdx.x;
    if (idx >= Bb * Ll * DI) return;
    int d  = idx & (DI - 1);
    int bl = idx >> 11;
    int l  = bl % Ll;

    float acc = conv_b[d];
    #pragma unroll
    for (int k = 0; k < Kc; k++) {
        int ls = l + k - (Kc - 1);
        if (ls >= 0)
            acc = fmaf(conv_w[d * Kc + k], bf2f(xz[(size_t)(bl + ls - l) * (2 * DI) + d]), acc);
    }
    float s = fast_silu(acc);
    xc[idx] = s;
    xc_bf[idx] = f2bf(s);
}

// ---------------------------------------------------------------------------
// Chunked selective scan, 2-pass. R14: part1's chunk 0 (z==0) also emits y
// (its local scan from h=0 IS the full chunk-0 recurrence); part2 covers
// chunks 1..3 only (c = blockIdx.z + 1). 7 -> 6 chunk-scans.
// ---------------------------------------------------------------------------
__global__ __launch_bounds__(256) void scan_part1(
    const float* __restrict__ delta, const float* __restrict__ xc,
    const unsigned short* __restrict__ xz, const float* __restrict__ proj,
    const float* __restrict__ A_log, const float* __restrict__ Dv,
    float* __restrict__ Pbuf, float* __restrict__ Sbuf,
    unsigned short* __restrict__ y)
{
    const int t    = threadIdx.x;
    const int nq   = t & 3;
    const int dloc = t >> 2;
    const int d    = blockIdx.x * 64 + dloc;
    const int b    = blockIdx.y;
    const int c    = blockIdx.z;          // chunk 0..2
    const bool emit = (c == 0);

    float4 Alq = *(const float4*)&A_log[(size_t)d * Nst + nq * 4];
    float Ar0 = -expf(Alq.x), Ar1 = -expf(Alq.y), Ar2 = -expf(Alq.z), Ar3 = -expf(Alq.w);
    const float Dd = Dv[d];

    float h0 = 0.f, h1 = 0.f, h2 = 0.f, h3 = 0.f;
    float sdl = 0.f;

    for (int l = c * CL; l < (c + 1) * CL; l++) {
        size_t bl = (size_t)b * Ll + l;
        float dl  = delta[bl * DI + d];
        float xcv = xc[bl * DI + d];
        float dx  = dl * xcv;
        const float* p = proj + bl * (DTR + 2 * Nst);
        float4 Bv = *(const float4*)&p[DTR + nq * 4];

        h0 = fmaf(__expf(dl * Ar0), h0, dx * Bv.x);
        h1 = fmaf(__expf(dl * Ar1), h1, dx * Bv.y);
        h2 = fmaf(__expf(dl * Ar2), h2, dx * Bv.z);
        h3 = fmaf(__expf(dl * Ar3), h3, dx * Bv.w);
        sdl += dl;

        if (emit) {
            float4 Cv = *(const float4*)&p[DTR + Nst + nq * 4];
            float yac = h0 * Cv.x + h1 * Cv.y + h2 * Cv.z + h3 * Cv.w;
            yac += __shfl_xor(yac, 1);
            yac += __shfl_xor(yac, 2);
            if (nq == 0) {
                float zv = bf2f(xz[bl * (2 * DI) + DI + d]);
                float yv = yac + Dd * xcv;
                yv *= fast_silu(zv);
                y[bl * DI + d] = f2bf(yv);
            }
        }
    }

    size_t o = (((size_t)c * Bb + b) * DI + d) * Nst + nq * 4;
    *(float4*)&Pbuf[o] = (float4){__expf(sdl * Ar0), __expf(sdl * Ar1),
                                  __expf(sdl * Ar2), __expf(sdl * Ar3)};
    *(float4*)&Sbuf[o] = (float4){h0, h1, h2, h3};
}

__global__ __launch_bounds__(256) void scan_part2(
    const float* __restrict__ delta, const float* __restrict__ xc,
    const unsigned short* __restrict__ xz, const float* __restrict__ proj,
    const float* __restrict__ A_log, const float* __restrict__ Dv,
    const float* __restrict__ Pbuf, const float* __restrict__ Sbuf,
    unsigned short* __restrict__ y)
{
    const int t    = threadIdx.x;
    const int nq   = t & 3;
    const int dloc = t >> 2;
    const int d    = blockIdx.x * 64 + dloc;
    const int b    = blockIdx.y;
    const int c    = blockIdx.z + 1;      // chunk 1..3

    float4 Alq = *(const float4*)&A_log[(size_t)d * Nst + nq * 4];
    float Ar0 = -expf(Alq.x), Ar1 = -expf(Alq.y), Ar2 = -expf(Alq.z), Ar3 = -expf(Alq.w);
    const float Dd = Dv[d];

    float h0 = 0.f, h1 = 0.f, h2 = 0.f, h3 = 0.f;
    for (int cc = 0; cc < c; cc++) {
        size_t o = (((size_t)cc * Bb + b) * DI + d) * Nst + nq * 4;
        float4 Pv = *(const float4*)&Pbuf[o];
        float4 Sv = *(const float4*)&Sbuf[o];
        h0 = fmaf(Pv.x, h0, Sv.x);
        h1 = fmaf(Pv.y, h1, Sv.y);
        h2 = fmaf(Pv.z, h2, Sv.z);
        h3 = fmaf(Pv.w, h3, Sv.w);
    }

    for (int l = c * CL; l < (c + 1) * CL; l++) {
        size_t bl = (size_t)b * Ll + l;
        float dl  = delta[bl * DI + d];
        float xcv = xc[bl * DI + d];
        float zv  = bf2f(xz[bl * (2 * DI) + DI + d]);
        float dx  = dl * xcv;
        const float* p = proj + bl * (DTR + 2 * Nst);
        float4 Bv = *(const float4*)&p[DTR + nq * 4];
        float4 Cv = *(const float4*)&p[DTR + Nst + nq * 4];

        h0 = fmaf(__expf(dl * Ar0), h0, dx * Bv.x);
        h1 = fmaf(__expf(dl * Ar1), h1, dx * Bv.y);
        h2 = fmaf(__expf(dl * Ar2), h2, dx * Bv.z);
        h3 = fmaf(__expf(dl * Ar3), h3, dx * Bv.w);

        float yac = h0 * Cv.x + h1 * Cv.y + h2 * Cv.z + h3 * Cv.w;
        yac += __shfl_xor(yac, 1);
        yac += __shfl_xor(yac, 2);

        if (nq == 0) {
            float yv = yac + Dd * xcv;
            yv *= fast_silu(zv);
            y[bl * DI + d] = f2bf(yv);
        }
    }
}

// ---------------------------------------------------------------------------
// logits[M,16] = (sum_z P_z)[M,1024] @ W_out + b_out, with the partial-sum
// distributed over the k-loop: logits = sum_z (P_z @ W_out). Kills the
// reduce_split_bf launch + out_bf round-trip.
// ---------------------------------------------------------------------------
__global__ __launch_bounds__(256) void gemm_n16(
    const unsigned short* __restrict__ P,   // [4][M][Kd] bf16 partials
    const float* __restrict__ W,
    const float* __restrict__ bias, float* __restrict__ C, int Kd, int total)
{
    int m  = blockIdx.x;
    int t  = threadIdx.x;
    int c  = t & 15;
    int kg = t >> 4;

    float acc = 0.f;
    #pragma unroll
    for (int s = 0; s < 4; s++) {
        const unsigned short* a = P + (size_t)s * total + (size_t)m * Kd;
        for (int k = kg; k < Kd; k += 16)
            acc = fmaf(bf2f(a[k]), W[k * NC + c], acc);
    }

    __shared__ float red[256];
    red[t] = acc;
    __syncthreads();
    #pragma unroll
    for (int s = 128; s >= 16; s >>= 1) {
        if (t < s) red[t] += red[t + s];
        __syncthreads();
    }
    if (t < 16) C[(size_t)m * NC + t] = red[t] + bias[t];
}

// ---------------------------------------------------------------------------
extern "C" void kernel_launch(void* const* d_in, const int* in_sizes, int n_in,
                              void* d_out, int out_size, void* d_ws, size_t ws_size,
                              hipStream_t stream) {
    const float* x         = (const float*)d_in[0];
    const float* W_in      = (const float*)d_in[1];
    const float* b_in      = (const float*)d_in[2];
    const float* in_proj_w = (const float*)d_in[3];
    const float* conv_w    = (const float*)d_in[4];
    const float* conv_b    = (const float*)d_in[5];
    const float* x_proj_w  = (const float*)d_in[6];
    const float* dt_proj_w = (const float*)d_in[7];
    const float* dt_proj_b = (const float*)d_in[8];
    const float* A_log     = (const float*)d_in[9];
    const float* Dv        = (const float*)d_in[10];
    const float* out_proj  = (const float*)d_in[11];
    const float* W_out     = (const float*)d_in[12];
    const float* b_out     = (const float*)d_in[13];
    float* logits = (float*)d_out;

    char* base = (char*)d_ws;
    size_t off = 0;
    auto alloc = [&](size_t bytes) {
        char* p = base + off;
        off += (bytes + 255) & ~(size_t)255;
        return p;
    };
    unsigned short* x_bf    = (unsigned short*)alloc((size_t)M * DIN * 2);
    unsigned short* Wt_in   = (unsigned short*)alloc((size_t)Hh * DIN * 2);
    unsigned short* Wt_ip   = (unsigned short*)alloc((size_t)(2 * DI) * Hh * 2);
    unsigned short* Wt_op   = (unsigned short*)alloc((size_t)Hh * DI * 2);
    unsigned short* xpw_t   = (unsigned short*)alloc((size_t)96 * DI * 2);
    unsigned short* dtw_t   = (unsigned short*)alloc((size_t)DI * DTR * 2);
    unsigned short* h_bf    = (unsigned short*)alloc((size_t)M * Hh * 2);
    unsigned short* xz_bf   = (unsigned short*)alloc((size_t)M * 2 * DI * 2);
    float*          xc      = (float*)alloc((size_t)M * DI * 4);       // | P14 alias (13.1MB)
    float*          delta   = (float*)alloc((size_t)M * DI * 4);       // | P8 alias
    unsigned short* xc_bf   = (unsigned short*)alloc((size_t)M * DI * 2);
    float*          proj_f  = (float*)alloc((size_t)M * 96 * 4);
    unsigned short* proj_bf = (unsigned short*)alloc((size_t)M * 96 * 2);
    unsigned short* y_bf    = (unsigned short*)alloc((size_t)M * DI * 2);

    unsigned short* P14 = (unsigned short*)xc;   // bf16 [4][1600][1024] = 13.1MB
    float*          P8  = delta;                 // fp32 [8][1600][96]  = 4.9MB
    float*          Pbuf = (float*)x_bf;         // scan chunk buffers (x_bf dead)
    float*          Sbuf = Pbuf + (size_t)(NCH - 1) * Bb * DI * Nst;

    dim3 blk(256), blk5(512);

    // 0) fused prologue: convert + 5 transposes
    prep_kernel<<<dim3(22208), blk, 0, stream>>>(
        x, x_bf, W_in, Wt_in, in_proj_w, Wt_ip, out_proj, Wt_op,
        x_proj_w, xpw_t, dt_proj_w, dtw_t);

    // 1) h = x @ W_in + b_in   [1600,6144]@[6144,1024], split-K 4 -> 224 blocks
    gemm_deep<true, false, false><<<dim3(7, Hh / 128, 4), blk5, 0, stream>>>(
        x_bf, DIN, Wt_in, DIN, nullptr, nullptr, P14, M, Hh, DIN / 4);
    reduce_split_bf<4, true><<<dim3((M * Hh) / 2048), blk, 0, stream>>>(
        P14, b_in, h_bf, M * Hh, Hh - 1);

    // 2) xz = h @ in_proj_w    [1600,1024]@[1024,4096], 224 blocks, no split
    gemm_deep<false, false, true><<<dim3(7, (2 * DI) / 128, 1), blk5, 0, stream>>>(
        h_bf, Hh, Wt_ip, Hh, nullptr, xz_bf, nullptr, M, 2 * DI, Hh);

    // 3) xc = silu(conv(xm) + conv_b)  -> fp32 + bf16
    conv_silu_kernel<<<dim3((Bb * Ll * DI) / 256), blk, 0, stream>>>(
        xz_bf, conv_w, conv_b, xc, xc_bf);

    // 4) proj = xc @ x_proj_w  [1600,2048]@[2048,96], split-K 8 -> 104 blocks
    gemm_mfma<true, false, false, 0, false, false><<<dim3(13, 1, 8), blk, 0, stream>>>(
        xc_bf, DI, xpw_t, DI, nullptr, nullptr, nullptr, P8, M, 96, DI / 8);
    reduce_split<8, false, 0, true, true><<<dim3((M * 96) / 1024), blk, 0, stream>>>(
        P8, nullptr, proj_f, proj_bf, M * 96, 0);

    // 5) delta = softplus(proj[:,:64] @ dt_proj_w + dt_proj_b)  [1600,64]@[64,2048]
    gemm_mfma<false, false, true, 1, true, false><<<dim3(13, DI / 128, 1), blk, 0, stream>>>(
        proj_bf, 96, dtw_t, DTR, dt_proj_b, delta, nullptr, nullptr, M, DI, DTR);

    // 6) chunked selective scan: part1 (chunks 0..2, chunk 0 emits y),
    //    part2 (chunks 1..3)
    scan_part1<<<dim3(DI / 64, Bb, NCH - 1), blk, 0, stream>>>(
        delta, xc, xz_bf, proj_f, A_log, Dv, Pbuf, Sbuf, y_bf);
    scan_part2<<<dim3(DI / 64, Bb, NCH - 1), blk, 0, stream>>>(
        delta, xc, xz_bf, proj_f, A_log, Dv, Pbuf, Sbuf, y_bf);

    // 7) out partials = y @ out_proj_w  [1600,2048]@[2048,1024], split-K 4
    gemm_deep<true, false, false><<<dim3(7, Hh / 128, 4), blk5, 0, stream>>>(
        y_bf, DI, Wt_op, DI, nullptr, nullptr, P14, M, Hh, DI / 4);

    // 8) logits = sum_z (P_z @ W_out) + b_out   (reduce folded into k-loop)
    gemm_n16<<<dim3(M), blk, 0, stream>>>(P14, W_out, b_out, logits, Hh, M * Hh);
}

// Round 15
// 244.983 us; speedup vs baseline: 1.1702x; 1.1702x over previous
//
#include <hip/hip_runtime.h>
#include <hip/hip_bf16.h>
#include <stdint.h>

// Problem constants
constexpr int Bb  = 16;
constexpr int Ll  = 100;
constexpr int DIN = 6144;
constexpr int Hh  = 1024;
constexpr int DI  = 2048;
constexpr int Nst = 16;
constexpr int DTR = 64;
constexpr int Kc  = 4;
constexpr int NC  = 16;
constexpr int M   = Bb * Ll;   // 1600 tokens
constexpr int NCH = 4;         // scan L-chunks
constexpr int CL  = Ll / NCH;  // 25

typedef __attribute__((ext_vector_type(8))) short short8;
typedef __attribute__((ext_vector_type(4))) float floatx4;

__device__ __forceinline__ float bf2f(unsigned short u) {
    union { uint32_t b; float f; } x; x.b = ((uint32_t)u) << 16; return x.f;
}
__device__ __forceinline__ unsigned short f2bf(float f) {
    union { float f; uint32_t b; } x; x.f = f;
    uint32_t r = x.b + 0x7FFF + ((x.b >> 16) & 1);   // RNE
    return (unsigned short)(r >> 16);
}
__device__ __forceinline__ float fast_silu(float x) {
    return x / (1.f + __expf(-x));
}

// ---------------------------------------------------------------------------
// Fused prologue: one kernel, sectioned grid.
// ---------------------------------------------------------------------------
__global__ __launch_bounds__(256) void prep_kernel(
    const float* __restrict__ x, unsigned short* __restrict__ x_bf,
    const float* __restrict__ W_in, unsigned short* __restrict__ Wt_in,
    const float* __restrict__ W_ip, unsigned short* __restrict__ Wt_ip,
    const float* __restrict__ W_op, unsigned short* __restrict__ Wt_op,
    const float* __restrict__ xpw,  unsigned short* __restrict__ xpw_t,
    const float* __restrict__ dtw,  unsigned short* __restrict__ dtw_t)
{
    __shared__ float t[32][33];
    int b = blockIdx.x;

    if (b < 9600) {                       // convert x
        int i = (b * 256 + threadIdx.x) * 4;
        float4 v = *(const float4*)&x[i];
        x_bf[i + 0] = f2bf(v.x);
        x_bf[i + 1] = f2bf(v.y);
        x_bf[i + 2] = f2bf(v.z);
        x_bf[i + 3] = f2bf(v.w);
        return;
    }
    const float* in; unsigned short* out; int K, N, bid;
    if      (b < 15744) { in = W_in; out = Wt_in; K = DIN; N = Hh;     bid = b - 9600;  }
    else if (b < 19840) { in = W_ip; out = Wt_ip; K = Hh;  N = 2 * DI; bid = b - 15744; }
    else if (b < 21888) { in = W_op; out = Wt_op; K = DI;  N = Hh;     bid = b - 19840; }
    else if (b < 22080) { in = xpw;  out = xpw_t; K = DI;  N = 96;     bid = b - 21888; }
    else                { in = dtw;  out = dtw_t; K = DTR; N = DI;     bid = b - 22080; }

    int kx = bid % (K / 32), ny = bid / (K / 32);
    int k0 = kx * 32, n0 = ny * 32;
    int tx = threadIdx.x & 31, ty = threadIdx.x >> 5;
    #pragma unroll
    for (int i = 0; i < 4; i++)
        t[ty + i * 8][tx] = in[(size_t)(k0 + ty + i * 8) * N + n0 + tx];
    __syncthreads();
    #pragma unroll
    for (int i = 0; i < 4; i++)
        out[(size_t)(n0 + ty + i * 8) * K + k0 + tx] = f2bf(t[tx][ty + i * 8]);
}

// ---------------------------------------------------------------------------
// Deep-pipelined bf16 MFMA GEMM (big GEMMs 1/2/7): BM=256, BN=128, BK=64;
// 512 thr = 8 waves (4m x 2n), wave tile 64x64. 3-buffer LDS ring (144 KB),
// 2-deep counted-vmcnt prefetch, swizzled staging, LDS-staged coalesced
// epilogue, early buffer release + intra-step lgkm split (R14).
// ---------------------------------------------------------------------------
template<bool SPLIT, bool BIAS, bool W16>
__global__ __launch_bounds__(512) void gemm_deep(
    const unsigned short* __restrict__ A, int lda,    // [Md x lda]
    const unsigned short* __restrict__ Bt, int ldb,   // [Nd x ldb]
    const float* __restrict__ bias,                   // [Nd]
    unsigned short* __restrict__ C16,                 // final bf16 out
    unsigned short* __restrict__ Cpart,               // bf16 partials
    int Md, int Nd, int Kslab)
{
    __shared__ short As[3 * 256 * 64];   // 96 KB
    __shared__ short Bs[3 * 128 * 64];   // 48 KB

    // XCD-aware block remap
    const int nx = gridDim.x, ny = gridDim.y, nz = gridDim.z;
    const int nb = nx * ny * nz;
    int id = blockIdx.x + nx * (blockIdx.y + ny * blockIdx.z);
    int bx, by, bz;
    if ((nb & 7) == 0) {
        int swz = (id & 7) * (nb >> 3) + (id >> 3);
        bx = swz % nx;
        int rem = swz / nx;
        by = rem % ny;
        bz = rem / ny;
    } else {
        bx = blockIdx.x; by = blockIdx.y; bz = blockIdx.z;
    }

    const int tid  = threadIdx.x;
    const int lane = tid & 63;
    const int wid  = tid >> 6;      // 0..7
    const int wr   = wid >> 1;      // 0..3 (m)
    const int wc   = wid & 1;       // 0..1 (n)
    const int l15  = lane & 15;
    const int kg   = lane >> 4;
    const int gsw  = l15 & 7;       // ds_read swizzle term
    const int m0   = bx * 256;
    const int n0   = by * 128;
    const int kbeg = SPLIT ? bz * Kslab : 0;

    floatx4 acc[4][4];
    #pragma unroll
    for (int m = 0; m < 4; m++)
        #pragma unroll
        for (int n = 0; n < 4; n++)
            acc[m][n] = (floatx4){0.f, 0.f, 0.f, 0.f};

    auto stage = [&](int buf, int k0) {
        // A: 2048 cells (256 rows x 8 g-chunks of 16B), swizzled source
        #pragma unroll
        for (int j = 0; j < 4; j++) {
            int c = j * 512 + tid;
            int row = c >> 3, gl = c & 7;
            int gg = gl ^ (row & 7);
            int grow = m0 + row; grow = grow < Md ? grow : Md - 1;
            const __attribute__((address_space(1))) short* src =
                (const __attribute__((address_space(1))) short*)(A + (size_t)grow * lda + k0 + gg * 8);
            __builtin_amdgcn_global_load_lds(
                (const __attribute__((address_space(1))) void*)src,
                (__attribute__((address_space(3))) void*)&As[(buf * 2048 + c) * 8], 16, 0, 0);
        }
        // B: 1024 cells (128 rows x 8 g-chunks)
        #pragma unroll
        for (int j = 0; j < 2; j++) {
            int c = j * 512 + tid;
            int row = c >> 3, gl = c & 7;
            int gg = gl ^ (row & 7);
            int brow = n0 + row; brow = brow < Nd ? brow : Nd - 1;
            const __attribute__((address_space(1))) short* src =
                (const __attribute__((address_space(1))) short*)(Bt + (size_t)brow * ldb + k0 + gg * 8);
            __builtin_amdgcn_global_load_lds(
                (const __attribute__((address_space(1))) void*)src,
                (__attribute__((address_space(3))) void*)&Bs[(buf * 1024 + c) * 8], 16, 0, 0);
        }
    };

    const int nt = Kslab >> 6;
    stage(0, kbeg);
    stage(1, kbeg + 64);

    for (int t = 0; t < nt; t++) {
        const int cur = t % 3;
        if (t + 2 < nt) {
            stage((t + 2) % 3, kbeg + (t + 2) * 64);
            asm volatile("s_waitcnt vmcnt(12)" ::: "memory");  // tile t landed
        } else if (t + 1 < nt) {
            asm volatile("s_waitcnt vmcnt(6)" ::: "memory");
        } else {
            asm volatile("s_waitcnt vmcnt(0)" ::: "memory");
        }
        __builtin_amdgcn_s_barrier();       // tile t staged (all waves)
        __builtin_amdgcn_sched_barrier(0);

        short8 a[2][4], bfr[2][4];
        // kk=0 reads first (order pinned for lgkmcnt(8))
        #pragma unroll
        for (int m = 0; m < 4; m++) {
            int row = wr * 64 + m * 16 + l15;
            int gs  = kg ^ gsw;
            a[0][m] = *(const short8*)&As[(cur * 2048 + row * 8 + gs) * 8];
        }
        #pragma unroll
        for (int n = 0; n < 4; n++) {
            int row = wc * 64 + n * 16 + l15;
            int gs  = kg ^ gsw;
            bfr[0][n] = *(const short8*)&Bs[(cur * 1024 + row * 8 + gs) * 8];
        }
        __builtin_amdgcn_sched_barrier(0);
        // kk=1 reads
        #pragma unroll
        for (int m = 0; m < 4; m++) {
            int row = wr * 64 + m * 16 + l15;
            int gs  = (4 + kg) ^ gsw;
            a[1][m] = *(const short8*)&As[(cur * 2048 + row * 8 + gs) * 8];
        }
        #pragma unroll
        for (int n = 0; n < 4; n++) {
            int row = wc * 64 + n * 16 + l15;
            int gs  = (4 + kg) ^ gsw;
            bfr[1][n] = *(const short8*)&Bs[(cur * 1024 + row * 8 + gs) * 8];
        }
        __builtin_amdgcn_sched_barrier(0);
        asm volatile("s_waitcnt lgkmcnt(8)" ::: "memory");   // kk=0 in regs
        __builtin_amdgcn_sched_barrier(0);

        __builtin_amdgcn_s_setprio(1);
        #pragma unroll
        for (int m = 0; m < 4; m++)
            #pragma unroll
            for (int n = 0; n < 4; n++)
                acc[m][n] = __builtin_amdgcn_mfma_f32_16x16x32_bf16(a[0][m], bfr[0][n], acc[m][n], 0, 0, 0);
        __builtin_amdgcn_s_setprio(0);
        __builtin_amdgcn_sched_barrier(0);
        asm volatile("s_waitcnt lgkmcnt(0)" ::: "memory");   // all reads in regs
        __builtin_amdgcn_sched_barrier(0);
        __builtin_amdgcn_s_barrier();       // buffer cur free for stage(t+3)
        __builtin_amdgcn_sched_barrier(0);

        __builtin_amdgcn_s_setprio(1);
        #pragma unroll
        for (int m = 0; m < 4; m++)
            #pragma unroll
            for (int n = 0; n < 4; n++)
                acc[m][n] = __builtin_amdgcn_mfma_f32_16x16x32_bf16(a[1][m], bfr[1][n], acc[m][n], 0, 0, 0);
        __builtin_amdgcn_s_setprio(0);
    }

    // ---- LDS-staged coalesced epilogue ----
    unsigned short* Cs = (unsigned short*)As;   // [256][136] bf16 = 69.6 KB
    #pragma unroll
    for (int n = 0; n < 4; n++) {
        int col = wc * 64 + n * 16 + l15;
        float bv = BIAS ? bias[n0 + col] : 0.f;
        #pragma unroll
        for (int m = 0; m < 4; m++) {
            #pragma unroll
            for (int q = 0; q < 4; q++) {
                int row = wr * 64 + m * 16 + kg * 4 + q;
                Cs[row * 136 + col] = f2bf(acc[m][n][q] + bv);
            }
        }
    }
    __syncthreads();
    #pragma unroll
    for (int j = 0; j < 8; j++) {
        int c = j * 512 + tid;          // 16B cell; 16 cells/row
        int row = c >> 4, cc = c & 15;
        int grow = m0 + row;
        if (grow >= Md) continue;
        short8 v = *(const short8*)&Cs[row * 136 + cc * 8];
        if (SPLIT)
            *(short8*)&Cpart[(size_t)bz * Md * Nd + (size_t)grow * Nd + n0 + cc * 8] = v;
        else if (W16)
            *(short8*)&C16[(size_t)grow * Nd + n0 + cc * 8] = v;
    }
}

// ---------------------------------------------------------------------------
// Swizzled 128x128 BK=64 dbuf MFMA GEMM — small GEMMs (proj, delta).
// ---------------------------------------------------------------------------
template<bool SPLIT, bool PARTBF, bool BIAS, int ACT, bool W32, bool W16>
__global__ __launch_bounds__(256) void gemm_mfma(
    const unsigned short* __restrict__ A, int lda,
    const unsigned short* __restrict__ Bt, int ldb,
    const float* __restrict__ bias,
    float* __restrict__ C32,
    unsigned short* __restrict__ C16,
    void* __restrict__ Cpart,
    int Md, int Nd, int Kslab)
{
    __shared__ short As[2][128 * 64];
    __shared__ short Bs[2][128 * 64];

    const int nx = gridDim.x, ny = gridDim.y, nz = gridDim.z;
    const int nb = nx * ny * nz;
    int id = blockIdx.x + nx * (blockIdx.y + ny * blockIdx.z);
    int bx, by, bz;
    if ((nb & 7) == 0) {
        int swz = (id & 7) * (nb >> 3) + (id >> 3);
        bx = swz % nx;
        int rem = swz / nx;
        by = rem % ny;
        bz = rem / ny;
    } else {
        bx = blockIdx.x; by = blockIdx.y; bz = blockIdx.z;
    }

    const int tid  = threadIdx.x;
    const int lane = tid & 63;
    const int wid  = tid >> 6;
    const int wr   = wid >> 1;
    const int wc   = wid & 1;
    const int l15  = lane & 15;
    const int kg   = lane >> 4;
    const int gsw  = l15 & 7;
    const int m0   = bx * 128;
    const int n0   = by * 128;
    const int kbeg = SPLIT ? bz * Kslab : 0;

    floatx4 acc[4][4];
    #pragma unroll
    for (int m = 0; m < 4; m++)
        #pragma unroll
        for (int n = 0; n < 4; n++)
            acc[m][n] = (floatx4){0.f, 0.f, 0.f, 0.f};

    auto stage = [&](int buf, int k0) {
        #pragma unroll
        for (int j = 0; j < 4; j++) {
            int c = j * 256 + tid;
            int row = c >> 3, gl = c & 7;
            int gg = gl ^ (row & 7);
            int grow = m0 + row; grow = grow < Md ? grow : Md - 1;
            const __attribute__((address_space(1))) short* src =
                (const __attribute__((address_space(1))) short*)(A + (size_t)grow * lda + k0 + gg * 8);
            __builtin_amdgcn_global_load_lds(
                (const __attribute__((address_space(1))) void*)src,
                (__attribute__((address_space(3))) void*)&As[buf][c * 8], 16, 0, 0);
        }
        #pragma unroll
        for (int j = 0; j < 4; j++) {
            int c = j * 256 + tid;
            int row = c >> 3, gl = c & 7;
            int gg = gl ^ (row & 7);
            int brow = n0 + row; brow = brow < Nd ? brow : Nd - 1;
            const __attribute__((address_space(1))) short* src =
                (const __attribute__((address_space(1))) short*)(Bt + (size_t)brow * ldb + k0 + gg * 8);
            __builtin_amdgcn_global_load_lds(
                (const __attribute__((address_space(1))) void*)src,
                (__attribute__((address_space(3))) void*)&Bs[buf][c * 8], 16, 0, 0);
        }
    };

    stage(0, kbeg);
    asm volatile("s_waitcnt vmcnt(0)" ::: "memory");
    __builtin_amdgcn_s_barrier();
    __builtin_amdgcn_sched_barrier(0);

    const int nt = Kslab >> 6;
    for (int t = 0; t < nt; t++) {
        const int cur = t & 1;
        if (t + 1 < nt) {
            stage(cur ^ 1, kbeg + (t + 1) * 64);
            asm volatile("s_waitcnt vmcnt(8)" ::: "memory");
        } else {
            asm volatile("s_waitcnt vmcnt(0)" ::: "memory");
        }
        __builtin_amdgcn_s_barrier();
        __builtin_amdgcn_sched_barrier(0);

        short8 a[2][4], bfr[2][4];
        #pragma unroll
        for (int kk = 0; kk < 2; kk++) {
            #pragma unroll
            for (int m = 0; m < 4; m++) {
                int row = wr * 64 + m * 16 + l15;
                int gs  = (kk * 4 + kg) ^ gsw;
                a[kk][m] = *(const short8*)&As[cur][(row * 8 + gs) * 8];
            }
            #pragma unroll
            for (int n = 0; n < 4; n++) {
                int row = wc * 64 + n * 16 + l15;
                int gs  = (kk * 4 + kg) ^ gsw;
                bfr[kk][n] = *(const short8*)&Bs[cur][(row * 8 + gs) * 8];
            }
        }
        __builtin_amdgcn_s_setprio(1);
        #pragma unroll
        for (int kk = 0; kk < 2; kk++)
            #pragma unroll
            for (int m = 0; m < 4; m++)
                #pragma unroll
                for (int n = 0; n < 4; n++)
                    acc[m][n] = __builtin_amdgcn_mfma_f32_16x16x32_bf16(a[kk][m], bfr[kk][n], acc[m][n], 0, 0, 0);
        __builtin_amdgcn_s_setprio(0);
        __builtin_amdgcn_sched_barrier(0);
        __builtin_amdgcn_s_barrier();
    }

    if (SPLIT) {
        #pragma unroll
        for (int n = 0; n < 4; n++) {
            int col = n0 + wc * 64 + n * 16 + l15;
            if (col >= Nd) continue;
            #pragma unroll
            for (int m = 0; m < 4; m++)
                #pragma unroll
                for (int q = 0; q < 4; q++) {
                    int row = m0 + wr * 64 + m * 16 + kg * 4 + q;
                    if (row >= Md) continue;
                    size_t ix = (size_t)bz * Md * Nd + (size_t)row * Nd + col;
                    if (PARTBF) ((unsigned short*)Cpart)[ix] = f2bf(acc[m][n][q]);
                    else        ((float*)Cpart)[ix] = acc[m][n][q];
                }
        }
    } else {
        #pragma unroll
        for (int n = 0; n < 4; n++) {
            int col = n0 + wc * 64 + n * 16 + l15;
            if (col >= Nd) continue;
            float bv = BIAS ? bias[col] : 0.f;
            #pragma unroll
            for (int m = 0; m < 4; m++)
                #pragma unroll
                for (int q = 0; q < 4; q++) {
                    int row = m0 + wr * 64 + m * 16 + kg * 4 + q;
                    if (row >= Md) continue;
                    float v = acc[m][n][q] + bv;
                    if (ACT == 1) v = fmaxf(v, 0.f) + log1pf(expf(-fabsf(v)));  // softplus
                    if (W32) C32[(size_t)row * Nd + col] = v;
                    if (W16) C16[(size_t)row * Nd + col] = f2bf(v);
                }
        }
    }
}

// ---------------------------------------------------------------------------
// Sum S fp32 split-K partials + bias/act -> fp32/bf16. total % 1024 == 0.
// ---------------------------------------------------------------------------
template<int S, bool BIAS, int ACT, bool W32, bool W16>
__global__ __launch_bounds__(256) void reduce_split(
    const float* __restrict__ P, const float* __restrict__ bias,
    float* __restrict__ C32, unsigned short* __restrict__ C16,
    int total, int nmask)
{
    int i = (blockIdx.x * 256 + threadIdx.x) * 4;
    float4 v = *(const float4*)&P[i];
    #pragma unroll
    for (int s = 1; s < S; s++) {
        float4 p = *(const float4*)&P[(size_t)s * total + i];
        v.x += p.x; v.y += p.y; v.z += p.z; v.w += p.w;
    }
    float r[4] = {v.x, v.y, v.z, v.w};
    #pragma unroll
    for (int j = 0; j < 4; j++) {
        float t = r[j];
        if (BIAS) t += bias[(i + j) & nmask];
        if (ACT == 1) t = fmaxf(t, 0.f) + log1pf(expf(-fabsf(t)));
        if (W32) C32[i + j] = t;
        if (W16) C16[i + j] = f2bf(t);
    }
}

// ---------------------------------------------------------------------------
// Sum S bf16 split-K partials + bias -> bf16. total % 2048 == 0.
// ---------------------------------------------------------------------------
template<int S, bool BIAS>
__global__ __launch_bounds__(256) void reduce_split_bf(
    const unsigned short* __restrict__ P, const float* __restrict__ bias,
    unsigned short* __restrict__ C16, int total, int nmask)
{
    int i = (blockIdx.x * 256 + threadIdx.x) * 8;
    float r[8] = {};
    #pragma unroll
    for (int s = 0; s < S; s++) {
        short8 p = *(const short8*)&P[(size_t)s * total + i];
        #pragma unroll
        for (int j = 0; j < 8; j++) r[j] += bf2f((unsigned short)p[j]);
    }
    short8 o;
    #pragma unroll
    for (int j = 0; j < 8; j++) {
        float t = r[j];
        if (BIAS) t += bias[(i + j) & nmask];
        o[j] = (short)f2bf(t);
    }
    *(short8*)&C16[i] = o;
}

// ---------------------------------------------------------------------------
// Causal depthwise conv (K=4) + bias + SiLU; xz is bf16 with row stride 2*DI.
// ---------------------------------------------------------------------------
__global__ __launch_bounds__(256) void conv_silu_kernel(
    const unsigned short* __restrict__ xz, const float* __restrict__ conv_w,
    const float* __restrict__ conv_b, float* __restrict__ xc,
    unsigned short* __restrict__ xc_bf)
{
    int idx = blockIdx.x * 256 + threadIdx.x;
    if (idx >= Bb * Ll * DI) return;
    int d  = idx & (DI - 1);
    int bl = idx >> 11;
    int l  = bl % Ll;

    float acc = conv_b[d];
    #pragma unroll
    for (int k = 0; k < Kc; k++) {
        int ls = l + k - (Kc - 1);
        if (ls >= 0)
            acc = fmaf(conv_w[d * Kc + k], bf2f(xz[(size_t)(bl + ls - l) * (2 * DI) + d]), acc);
    }
    float s = fast_silu(acc);
    xc[idx] = s;
    xc_bf[idx] = f2bf(s);
}

// ---------------------------------------------------------------------------
// Chunked selective scan, 2-pass; chunk 0 emits y inside part1.
// ---------------------------------------------------------------------------
__global__ __launch_bounds__(256) void scan_part1(
    const float* __restrict__ delta, const float* __restrict__ xc,
    const unsigned short* __restrict__ xz, const float* __restrict__ proj,
    const float* __restrict__ A_log, const float* __restrict__ Dv,
    float* __restrict__ Pbuf, float* __restrict__ Sbuf,
    unsigned short* __restrict__ y)
{
    const int t    = threadIdx.x;
    const int nq   = t & 3;
    const int dloc = t >> 2;
    const int d    = blockIdx.x * 64 + dloc;
    const int b    = blockIdx.y;
    const int c    = blockIdx.z;          // chunk 0..2
    const bool emit = (c == 0);

    float4 Alq = *(const float4*)&A_log[(size_t)d * Nst + nq * 4];
    float Ar0 = -expf(Alq.x), Ar1 = -expf(Alq.y), Ar2 = -expf(Alq.z), Ar3 = -expf(Alq.w);
    const float Dd = Dv[d];

    float h0 = 0.f, h1 = 0.f, h2 = 0.f, h3 = 0.f;
    float sdl = 0.f;

    for (int l = c * CL; l < (c + 1) * CL; l++) {
        size_t bl = (size_t)b * Ll + l;
        float dl  = delta[bl * DI + d];
        float xcv = xc[bl * DI + d];
        float dx  = dl * xcv;
        const float* p = proj + bl * (DTR + 2 * Nst);
        float4 Bv = *(const float4*)&p[DTR + nq * 4];

        h0 = fmaf(__expf(dl * Ar0), h0, dx * Bv.x);
        h1 = fmaf(__expf(dl * Ar1), h1, dx * Bv.y);
        h2 = fmaf(__expf(dl * Ar2), h2, dx * Bv.z);
        h3 = fmaf(__expf(dl * Ar3), h3, dx * Bv.w);
        sdl += dl;

        if (emit) {
            float4 Cv = *(const float4*)&p[DTR + Nst + nq * 4];
            float yac = h0 * Cv.x + h1 * Cv.y + h2 * Cv.z + h3 * Cv.w;
            yac += __shfl_xor(yac, 1);
            yac += __shfl_xor(yac, 2);
            if (nq == 0) {
                float zv = bf2f(xz[bl * (2 * DI) + DI + d]);
                float yv = yac + Dd * xcv;
                yv *= fast_silu(zv);
                y[bl * DI + d] = f2bf(yv);
            }
        }
    }

    size_t o = (((size_t)c * Bb + b) * DI + d) * Nst + nq * 4;
    *(float4*)&Pbuf[o] = (float4){__expf(sdl * Ar0), __expf(sdl * Ar1),
                                  __expf(sdl * Ar2), __expf(sdl * Ar3)};
    *(float4*)&Sbuf[o] = (float4){h0, h1, h2, h3};
}

__global__ __launch_bounds__(256) void scan_part2(
    const float* __restrict__ delta, const float* __restrict__ xc,
    const unsigned short* __restrict__ xz, const float* __restrict__ proj,
    const float* __restrict__ A_log, const float* __restrict__ Dv,
    const float* __restrict__ Pbuf, const float* __restrict__ Sbuf,
    unsigned short* __restrict__ y)
{
    const int t    = threadIdx.x;
    const int nq   = t & 3;
    const int dloc = t >> 2;
    const int d    = blockIdx.x * 64 + dloc;
    const int b    = blockIdx.y;
    const int c    = blockIdx.z + 1;      // chunk 1..3

    float4 Alq = *(const float4*)&A_log[(size_t)d * Nst + nq * 4];
    float Ar0 = -expf(Alq.x), Ar1 = -expf(Alq.y), Ar2 = -expf(Alq.z), Ar3 = -expf(Alq.w);
    const float Dd = Dv[d];

    float h0 = 0.f, h1 = 0.f, h2 = 0.f, h3 = 0.f;
    for (int cc = 0; cc < c; cc++) {
        size_t o = (((size_t)cc * Bb + b) * DI + d) * Nst + nq * 4;
        float4 Pv = *(const float4*)&Pbuf[o];
        float4 Sv = *(const float4*)&Sbuf[o];
        h0 = fmaf(Pv.x, h0, Sv.x);
        h1 = fmaf(Pv.y, h1, Sv.y);
        h2 = fmaf(Pv.z, h2, Sv.z);
        h3 = fmaf(Pv.w, h3, Sv.w);
    }

    for (int l = c * CL; l < (c + 1) * CL; l++) {
        size_t bl = (size_t)b * Ll + l;
        float dl  = delta[bl * DI + d];
        float xcv = xc[bl * DI + d];
        float zv  = bf2f(xz[bl * (2 * DI) + DI + d]);
        float dx  = dl * xcv;
        const float* p = proj + bl * (DTR + 2 * Nst);
        float4 Bv = *(const float4*)&p[DTR + nq * 4];
        float4 Cv = *(const float4*)&p[DTR + Nst + nq * 4];

        h0 = fmaf(__expf(dl * Ar0), h0, dx * Bv.x);
        h1 = fmaf(__expf(dl * Ar1), h1, dx * Bv.y);
        h2 = fmaf(__expf(dl * Ar2), h2, dx * Bv.z);
        h3 = fmaf(__expf(dl * Ar3), h3, dx * Bv.w);

        float yac = h0 * Cv.x + h1 * Cv.y + h2 * Cv.z + h3 * Cv.w;
        yac += __shfl_xor(yac, 1);
        yac += __shfl_xor(yac, 2);

        if (nq == 0) {
            float yv = yac + Dd * xcv;
            yv *= fast_silu(zv);
            y[bl * DI + d] = f2bf(yv);
        }
    }
}

// ---------------------------------------------------------------------------
// logits[M,16] = out_bf[M,1024] @ W_out[1024,16] + b_out  (R13-proven form)
// ---------------------------------------------------------------------------
__global__ __launch_bounds__(256) void gemm_n16(
    const unsigned short* __restrict__ A, const float* __restrict__ W,
    const float* __restrict__ bias, float* __restrict__ C, int Kd)
{
    int m  = blockIdx.x;
    int t  = threadIdx.x;
    int c  = t & 15;
    int kg = t >> 4;
    const unsigned short* a = A + (size_t)m * Kd;

    float acc = 0.f;
    for (int k = kg; k < Kd; k += 16)
        acc = fmaf(bf2f(a[k]), W[k * NC + c], acc);

    __shared__ float red[256];
    red[t] = acc;
    __syncthreads();
    #pragma unroll
    for (int s = 128; s >= 16; s >>= 1) {
        if (t < s) red[t] += red[t + s];
        __syncthreads();
    }
    if (t < 16) C[(size_t)m * NC + t] = red[t] + bias[t];
}

// ---------------------------------------------------------------------------
extern "C" void kernel_launch(void* const* d_in, const int* in_sizes, int n_in,
                              void* d_out, int out_size, void* d_ws, size_t ws_size,
                              hipStream_t stream) {
    const float* x         = (const float*)d_in[0];
    const float* W_in      = (const float*)d_in[1];
    const float* b_in      = (const float*)d_in[2];
    const float* in_proj_w = (const float*)d_in[3];
    const float* conv_w    = (const float*)d_in[4];
    const float* conv_b    = (const float*)d_in[5];
    const float* x_proj_w  = (const float*)d_in[6];
    const float* dt_proj_w = (const float*)d_in[7];
    const float* dt_proj_b = (const float*)d_in[8];
    const float* A_log     = (const float*)d_in[9];
    const float* Dv        = (const float*)d_in[10];
    const float* out_proj  = (const float*)d_in[11];
    const float* W_out     = (const float*)d_in[12];
    const float* b_out     = (const float*)d_in[13];
    float* logits = (float*)d_out;

    char* base = (char*)d_ws;
    size_t off = 0;
    auto alloc = [&](size_t bytes) {
        char* p = base + off;
        off += (bytes + 255) & ~(size_t)255;
        return p;
    };
    unsigned short* x_bf    = (unsigned short*)alloc((size_t)M * DIN * 2);
    unsigned short* Wt_in   = (unsigned short*)alloc((size_t)Hh * DIN * 2);
    unsigned short* Wt_ip   = (unsigned short*)alloc((size_t)(2 * DI) * Hh * 2);
    unsigned short* Wt_op   = (unsigned short*)alloc((size_t)Hh * DI * 2);
    unsigned short* xpw_t   = (unsigned short*)alloc((size_t)96 * DI * 2);
    unsigned short* dtw_t   = (unsigned short*)alloc((size_t)DI * DTR * 2);
    unsigned short* h_bf    = (unsigned short*)alloc((size_t)M * Hh * 2);
    unsigned short* xz_bf   = (unsigned short*)alloc((size_t)M * 2 * DI * 2);
    float*          xc      = (float*)alloc((size_t)M * DI * 4);       // | P14 alias (13.1MB)
    float*          delta   = (float*)alloc((size_t)M * DI * 4);       // | P8 alias
    unsigned short* xc_bf   = (unsigned short*)alloc((size_t)M * DI * 2);
    float*          proj_f  = (float*)alloc((size_t)M * 96 * 4);
    unsigned short* proj_bf = (unsigned short*)alloc((size_t)M * 96 * 2);
    unsigned short* y_bf    = (unsigned short*)alloc((size_t)M * DI * 2);
    unsigned short* out_bf  = (unsigned short*)alloc((size_t)M * Hh * 2);

    unsigned short* P14 = (unsigned short*)xc;   // bf16 [4][1600][1024] = 13.1MB
    float*          P8  = delta;                 // fp32 [8][1600][96]  = 4.9MB
    float*          Pbuf = (float*)x_bf;         // scan chunk buffers (x_bf dead)
    float*          Sbuf = Pbuf + (size_t)(NCH - 1) * Bb * DI * Nst;

    dim3 blk(256), blk5(512);

    // 0) fused prologue: convert + 5 transposes
    prep_kernel<<<dim3(22208), blk, 0, stream>>>(
        x, x_bf, W_in, Wt_in, in_proj_w, Wt_ip, out_proj, Wt_op,
        x_proj_w, xpw_t, dt_proj_w, dtw_t);

    // 1) h = x @ W_in + b_in   [1600,6144]@[6144,1024], split-K 4 -> 224 blocks
    gemm_deep<true, false, false><<<dim3(7, Hh / 128, 4), blk5, 0, stream>>>(
        x_bf, DIN, Wt_in, DIN, nullptr, nullptr, P14, M, Hh, DIN / 4);
    reduce_split_bf<4, true><<<dim3((M * Hh) / 2048), blk, 0, stream>>>(
        P14, b_in, h_bf, M * Hh, Hh - 1);

    // 2) xz = h @ in_proj_w    [1600,1024]@[1024,4096], 224 blocks, no split
    gemm_deep<false, false, true><<<dim3(7, (2 * DI) / 128, 1), blk5, 0, stream>>>(
        h_bf, Hh, Wt_ip, Hh, nullptr, xz_bf, nullptr, M, 2 * DI, Hh);

    // 3) xc = silu(conv(xm) + conv_b)  -> fp32 + bf16
    conv_silu_kernel<<<dim3((Bb * Ll * DI) / 256), blk, 0, stream>>>(
        xz_bf, conv_w, conv_b, xc, xc_bf);

    // 4) proj = xc @ x_proj_w  [1600,2048]@[2048,96], split-K 8 -> 104 blocks
    gemm_mfma<true, false, false, 0, false, false><<<dim3(13, 1, 8), blk, 0, stream>>>(
        xc_bf, DI, xpw_t, DI, nullptr, nullptr, nullptr, P8, M, 96, DI / 8);
    reduce_split<8, false, 0, true, true><<<dim3((M * 96) / 1024), blk, 0, stream>>>(
        P8, nullptr, proj_f, proj_bf, M * 96, 0);

    // 5) delta = softplus(proj[:,:64] @ dt_proj_w + dt_proj_b)  [1600,64]@[64,2048]
    gemm_mfma<false, false, true, 1, true, false><<<dim3(13, DI / 128, 1), blk, 0, stream>>>(
        proj_bf, 96, dtw_t, DTR, dt_proj_b, delta, nullptr, nullptr, M, DI, DTR);

    // 6) chunked selective scan: part1 (chunks 0..2, chunk 0 emits y),
    //    part2 (chunks 1..3)
    scan_part1<<<dim3(DI / 64, Bb, NCH - 1), blk, 0, stream>>>(
        delta, xc, xz_bf, proj_f, A_log, Dv, Pbuf, Sbuf, y_bf);
    scan_part2<<<dim3(DI / 64, Bb, NCH - 1), blk, 0, stream>>>(
        delta, xc, xz_bf, proj_f, A_log, Dv, Pbuf, Sbuf, y_bf);

    // 7) out = y @ out_proj_w  [1600,2048]@[2048,1024], split-K 4 -> 224 blocks
    gemm_deep<true, false, false><<<dim3(7, Hh / 128, 4), blk5, 0, stream>>>(
        y_bf, DI, Wt_op, DI, nullptr, nullptr, P14, M, Hh, DI / 4);
    reduce_split_bf<4, false><<<dim3((M * Hh) / 2048), blk, 0, stream>>>(
        P14, nullptr, out_bf, M * Hh, 0);

    // 8) logits = out @ W_out + b_out  [1600,1024]@[1024,16]
    gemm_n16<<<dim3(M), blk, 0, stream>>>(out_bf, W_out, b_out, logits, Hh);
}

// Round 16
// 236.639 us; speedup vs baseline: 1.2114x; 1.0353x over previous
//
#include <hip/hip_runtime.h>
#include <hip/hip_bf16.h>
#include <stdint.h>

// Problem constants
constexpr int Bb  = 16;
constexpr int Ll  = 100;
constexpr int DIN = 6144;
constexpr int Hh  = 1024;
constexpr int DI  = 2048;
constexpr int Nst = 16;
constexpr int DTR = 64;
constexpr int Kc  = 4;
constexpr int NC  = 16;
constexpr int M   = Bb * Ll;   // 1600 tokens
constexpr int NCH = 4;         // scan L-chunks
constexpr int CL  = Ll / NCH;  // 25

typedef __attribute__((ext_vector_type(8))) short short8;
typedef __attribute__((ext_vector_type(4))) float floatx4;

__device__ __forceinline__ float bf2f(unsigned short u) {
    union { uint32_t b; float f; } x; x.b = ((uint32_t)u) << 16; return x.f;
}
__device__ __forceinline__ unsigned short f2bf(float f) {
    union { float f; uint32_t b; } x; x.f = f;
    uint32_t r = x.b + 0x7FFF + ((x.b >> 16) & 1);   // RNE
    return (unsigned short)(r >> 16);
}
__device__ __forceinline__ float fast_silu(float x) {
    return x / (1.f + __expf(-x));
}

// ---------------------------------------------------------------------------
// Fused prologue: one kernel, sectioned grid (saves 5 serial launch gaps).
// ---------------------------------------------------------------------------
__global__ __launch_bounds__(256) void prep_kernel(
    const float* __restrict__ x, unsigned short* __restrict__ x_bf,
    const float* __restrict__ W_in, unsigned short* __restrict__ Wt_in,
    const float* __restrict__ W_ip, unsigned short* __restrict__ Wt_ip,
    const float* __restrict__ W_op, unsigned short* __restrict__ Wt_op,
    const float* __restrict__ xpw,  unsigned short* __restrict__ xpw_t,
    const float* __restrict__ dtw,  unsigned short* __restrict__ dtw_t)
{
    __shared__ float t[32][33];
    int b = blockIdx.x;

    if (b < 9600) {                       // convert x
        int i = (b * 256 + threadIdx.x) * 4;
        float4 v = *(const float4*)&x[i];
        x_bf[i + 0] = f2bf(v.x);
        x_bf[i + 1] = f2bf(v.y);
        x_bf[i + 2] = f2bf(v.z);
        x_bf[i + 3] = f2bf(v.w);
        return;
    }
    const float* in; unsigned short* out; int K, N, bid;
    if      (b < 15744) { in = W_in; out = Wt_in; K = DIN; N = Hh;     bid = b - 9600;  }
    else if (b < 19840) { in = W_ip; out = Wt_ip; K = Hh;  N = 2 * DI; bid = b - 15744; }
    else if (b < 21888) { in = W_op; out = Wt_op; K = DI;  N = Hh;     bid = b - 19840; }
    else if (b < 22080) { in = xpw;  out = xpw_t; K = DI;  N = 96;     bid = b - 21888; }
    else                { in = dtw;  out = dtw_t; K = DTR; N = DI;     bid = b - 22080; }

    int kx = bid % (K / 32), ny = bid / (K / 32);
    int k0 = kx * 32, n0 = ny * 32;
    int tx = threadIdx.x & 31, ty = threadIdx.x >> 5;
    #pragma unroll
    for (int i = 0; i < 4; i++)
        t[ty + i * 8][tx] = in[(size_t)(k0 + ty + i * 8) * N + n0 + tx];
    __syncthreads();
    #pragma unroll
    for (int i = 0; i < 4; i++)
        out[(size_t)(n0 + ty + i * 8) * K + k0 + tx] = f2bf(t[tx][ty + i * 8]);
}

// ---------------------------------------------------------------------------
// Deep-pipelined bf16 MFMA GEMM (big GEMMs 1/2/7): BM=256, BN=128, BK=64;
// 512 thr = 8 waves (4m x 2n), wave tile 64x64. 3-buffer LDS ring (144 KB),
// 2-deep counted-vmcnt prefetch, swizzled staging (R11), LDS-staged
// coalesced epilogue. Early buffer release (R13): the reads-done barrier
// sits after lgkmcnt(0) and BEFORE the single 32-MFMA cluster — ds_reads
// retire into regs, buffer freed early, MFMA overlaps other waves' stage.
// (R14's further lgkm-split of the MFMA cluster was a measured regression —
//  R13 vs R15 A/B — and is intentionally NOT present.)
// ---------------------------------------------------------------------------
template<bool SPLIT, bool BIAS, bool W16>
__global__ __launch_bounds__(512) void gemm_deep(
    const unsigned short* __restrict__ A, int lda,    // [Md x lda]
    const unsigned short* __restrict__ Bt, int ldb,   // [Nd x ldb]
    const float* __restrict__ bias,                   // [Nd]
    unsigned short* __restrict__ C16,                 // final bf16 out
    unsigned short* __restrict__ Cpart,               // bf16 partials
    int Md, int Nd, int Kslab)
{
    __shared__ short As[3 * 256 * 64];   // 96 KB
    __shared__ short Bs[3 * 128 * 64];   // 48 KB

    // XCD-aware block remap
    const int nx = gridDim.x, ny = gridDim.y, nz = gridDim.z;
    const int nb = nx * ny * nz;
    int id = blockIdx.x + nx * (blockIdx.y + ny * blockIdx.z);
    int bx, by, bz;
    if ((nb & 7) == 0) {
        int swz = (id & 7) * (nb >> 3) + (id >> 3);
        bx = swz % nx;
        int rem = swz / nx;
        by = rem % ny;
        bz = rem / ny;
    } else {
        bx = blockIdx.x; by = blockIdx.y; bz = blockIdx.z;
    }

    const int tid  = threadIdx.x;
    const int lane = tid & 63;
    const int wid  = tid >> 6;      // 0..7
    const int wr   = wid >> 1;      // 0..3 (m)
    const int wc   = wid & 1;       // 0..1 (n)
    const int l15  = lane & 15;
    const int kg   = lane >> 4;
    const int gsw  = l15 & 7;       // ds_read swizzle term
    const int m0   = bx * 256;
    const int n0   = by * 128;
    const int kbeg = SPLIT ? bz * Kslab : 0;

    floatx4 acc[4][4];
    #pragma unroll
    for (int m = 0; m < 4; m++)
        #pragma unroll
        for (int n = 0; n < 4; n++)
            acc[m][n] = (floatx4){0.f, 0.f, 0.f, 0.f};

    auto stage = [&](int buf, int k0) {
        // A: 2048 cells (256 rows x 8 g-chunks of 16B), swizzled source
        #pragma unroll
        for (int j = 0; j < 4; j++) {
            int c = j * 512 + tid;
            int row = c >> 3, gl = c & 7;
            int gg = gl ^ (row & 7);
            int grow = m0 + row; grow = grow < Md ? grow : Md - 1;
            const __attribute__((address_space(1))) short* src =
                (const __attribute__((address_space(1))) short*)(A + (size_t)grow * lda + k0 + gg * 8);
            __builtin_amdgcn_global_load_lds(
                (const __attribute__((address_space(1))) void*)src,
                (__attribute__((address_space(3))) void*)&As[(buf * 2048 + c) * 8], 16, 0, 0);
        }
        // B: 1024 cells (128 rows x 8 g-chunks)
        #pragma unroll
        for (int j = 0; j < 2; j++) {
            int c = j * 512 + tid;
            int row = c >> 3, gl = c & 7;
            int gg = gl ^ (row & 7);
            int brow = n0 + row; brow = brow < Nd ? brow : Nd - 1;
            const __attribute__((address_space(1))) short* src =
                (const __attribute__((address_space(1))) short*)(Bt + (size_t)brow * ldb + k0 + gg * 8);
            __builtin_amdgcn_global_load_lds(
                (const __attribute__((address_space(1))) void*)src,
                (__attribute__((address_space(3))) void*)&Bs[(buf * 1024 + c) * 8], 16, 0, 0);
        }
    };

    const int nt = Kslab >> 6;
    stage(0, kbeg);
    stage(1, kbeg + 64);

    for (int t = 0; t < nt; t++) {
        const int cur = t % 3;
        if (t + 2 < nt) {
            stage((t + 2) % 3, kbeg + (t + 2) * 64);
            asm volatile("s_waitcnt vmcnt(12)" ::: "memory");  // tile t landed
        } else if (t + 1 < nt) {
            asm volatile("s_waitcnt vmcnt(6)" ::: "memory");
        } else {
            asm volatile("s_waitcnt vmcnt(0)" ::: "memory");
        }
        __builtin_amdgcn_s_barrier();       // tile t staged (all waves)
        __builtin_amdgcn_sched_barrier(0);

        short8 a[2][4], bfr[2][4];
        #pragma unroll
        for (int kk = 0; kk < 2; kk++) {
            #pragma unroll
            for (int m = 0; m < 4; m++) {
                int row = wr * 64 + m * 16 + l15;
                int gs  = (kk * 4 + kg) ^ gsw;
                a[kk][m] = *(const short8*)&As[(cur * 2048 + row * 8 + gs) * 8];
            }
            #pragma unroll
            for (int n = 0; n < 4; n++) {
                int row = wc * 64 + n * 16 + l15;
                int gs  = (kk * 4 + kg) ^ gsw;
                bfr[kk][n] = *(const short8*)&Bs[(cur * 1024 + row * 8 + gs) * 8];
            }
        }
        asm volatile("s_waitcnt lgkmcnt(0)" ::: "memory");   // reads in regs
        __builtin_amdgcn_sched_barrier(0);
        __builtin_amdgcn_s_barrier();       // buffer cur free for stage(t+3)
        __builtin_amdgcn_sched_barrier(0);

        __builtin_amdgcn_s_setprio(1);
        #pragma unroll
        for (int kk = 0; kk < 2; kk++)
            #pragma unroll
            for (int m = 0; m < 4; m++)
                #pragma unroll
                for (int n = 0; n < 4; n++)
                    acc[m][n] = __builtin_amdgcn_mfma_f32_16x16x32_bf16(a[kk][m], bfr[kk][n], acc[m][n], 0, 0, 0);
        __builtin_amdgcn_s_setprio(0);
    }

    // ---- LDS-staged coalesced epilogue ----
    unsigned short* Cs = (unsigned short*)As;   // [256][136] bf16 = 69.6 KB
    #pragma unroll
    for (int n = 0; n < 4; n++) {
        int col = wc * 64 + n * 16 + l15;
        float bv = BIAS ? bias[n0 + col] : 0.f;
        #pragma unroll
        for (int m = 0; m < 4; m++) {
            #pragma unroll
            for (int q = 0; q < 4; q++) {
                int row = wr * 64 + m * 16 + kg * 4 + q;
                Cs[row * 136 + col] = f2bf(acc[m][n][q] + bv);
            }
        }
    }
    __syncthreads();
    #pragma unroll
    for (int j = 0; j < 8; j++) {
        int c = j * 512 + tid;          // 16B cell; 16 cells/row
        int row = c >> 4, cc = c & 15;
        int grow = m0 + row;
        if (grow >= Md) continue;
        short8 v = *(const short8*)&Cs[row * 136 + cc * 8];
        if (SPLIT)
            *(short8*)&Cpart[(size_t)bz * Md * Nd + (size_t)grow * Nd + n0 + cc * 8] = v;
        else if (W16)
            *(short8*)&C16[(size_t)grow * Nd + n0 + cc * 8] = v;
    }
}

// ---------------------------------------------------------------------------
// Swizzled 128x128 BK=64 dbuf MFMA GEMM — small GEMMs (proj, delta).
// ---------------------------------------------------------------------------
template<bool SPLIT, bool PARTBF, bool BIAS, int ACT, bool W32, bool W16>
__global__ __launch_bounds__(256) void gemm_mfma(
    const unsigned short* __restrict__ A, int lda,
    const unsigned short* __restrict__ Bt, int ldb,
    const float* __restrict__ bias,
    float* __restrict__ C32,
    unsigned short* __restrict__ C16,
    void* __restrict__ Cpart,
    int Md, int Nd, int Kslab)
{
    __shared__ short As[2][128 * 64];
    __shared__ short Bs[2][128 * 64];

    const int nx = gridDim.x, ny = gridDim.y, nz = gridDim.z;
    const int nb = nx * ny * nz;
    int id = blockIdx.x + nx * (blockIdx.y + ny * blockIdx.z);
    int bx, by, bz;
    if ((nb & 7) == 0) {
        int swz = (id & 7) * (nb >> 3) + (id >> 3);
        bx = swz % nx;
        int rem = swz / nx;
        by = rem % ny;
        bz = rem / ny;
    } else {
        bx = blockIdx.x; by = blockIdx.y; bz = blockIdx.z;
    }

    const int tid  = threadIdx.x;
    const int lane = tid & 63;
    const int wid  = tid >> 6;
    const int wr   = wid >> 1;
    const int wc   = wid & 1;
    const int l15  = lane & 15;
    const int kg   = lane >> 4;
    const int gsw  = l15 & 7;
    const int m0   = bx * 128;
    const int n0   = by * 128;
    const int kbeg = SPLIT ? bz * Kslab : 0;

    floatx4 acc[4][4];
    #pragma unroll
    for (int m = 0; m < 4; m++)
        #pragma unroll
        for (int n = 0; n < 4; n++)
            acc[m][n] = (floatx4){0.f, 0.f, 0.f, 0.f};

    auto stage = [&](int buf, int k0) {
        #pragma unroll
        for (int j = 0; j < 4; j++) {
            int c = j * 256 + tid;
            int row = c >> 3, gl = c & 7;
            int gg = gl ^ (row & 7);
            int grow = m0 + row; grow = grow < Md ? grow : Md - 1;
            const __attribute__((address_space(1))) short* src =
                (const __attribute__((address_space(1))) short*)(A + (size_t)grow * lda + k0 + gg * 8);
            __builtin_amdgcn_global_load_lds(
                (const __attribute__((address_space(1))) void*)src,
                (__attribute__((address_space(3))) void*)&As[buf][c * 8], 16, 0, 0);
        }
        #pragma unroll
        for (int j = 0; j < 4; j++) {
            int c = j * 256 + tid;
            int row = c >> 3, gl = c & 7;
            int gg = gl ^ (row & 7);
            int brow = n0 + row; brow = brow < Nd ? brow : Nd - 1;
            const __attribute__((address_space(1))) short* src =
                (const __attribute__((address_space(1))) short*)(Bt + (size_t)brow * ldb + k0 + gg * 8);
            __builtin_amdgcn_global_load_lds(
                (const __attribute__((address_space(1))) void*)src,
                (__attribute__((address_space(3))) void*)&Bs[buf][c * 8], 16, 0, 0);
        }
    };

    stage(0, kbeg);
    asm volatile("s_waitcnt vmcnt(0)" ::: "memory");
    __builtin_amdgcn_s_barrier();
    __builtin_amdgcn_sched_barrier(0);

    const int nt = Kslab >> 6;
    for (int t = 0; t < nt; t++) {
        const int cur = t & 1;
        if (t + 1 < nt) {
            stage(cur ^ 1, kbeg + (t + 1) * 64);
            asm volatile("s_waitcnt vmcnt(8)" ::: "memory");
        } else {
            asm volatile("s_waitcnt vmcnt(0)" ::: "memory");
        }
        __builtin_amdgcn_s_barrier();
        __builtin_amdgcn_sched_barrier(0);

        short8 a[2][4], bfr[2][4];
        #pragma unroll
        for (int kk = 0; kk < 2; kk++) {
            #pragma unroll
            for (int m = 0; m < 4; m++) {
                int row = wr * 64 + m * 16 + l15;
                int gs  = (kk * 4 + kg) ^ gsw;
                a[kk][m] = *(const short8*)&As[cur][(row * 8 + gs) * 8];
            }
            #pragma unroll
            for (int n = 0; n < 4; n++) {
                int row = wc * 64 + n * 16 + l15;
                int gs  = (kk * 4 + kg) ^ gsw;
                bfr[kk][n] = *(const short8*)&Bs[cur][(row * 8 + gs) * 8];
            }
        }
        __builtin_amdgcn_s_setprio(1);
        #pragma unroll
        for (int kk = 0; kk < 2; kk++)
            #pragma unroll
            for (int m = 0; m < 4; m++)
                #pragma unroll
                for (int n = 0; n < 4; n++)
                    acc[m][n] = __builtin_amdgcn_mfma_f32_16x16x32_bf16(a[kk][m], bfr[kk][n], acc[m][n], 0, 0, 0);
        __builtin_amdgcn_s_setprio(0);
        __builtin_amdgcn_sched_barrier(0);
        __builtin_amdgcn_s_barrier();
    }

    if (SPLIT) {
        #pragma unroll
        for (int n = 0; n < 4; n++) {
            int col = n0 + wc * 64 + n * 16 + l15;
            if (col >= Nd) continue;
            #pragma unroll
            for (int m = 0; m < 4; m++)
                #pragma unroll
                for (int q = 0; q < 4; q++) {
                    int row = m0 + wr * 64 + m * 16 + kg * 4 + q;
                    if (row >= Md) continue;
                    size_t ix = (size_t)bz * Md * Nd + (size_t)row * Nd + col;
                    if (PARTBF) ((unsigned short*)Cpart)[ix] = f2bf(acc[m][n][q]);
                    else        ((float*)Cpart)[ix] = acc[m][n][q];
                }
        }
    } else {
        #pragma unroll
        for (int n = 0; n < 4; n++) {
            int col = n0 + wc * 64 + n * 16 + l15;
            if (col >= Nd) continue;
            float bv = BIAS ? bias[col] : 0.f;
            #pragma unroll
            for (int m = 0; m < 4; m++)
                #pragma unroll
                for (int q = 0; q < 4; q++) {
                    int row = m0 + wr * 64 + m * 16 + kg * 4 + q;
                    if (row >= Md) continue;
                    float v = acc[m][n][q] + bv;
                    if (ACT == 1) v = fmaxf(v, 0.f) + log1pf(expf(-fabsf(v)));  // softplus
                    if (W32) C32[(size_t)row * Nd + col] = v;
                    if (W16) C16[(size_t)row * Nd + col] = f2bf(v);
                }
        }
    }
}

// ---------------------------------------------------------------------------
// Sum S fp32 split-K partials + bias/act -> fp32/bf16. total % 1024 == 0.
// ---------------------------------------------------------------------------
template<int S, bool BIAS, int ACT, bool W32, bool W16>
__global__ __launch_bounds__(256) void reduce_split(
    const float* __restrict__ P, const float* __restrict__ bias,
    float* __restrict__ C32, unsigned short* __restrict__ C16,
    int total, int nmask)
{
    int i = (blockIdx.x * 256 + threadIdx.x) * 4;
    float4 v = *(const float4*)&P[i];
    #pragma unroll
    for (int s = 1; s < S; s++) {
        float4 p = *(const float4*)&P[(size_t)s * total + i];
        v.x += p.x; v.y += p.y; v.z += p.z; v.w += p.w;
    }
    float r[4] = {v.x, v.y, v.z, v.w};
    #pragma unroll
    for (int j = 0; j < 4; j++) {
        float t = r[j];
        if (BIAS) t += bias[(i + j) & nmask];
        if (ACT == 1) t = fmaxf(t, 0.f) + log1pf(expf(-fabsf(t)));
        if (W32) C32[i + j] = t;
        if (W16) C16[i + j] = f2bf(t);
    }
}

// ---------------------------------------------------------------------------
// Sum S bf16 split-K partials + bias -> bf16. total % 2048 == 0.
// ---------------------------------------------------------------------------
template<int S, bool BIAS>
__global__ __launch_bounds__(256) void reduce_split_bf(
    const unsigned short* __restrict__ P, const float* __restrict__ bias,
    unsigned short* __restrict__ C16, int total, int nmask)
{
    int i = (blockIdx.x * 256 + threadIdx.x) * 8;
    float r[8] = {};
    #pragma unroll
    for (int s = 0; s < S; s++) {
        short8 p = *(const short8*)&P[(size_t)s * total + i];
        #pragma unroll
        for (int j = 0; j < 8; j++) r[j] += bf2f((unsigned short)p[j]);
    }
    short8 o;
    #pragma unroll
    for (int j = 0; j < 8; j++) {
        float t = r[j];
        if (BIAS) t += bias[(i + j) & nmask];
        o[j] = (short)f2bf(t);
    }
    *(short8*)&C16[i] = o;
}

// ---------------------------------------------------------------------------
// Causal depthwise conv (K=4) + bias + SiLU; xz is bf16 with row stride 2*DI.
// ---------------------------------------------------------------------------
__global__ __launch_bounds__(256) void conv_silu_kernel(
    const unsigned short* __restrict__ xz, const float* __restrict__ conv_w,
    const float* __restrict__ conv_b, float* __restrict__ xc,
    unsigned short* __restrict__ xc_bf)
{
    int idx = blockIdx.x * 256 + threadIdx.x;
    if (idx >= Bb * Ll * DI) return;
    int d  = idx & (DI - 1);
    int bl = idx >> 11;
    int l  = bl % Ll;

    float acc = conv_b[d];
    #pragma unroll
    for (int k = 0; k < Kc; k++) {
        int ls = l + k - (Kc - 1);
        if (ls >= 0)
            acc = fmaf(conv_w[d * Kc + k], bf2f(xz[(size_t)(bl + ls - l) * (2 * DI) + d]), acc);
    }
    float s = fast_silu(acc);
    xc[idx] = s;
    xc_bf[idx] = f2bf(s);
}

// ---------------------------------------------------------------------------
// Chunked selective scan, 2-pass (R13-proven): part1 chunks 0..2 (P/S only,
// light), part2 all 4 chunks (h_start fold + recurrence + y emit).
// ---------------------------------------------------------------------------
__global__ __launch_bounds__(256) void scan_part1(
    const float* __restrict__ delta, const float* __restrict__ xc,
    const float* __restrict__ proj,  const float* __restrict__ A_log,
    float* __restrict__ Pbuf, float* __restrict__ Sbuf)
{
    const int t    = threadIdx.x;
    const int nq   = t & 3;
    const int dloc = t >> 2;
    const int d    = blockIdx.x * 64 + dloc;
    const int b    = blockIdx.y;
    const int c    = blockIdx.z;

    float4 Alq = *(const float4*)&A_log[(size_t)d * Nst + nq * 4];
    float Ar0 = -expf(Alq.x), Ar1 = -expf(Alq.y), Ar2 = -expf(Alq.z), Ar3 = -expf(Alq.w);

    float h0 = 0.f, h1 = 0.f, h2 = 0.f, h3 = 0.f;
    float sdl = 0.f;

    for (int l = c * CL; l < (c + 1) * CL; l++) {
        size_t bl = (size_t)b * Ll + l;
        float dl  = delta[bl * DI + d];
        float xcv = xc[bl * DI + d];
        float dx  = dl * xcv;
        float4 Bv = *(const float4*)&proj[bl * (DTR + 2 * Nst) + DTR + nq * 4];

        h0 = fmaf(__expf(dl * Ar0), h0, dx * Bv.x);
        h1 = fmaf(__expf(dl * Ar1), h1, dx * Bv.y);
        h2 = fmaf(__expf(dl * Ar2), h2, dx * Bv.z);
        h3 = fmaf(__expf(dl * Ar3), h3, dx * Bv.w);
        sdl += dl;
    }

    size_t o = (((size_t)c * Bb + b) * DI + d) * Nst + nq * 4;
    *(float4*)&Pbuf[o] = (float4){__expf(sdl * Ar0), __expf(sdl * Ar1),
                                  __expf(sdl * Ar2), __expf(sdl * Ar3)};
    *(float4*)&Sbuf[o] = (float4){h0, h1, h2, h3};
}

__global__ __launch_bounds__(256) void scan_part2(
    const float* __restrict__ delta, const float* __restrict__ xc,
    const unsigned short* __restrict__ xz, const float* __restrict__ proj,
    const float* __restrict__ A_log, const float* __restrict__ Dv,
    const float* __restrict__ Pbuf, const float* __restrict__ Sbuf,
    unsigned short* __restrict__ y)
{
    const int t    = threadIdx.x;
    const int nq   = t & 3;
    const int dloc = t >> 2;
    const int d    = blockIdx.x * 64 + dloc;
    const int b    = blockIdx.y;
    const int c    = blockIdx.z;

    float4 Alq = *(const float4*)&A_log[(size_t)d * Nst + nq * 4];
    float Ar0 = -expf(Alq.x), Ar1 = -expf(Alq.y), Ar2 = -expf(Alq.z), Ar3 = -expf(Alq.w);
    const float Dd = Dv[d];

    float h0 = 0.f, h1 = 0.f, h2 = 0.f, h3 = 0.f;
    for (int cc = 0; cc < c; cc++) {
        size_t o = (((size_t)cc * Bb + b) * DI + d) * Nst + nq * 4;
        float4 Pv = *(const float4*)&Pbuf[o];
        float4 Sv = *(const float4*)&Sbuf[o];
        h0 = fmaf(Pv.x, h0, Sv.x);
        h1 = fmaf(Pv.y, h1, Sv.y);
        h2 = fmaf(Pv.z, h2, Sv.z);
        h3 = fmaf(Pv.w, h3, Sv.w);
    }

    for (int l = c * CL; l < (c + 1) * CL; l++) {
        size_t bl = (size_t)b * Ll + l;
        float dl  = delta[bl * DI + d];
        float xcv = xc[bl * DI + d];
        float zv  = bf2f(xz[bl * (2 * DI) + DI + d]);
        float dx  = dl * xcv;
        const float* p = proj + bl * (DTR + 2 * Nst);
        float4 Bv = *(const float4*)&p[DTR + nq * 4];
        float4 Cv = *(const float4*)&p[DTR + Nst + nq * 4];

        h0 = fmaf(__expf(dl * Ar0), h0, dx * Bv.x);
        h1 = fmaf(__expf(dl * Ar1), h1, dx * Bv.y);
        h2 = fmaf(__expf(dl * Ar2), h2, dx * Bv.z);
        h3 = fmaf(__expf(dl * Ar3), h3, dx * Bv.w);

        float yac = h0 * Cv.x + h1 * Cv.y + h2 * Cv.z + h3 * Cv.w;
        yac += __shfl_xor(yac, 1);
        yac += __shfl_xor(yac, 2);

        if (nq == 0) {
            float yv = yac + Dd * xcv;
            yv *= fast_silu(zv);
            y[bl * DI + d] = f2bf(yv);
        }
    }
}

// ---------------------------------------------------------------------------
// logits[M,16] = out_bf[M,1024] @ W_out[1024,16] + b_out
// ---------------------------------------------------------------------------
__global__ __launch_bounds__(256) void gemm_n16(
    const unsigned short* __restrict__ A, const float* __restrict__ W,
    const float* __restrict__ bias, float* __restrict__ C, int Kd)
{
    int m  = blockIdx.x;
    int t  = threadIdx.x;
    int c  = t & 15;
    int kg = t >> 4;
    const unsigned short* a = A + (size_t)m * Kd;

    float acc = 0.f;
    for (int k = kg; k < Kd; k += 16)
        acc = fmaf(bf2f(a[k]), W[k * NC + c], acc);

    __shared__ float red[256];
    red[t] = acc;
    __syncthreads();
    #pragma unroll
    for (int s = 128; s >= 16; s >>= 1) {
        if (t < s) red[t] += red[t + s];
        __syncthreads();
    }
    if (t < 16) C[(size_t)m * NC + t] = red[t] + bias[t];
}

// ---------------------------------------------------------------------------
extern "C" void kernel_launch(void* const* d_in, const int* in_sizes, int n_in,
                              void* d_out, int out_size, void* d_ws, size_t ws_size,
                              hipStream_t stream) {
    const float* x         = (const float*)d_in[0];
    const float* W_in      = (const float*)d_in[1];
    const float* b_in      = (const float*)d_in[2];
    const float* in_proj_w = (const float*)d_in[3];
    const float* conv_w    = (const float*)d_in[4];
    const float* conv_b    = (const float*)d_in[5];
    const float* x_proj_w  = (const float*)d_in[6];
    const float* dt_proj_w = (const float*)d_in[7];
    const float* dt_proj_b = (const float*)d_in[8];
    const float* A_log     = (const float*)d_in[9];
    const float* Dv        = (const float*)d_in[10];
    const float* out_proj  = (const float*)d_in[11];
    const float* W_out     = (const float*)d_in[12];
    const float* b_out     = (const float*)d_in[13];
    float* logits = (float*)d_out;

    char* base = (char*)d_ws;
    size_t off = 0;
    auto alloc = [&](size_t bytes) {
        char* p = base + off;
        off += (bytes + 255) & ~(size_t)255;
        return p;
    };
    unsigned short* x_bf    = (unsigned short*)alloc((size_t)M * DIN * 2);
    unsigned short* Wt_in   = (unsigned short*)alloc((size_t)Hh * DIN * 2);
    unsigned short* Wt_ip   = (unsigned short*)alloc((size_t)(2 * DI) * Hh * 2);
    unsigned short* Wt_op   = (unsigned short*)alloc((size_t)Hh * DI * 2);
    unsigned short* xpw_t   = (unsigned short*)alloc((size_t)96 * DI * 2);
    unsigned short* dtw_t   = (unsigned short*)alloc((size_t)DI * DTR * 2);
    unsigned short* h_bf    = (unsigned short*)alloc((size_t)M * Hh * 2);
    unsigned short* xz_bf   = (unsigned short*)alloc((size_t)M * 2 * DI * 2);
    float*          xc      = (float*)alloc((size_t)M * DI * 4);       // | P14 alias (13.1MB)
    float*          delta   = (float*)alloc((size_t)M * DI * 4);       // | P8 alias
    unsigned short* xc_bf   = (unsigned short*)alloc((size_t)M * DI * 2);
    float*          proj_f  = (float*)alloc((size_t)M * 96 * 4);
    unsigned short* proj_bf = (unsigned short*)alloc((size_t)M * 96 * 2);
    unsigned short* y_bf    = (unsigned short*)alloc((size_t)M * DI * 2);
    unsigned short* out_bf  = (unsigned short*)alloc((size_t)M * Hh * 2);

    unsigned short* P14 = (unsigned short*)xc;   // bf16 [4][1600][1024] = 13.1MB
    float*          P8  = delta;                 // fp32 [8][1600][96]  = 4.9MB
    float*          Pbuf = (float*)x_bf;         // scan chunk buffers (x_bf dead)
    float*          Sbuf = Pbuf + (size_t)(NCH - 1) * Bb * DI * Nst;

    dim3 blk(256), blk5(512);

    // 0) fused prologue: convert + 5 transposes
    prep_kernel<<<dim3(22208), blk, 0, stream>>>(
        x, x_bf, W_in, Wt_in, in_proj_w, Wt_ip, out_proj, Wt_op,
        x_proj_w, xpw_t, dt_proj_w, dtw_t);

    // 1) h = x @ W_in + b_in   [1600,6144]@[6144,1024], split-K 4 -> 224 blocks
    gemm_deep<true, false, false><<<dim3(7, Hh / 128, 4), blk5, 0, stream>>>(
        x_bf, DIN, Wt_in, DIN, nullptr, nullptr, P14, M, Hh, DIN / 4);
    reduce_split_bf<4, true><<<dim3((M * Hh) / 2048), blk, 0, stream>>>(
        P14, b_in, h_bf, M * Hh, Hh - 1);

    // 2) xz = h @ in_proj_w    [1600,1024]@[1024,4096], 224 blocks, no split
    gemm_deep<false, false, true><<<dim3(7, (2 * DI) / 128, 1), blk5, 0, stream>>>(
        h_bf, Hh, Wt_ip, Hh, nullptr, xz_bf, nullptr, M, 2 * DI, Hh);

    // 3) xc = silu(conv(xm) + conv_b)  -> fp32 + bf16
    conv_silu_kernel<<<dim3((Bb * Ll * DI) / 256), blk, 0, stream>>>(
        xz_bf, conv_w, conv_b, xc, xc_bf);

    // 4) proj = xc @ x_proj_w  [1600,2048]@[2048,96], split-K 8 -> 104 blocks
    gemm_mfma<true, false, false, 0, false, false><<<dim3(13, 1, 8), blk, 0, stream>>>(
        xc_bf, DI, xpw_t, DI, nullptr, nullptr, nullptr, P8, M, 96, DI / 8);
    reduce_split<8, false, 0, true, true><<<dim3((M * 96) / 1024), blk, 0, stream>>>(
        P8, nullptr, proj_f, proj_bf, M * 96, 0);

    // 5) delta = softplus(proj[:,:64] @ dt_proj_w + dt_proj_b)  [1600,64]@[64,2048]
    gemm_mfma<false, false, true, 1, true, false><<<dim3(13, DI / 128, 1), blk, 0, stream>>>(
        proj_bf, 96, dtw_t, DTR, dt_proj_b, delta, nullptr, nullptr, M, DI, DTR);

    // 6) chunked selective scan: pass1 (chunks 0..2) then pass2 (all 4)
    scan_part1<<<dim3(DI / 64, Bb, NCH - 1), blk, 0, stream>>>(
        delta, xc, proj_f, A_log, Pbuf, Sbuf);
    scan_part2<<<dim3(DI / 64, Bb, NCH), blk, 0, stream>>>(
        delta, xc, xz_bf, proj_f, A_log, Dv, Pbuf, Sbuf, y_bf);

    // 7) out = y @ out_proj_w  [1600,2048]@[2048,1024], split-K 4 -> 224 blocks
    gemm_deep<true, false, false><<<dim3(7, Hh / 128, 4), blk5, 0, stream>>>(
        y_bf, DI, Wt_op, DI, nullptr, nullptr, P14, M, Hh, DI / 4);
    reduce_split_bf<4, false><<<dim3((M * Hh) / 2048), blk, 0, stream>>>(
        P14, nullptr, out_bf, M * Hh, 0);

    // 8) logits = out @ W_out + b_out  [1600,1024]@[1024,16]
    gemm_n16<<<dim3(M), blk, 0, stream>>>(out_bf, W_out, b_out, logits, Hh);
}

// Round 17
// 224.383 us; speedup vs baseline: 1.2776x; 1.0546x over previous
//
#include <hip/hip_runtime.h>
#include <hip/hip_bf16.h>
#include <stdint.h>

// Problem constants
constexpr int Bb  = 16;
constexpr int Ll  = 100;
constexpr int DIN = 6144;
constexpr int Hh  = 1024;
constexpr int DI  = 2048;
constexpr int Nst = 16;
constexpr int DTR = 64;
constexpr int Kc  = 4;
constexpr int NC  = 16;
constexpr int M   = Bb * Ll;   // 1600 tokens
constexpr int NCH = 4;         // scan L-chunks
constexpr int CL  = Ll / NCH;  // 25

typedef __attribute__((ext_vector_type(8))) short short8;
typedef __attribute__((ext_vector_type(4))) float floatx4;

__device__ __forceinline__ float bf2f(unsigned short u) {
    union { uint32_t b; float f; } x; x.b = ((uint32_t)u) << 16; return x.f;
}
__device__ __forceinline__ unsigned short f2bf(float f) {
    union { float f; uint32_t b; } x; x.f = f;
    uint32_t r = x.b + 0x7FFF + ((x.b >> 16) & 1);   // RNE
    return (unsigned short)(r >> 16);
}
__device__ __forceinline__ float fast_silu(float x) {
    return x / (1.f + __expf(-x));
}

// ---------------------------------------------------------------------------
// Fused prologue: one kernel, sectioned grid (saves 5 serial launch gaps).
// ---------------------------------------------------------------------------
__global__ __launch_bounds__(256) void prep_kernel(
    const float* __restrict__ x, unsigned short* __restrict__ x_bf,
    const float* __restrict__ W_in, unsigned short* __restrict__ Wt_in,
    const float* __restrict__ W_ip, unsigned short* __restrict__ Wt_ip,
    const float* __restrict__ W_op, unsigned short* __restrict__ Wt_op,
    const float* __restrict__ xpw,  unsigned short* __restrict__ xpw_t,
    const float* __restrict__ dtw,  unsigned short* __restrict__ dtw_t)
{
    __shared__ float t[32][33];
    int b = blockIdx.x;

    if (b < 9600) {                       // convert x
        int i = (b * 256 + threadIdx.x) * 4;
        float4 v = *(const float4*)&x[i];
        x_bf[i + 0] = f2bf(v.x);
        x_bf[i + 1] = f2bf(v.y);
        x_bf[i + 2] = f2bf(v.z);
        x_bf[i + 3] = f2bf(v.w);
        return;
    }
    const float* in; unsigned short* out; int K, N, bid;
    if      (b < 15744) { in = W_in; out = Wt_in; K = DIN; N = Hh;     bid = b - 9600;  }
    else if (b < 19840) { in = W_ip; out = Wt_ip; K = Hh;  N = 2 * DI; bid = b - 15744; }
    else if (b < 21888) { in = W_op; out = Wt_op; K = DI;  N = Hh;     bid = b - 19840; }
    else if (b < 22080) { in = xpw;  out = xpw_t; K = DI;  N = 96;     bid = b - 21888; }
    else                { in = dtw;  out = dtw_t; K = DTR; N = DI;     bid = b - 22080; }

    int kx = bid % (K / 32), ny = bid / (K / 32);
    int k0 = kx * 32, n0 = ny * 32;
    int tx = threadIdx.x & 31, ty = threadIdx.x >> 5;
    #pragma unroll
    for (int i = 0; i < 4; i++)
        t[ty + i * 8][tx] = in[(size_t)(k0 + ty + i * 8) * N + n0 + tx];
    __syncthreads();
    #pragma unroll
    for (int i = 0; i < 4; i++)
        out[(size_t)(n0 + ty + i * 8) * K + k0 + tx] = f2bf(t[tx][ty + i * 8]);
}

// ---------------------------------------------------------------------------
// Deep-pipelined bf16 MFMA GEMM (big GEMMs 1/2/7): BM=256, BN=128, BK=64;
// 512 thr = 8 waves (4m x 2n), wave tile 64x64. 3-buffer LDS ring (144 KB),
// 2-deep counted-vmcnt prefetch, swizzled staging (R11), LDS-staged
// coalesced epilogue, early buffer release (R13-proven config).
// ---------------------------------------------------------------------------
template<bool SPLIT, bool BIAS, bool W16>
__global__ __launch_bounds__(512) void gemm_deep(
    const unsigned short* __restrict__ A, int lda,    // [Md x lda]
    const unsigned short* __restrict__ Bt, int ldb,   // [Nd x ldb]
    const float* __restrict__ bias,                   // [Nd]
    unsigned short* __restrict__ C16,                 // final bf16 out
    unsigned short* __restrict__ Cpart,               // bf16 partials
    int Md, int Nd, int Kslab)
{
    __shared__ short As[3 * 256 * 64];   // 96 KB
    __shared__ short Bs[3 * 128 * 64];   // 48 KB

    // XCD-aware block remap
    const int nx = gridDim.x, ny = gridDim.y, nz = gridDim.z;
    const int nb = nx * ny * nz;
    int id = blockIdx.x + nx * (blockIdx.y + ny * blockIdx.z);
    int bx, by, bz;
    if ((nb & 7) == 0) {
        int swz = (id & 7) * (nb >> 3) + (id >> 3);
        bx = swz % nx;
        int rem = swz / nx;
        by = rem % ny;
        bz = rem / ny;
    } else {
        bx = blockIdx.x; by = blockIdx.y; bz = blockIdx.z;
    }

    const int tid  = threadIdx.x;
    const int lane = tid & 63;
    const int wid  = tid >> 6;      // 0..7
    const int wr   = wid >> 1;      // 0..3 (m)
    const int wc   = wid & 1;       // 0..1 (n)
    const int l15  = lane & 15;
    const int kg   = lane >> 4;
    const int gsw  = l15 & 7;       // ds_read swizzle term
    const int m0   = bx * 256;
    const int n0   = by * 128;
    const int kbeg = SPLIT ? bz * Kslab : 0;

    floatx4 acc[4][4];
    #pragma unroll
    for (int m = 0; m < 4; m++)
        #pragma unroll
        for (int n = 0; n < 4; n++)
            acc[m][n] = (floatx4){0.f, 0.f, 0.f, 0.f};

    auto stage = [&](int buf, int k0) {
        // A: 2048 cells (256 rows x 8 g-chunks of 16B), swizzled source
        #pragma unroll
        for (int j = 0; j < 4; j++) {
            int c = j * 512 + tid;
            int row = c >> 3, gl = c & 7;
            int gg = gl ^ (row & 7);
            int grow = m0 + row; grow = grow < Md ? grow : Md - 1;
            const __attribute__((address_space(1))) short* src =
                (const __attribute__((address_space(1))) short*)(A + (size_t)grow * lda + k0 + gg * 8);
            __builtin_amdgcn_global_load_lds(
                (const __attribute__((address_space(1))) void*)src,
                (__attribute__((address_space(3))) void*)&As[(buf * 2048 + c) * 8], 16, 0, 0);
        }
        // B: 1024 cells (128 rows x 8 g-chunks)
        #pragma unroll
        for (int j = 0; j < 2; j++) {
            int c = j * 512 + tid;
            int row = c >> 3, gl = c & 7;
            int gg = gl ^ (row & 7);
            int brow = n0 + row; brow = brow < Nd ? brow : Nd - 1;
            const __attribute__((address_space(1))) short* src =
                (const __attribute__((address_space(1))) short*)(Bt + (size_t)brow * ldb + k0 + gg * 8);
            __builtin_amdgcn_global_load_lds(
                (const __attribute__((address_space(1))) void*)src,
                (__attribute__((address_space(3))) void*)&Bs[(buf * 1024 + c) * 8], 16, 0, 0);
        }
    };

    const int nt = Kslab >> 6;
    stage(0, kbeg);
    stage(1, kbeg + 64);

    for (int t = 0; t < nt; t++) {
        const int cur = t % 3;
        if (t + 2 < nt) {
            stage((t + 2) % 3, kbeg + (t + 2) * 64);
            asm volatile("s_waitcnt vmcnt(12)" ::: "memory");  // tile t landed
        } else if (t + 1 < nt) {
            asm volatile("s_waitcnt vmcnt(6)" ::: "memory");
        } else {
            asm volatile("s_waitcnt vmcnt(0)" ::: "memory");
        }
        __builtin_amdgcn_s_barrier();       // tile t staged (all waves)
        __builtin_amdgcn_sched_barrier(0);

        short8 a[2][4], bfr[2][4];
        #pragma unroll
        for (int kk = 0; kk < 2; kk++) {
            #pragma unroll
            for (int m = 0; m < 4; m++) {
                int row = wr * 64 + m * 16 + l15;
                int gs  = (kk * 4 + kg) ^ gsw;
                a[kk][m] = *(const short8*)&As[(cur * 2048 + row * 8 + gs) * 8];
            }
            #pragma unroll
            for (int n = 0; n < 4; n++) {
                int row = wc * 64 + n * 16 + l15;
                int gs  = (kk * 4 + kg) ^ gsw;
                bfr[kk][n] = *(const short8*)&Bs[(cur * 1024 + row * 8 + gs) * 8];
            }
        }
        asm volatile("s_waitcnt lgkmcnt(0)" ::: "memory");   // reads in regs
        __builtin_amdgcn_sched_barrier(0);
        __builtin_amdgcn_s_barrier();       // buffer cur free for stage(t+3)
        __builtin_amdgcn_sched_barrier(0);

        __builtin_amdgcn_s_setprio(1);
        #pragma unroll
        for (int kk = 0; kk < 2; kk++)
            #pragma unroll
            for (int m = 0; m < 4; m++)
                #pragma unroll
                for (int n = 0; n < 4; n++)
                    acc[m][n] = __builtin_amdgcn_mfma_f32_16x16x32_bf16(a[kk][m], bfr[kk][n], acc[m][n], 0, 0, 0);
        __builtin_amdgcn_s_setprio(0);
    }

    // ---- LDS-staged coalesced epilogue ----
    unsigned short* Cs = (unsigned short*)As;   // [256][136] bf16 = 69.6 KB
    #pragma unroll
    for (int n = 0; n < 4; n++) {
        int col = wc * 64 + n * 16 + l15;
        float bv = BIAS ? bias[n0 + col] : 0.f;
        #pragma unroll
        for (int m = 0; m < 4; m++) {
            #pragma unroll
            for (int q = 0; q < 4; q++) {
                int row = wr * 64 + m * 16 + kg * 4 + q;
                Cs[row * 136 + col] = f2bf(acc[m][n][q] + bv);
            }
        }
    }
    __syncthreads();
    #pragma unroll
    for (int j = 0; j < 8; j++) {
        int c = j * 512 + tid;          // 16B cell; 16 cells/row
        int row = c >> 4, cc = c & 15;
        int grow = m0 + row;
        if (grow >= Md) continue;
        short8 v = *(const short8*)&Cs[row * 136 + cc * 8];
        if (SPLIT)
            *(short8*)&Cpart[(size_t)bz * Md * Nd + (size_t)grow * Nd + n0 + cc * 8] = v;
        else if (W16)
            *(short8*)&C16[(size_t)grow * Nd + n0 + cc * 8] = v;
    }
}

// ---------------------------------------------------------------------------
// Swizzled 128x128 BK=64 dbuf MFMA GEMM — small GEMMs (proj, delta).
// ---------------------------------------------------------------------------
template<bool SPLIT, bool PARTBF, bool BIAS, int ACT, bool W32, bool W16>
__global__ __launch_bounds__(256) void gemm_mfma(
    const unsigned short* __restrict__ A, int lda,
    const unsigned short* __restrict__ Bt, int ldb,
    const float* __restrict__ bias,
    float* __restrict__ C32,
    unsigned short* __restrict__ C16,
    void* __restrict__ Cpart,
    int Md, int Nd, int Kslab)
{
    __shared__ short As[2][128 * 64];
    __shared__ short Bs[2][128 * 64];

    const int nx = gridDim.x, ny = gridDim.y, nz = gridDim.z;
    const int nb = nx * ny * nz;
    int id = blockIdx.x + nx * (blockIdx.y + ny * blockIdx.z);
    int bx, by, bz;
    if ((nb & 7) == 0) {
        int swz = (id & 7) * (nb >> 3) + (id >> 3);
        bx = swz % nx;
        int rem = swz / nx;
        by = rem % ny;
        bz = rem / ny;
    } else {
        bx = blockIdx.x; by = blockIdx.y; bz = blockIdx.z;
    }

    const int tid  = threadIdx.x;
    const int lane = tid & 63;
    const int wid  = tid >> 6;
    const int wr   = wid >> 1;
    const int wc   = wid & 1;
    const int l15  = lane & 15;
    const int kg   = lane >> 4;
    const int gsw  = l15 & 7;
    const int m0   = bx * 128;
    const int n0   = by * 128;
    const int kbeg = SPLIT ? bz * Kslab : 0;

    floatx4 acc[4][4];
    #pragma unroll
    for (int m = 0; m < 4; m++)
        #pragma unroll
        for (int n = 0; n < 4; n++)
            acc[m][n] = (floatx4){0.f, 0.f, 0.f, 0.f};

    auto stage = [&](int buf, int k0) {
        #pragma unroll
        for (int j = 0; j < 4; j++) {
            int c = j * 256 + tid;
            int row = c >> 3, gl = c & 7;
            int gg = gl ^ (row & 7);
            int grow = m0 + row; grow = grow < Md ? grow : Md - 1;
            const __attribute__((address_space(1))) short* src =
                (const __attribute__((address_space(1))) short*)(A + (size_t)grow * lda + k0 + gg * 8);
            __builtin_amdgcn_global_load_lds(
                (const __attribute__((address_space(1))) void*)src,
                (__attribute__((address_space(3))) void*)&As[buf][c * 8], 16, 0, 0);
        }
        #pragma unroll
        for (int j = 0; j < 4; j++) {
            int c = j * 256 + tid;
            int row = c >> 3, gl = c & 7;
            int gg = gl ^ (row & 7);
            int brow = n0 + row; brow = brow < Nd ? brow : Nd - 1;
            const __attribute__((address_space(1))) short* src =
                (const __attribute__((address_space(1))) short*)(Bt + (size_t)brow * ldb + k0 + gg * 8);
            __builtin_amdgcn_global_load_lds(
                (const __attribute__((address_space(1))) void*)src,
                (__attribute__((address_space(3))) void*)&Bs[buf][c * 8], 16, 0, 0);
        }
    };

    stage(0, kbeg);
    asm volatile("s_waitcnt vmcnt(0)" ::: "memory");
    __builtin_amdgcn_s_barrier();
    __builtin_amdgcn_sched_barrier(0);

    const int nt = Kslab >> 6;
    for (int t = 0; t < nt; t++) {
        const int cur = t & 1;
        if (t + 1 < nt) {
            stage(cur ^ 1, kbeg + (t + 1) * 64);
            asm volatile("s_waitcnt vmcnt(8)" ::: "memory");
        } else {
            asm volatile("s_waitcnt vmcnt(0)" ::: "memory");
        }
        __builtin_amdgcn_s_barrier();
        __builtin_amdgcn_sched_barrier(0);

        short8 a[2][4], bfr[2][4];
        #pragma unroll
        for (int kk = 0; kk < 2; kk++) {
            #pragma unroll
            for (int m = 0; m < 4; m++) {
                int row = wr * 64 + m * 16 + l15;
                int gs  = (kk * 4 + kg) ^ gsw;
                a[kk][m] = *(const short8*)&As[cur][(row * 8 + gs) * 8];
            }
            #pragma unroll
            for (int n = 0; n < 4; n++) {
                int row = wc * 64 + n * 16 + l15;
                int gs  = (kk * 4 + kg) ^ gsw;
                bfr[kk][n] = *(const short8*)&Bs[cur][(row * 8 + gs) * 8];
            }
        }
        __builtin_amdgcn_s_setprio(1);
        #pragma unroll
        for (int kk = 0; kk < 2; kk++)
            #pragma unroll
            for (int m = 0; m < 4; m++)
                #pragma unroll
                for (int n = 0; n < 4; n++)
                    acc[m][n] = __builtin_amdgcn_mfma_f32_16x16x32_bf16(a[kk][m], bfr[kk][n], acc[m][n], 0, 0, 0);
        __builtin_amdgcn_s_setprio(0);
        __builtin_amdgcn_sched_barrier(0);
        __builtin_amdgcn_s_barrier();
    }

    if (SPLIT) {
        #pragma unroll
        for (int n = 0; n < 4; n++) {
            int col = n0 + wc * 64 + n * 16 + l15;
            if (col >= Nd) continue;
            #pragma unroll
            for (int m = 0; m < 4; m++)
                #pragma unroll
                for (int q = 0; q < 4; q++) {
                    int row = m0 + wr * 64 + m * 16 + kg * 4 + q;
                    if (row >= Md) continue;
                    size_t ix = (size_t)bz * Md * Nd + (size_t)row * Nd + col;
                    if (PARTBF) ((unsigned short*)Cpart)[ix] = f2bf(acc[m][n][q]);
                    else        ((float*)Cpart)[ix] = acc[m][n][q];
                }
        }
    } else {
        #pragma unroll
        for (int n = 0; n < 4; n++) {
            int col = n0 + wc * 64 + n * 16 + l15;
            if (col >= Nd) continue;
            float bv = BIAS ? bias[col] : 0.f;
            #pragma unroll
            for (int m = 0; m < 4; m++)
                #pragma unroll
                for (int q = 0; q < 4; q++) {
                    int row = m0 + wr * 64 + m * 16 + kg * 4 + q;
                    if (row >= Md) continue;
                    float v = acc[m][n][q] + bv;
                    if (ACT == 1) v = fmaxf(v, 0.f) + log1pf(expf(-fabsf(v)));  // softplus
                    if (W32) C32[(size_t)row * Nd + col] = v;
                    if (W16) C16[(size_t)row * Nd + col] = f2bf(v);
                }
        }
    }
}

// ---------------------------------------------------------------------------
// Sum S fp32 split-K partials + bias/act -> fp32/bf16. total % 1024 == 0.
// ---------------------------------------------------------------------------
template<int S, bool BIAS, int ACT, bool W32, bool W16>
__global__ __launch_bounds__(256) void reduce_split(
    const float* __restrict__ P, const float* __restrict__ bias,
    float* __restrict__ C32, unsigned short* __restrict__ C16,
    int total, int nmask)
{
    int i = (blockIdx.x * 256 + threadIdx.x) * 4;
    float4 v = *(const float4*)&P[i];
    #pragma unroll
    for (int s = 1; s < S; s++) {
        float4 p = *(const float4*)&P[(size_t)s * total + i];
        v.x += p.x; v.y += p.y; v.z += p.z; v.w += p.w;
    }
    float r[4] = {v.x, v.y, v.z, v.w};
    #pragma unroll
    for (int j = 0; j < 4; j++) {
        float t = r[j];
        if (BIAS) t += bias[(i + j) & nmask];
        if (ACT == 1) t = fmaxf(t, 0.f) + log1pf(expf(-fabsf(t)));
        if (W32) C32[i + j] = t;
        if (W16) C16[i + j] = f2bf(t);
    }
}

// ---------------------------------------------------------------------------
// Sum S bf16 split-K partials + bias -> bf16. total % 2048 == 0.
// ---------------------------------------------------------------------------
template<int S, bool BIAS>
__global__ __launch_bounds__(256) void reduce_split_bf(
    const unsigned short* __restrict__ P, const float* __restrict__ bias,
    unsigned short* __restrict__ C16, int total, int nmask)
{
    int i = (blockIdx.x * 256 + threadIdx.x) * 8;
    float r[8] = {};
    #pragma unroll
    for (int s = 0; s < S; s++) {
        short8 p = *(const short8*)&P[(size_t)s * total + i];
        #pragma unroll
        for (int j = 0; j < 8; j++) r[j] += bf2f((unsigned short)p[j]);
    }
    short8 o;
    #pragma unroll
    for (int j = 0; j < 8; j++) {
        float t = r[j];
        if (BIAS) t += bias[(i + j) & nmask];
        o[j] = (short)f2bf(t);
    }
    *(short8*)&C16[i] = o;
}

// ---------------------------------------------------------------------------
// Causal depthwise conv (K=4) + bias + SiLU; xz is bf16 with row stride 2*DI.
// ---------------------------------------------------------------------------
__global__ __launch_bounds__(256) void conv_silu_kernel(
    const unsigned short* __restrict__ xz, const float* __restrict__ conv_w,
    const float* __restrict__ conv_b, float* __restrict__ xc,
    unsigned short* __restrict__ xc_bf)
{
    int idx = blockIdx.x * 256 + threadIdx.x;
    if (idx >= Bb * Ll * DI) return;
    int d  = idx & (DI - 1);
    int bl = idx >> 11;
    int l  = bl % Ll;

    float acc = conv_b[d];
    #pragma unroll
    for (int k = 0; k < Kc; k++) {
        int ls = l + k - (Kc - 1);
        if (ls >= 0)
            acc = fmaf(conv_w[d * Kc + k], bf2f(xz[(size_t)(bl + ls - l) * (2 * DI) + d]), acc);
    }
    float s = fast_silu(acc);
    xc[idx] = s;
    xc_bf[idx] = f2bf(s);
}

// ---------------------------------------------------------------------------
// Chunked selective scan, 2-pass (R13-proven): part1 chunks 0..2 (P/S only,
// light), part2 all 4 chunks (h_start fold + recurrence + y emit).
// ---------------------------------------------------------------------------
__global__ __launch_bounds__(256) void scan_part1(
    const float* __restrict__ delta, const float* __restrict__ xc,
    const float* __restrict__ proj,  const float* __restrict__ A_log,
    float* __restrict__ Pbuf, float* __restrict__ Sbuf)
{
    const int t    = threadIdx.x;
    const int nq   = t & 3;
    const int dloc = t >> 2;
    const int d    = blockIdx.x * 64 + dloc;
    const int b    = blockIdx.y;
    const int c    = blockIdx.z;

    float4 Alq = *(const float4*)&A_log[(size_t)d * Nst + nq * 4];
    float Ar0 = -expf(Alq.x), Ar1 = -expf(Alq.y), Ar2 = -expf(Alq.z), Ar3 = -expf(Alq.w);

    float h0 = 0.f, h1 = 0.f, h2 = 0.f, h3 = 0.f;
    float sdl = 0.f;

    for (int l = c * CL; l < (c + 1) * CL; l++) {
        size_t bl = (size_t)b * Ll + l;
        float dl  = delta[bl * DI + d];
        float xcv = xc[bl * DI + d];
        float dx  = dl * xcv;
        float4 Bv = *(const float4*)&proj[bl * (DTR + 2 * Nst) + DTR + nq * 4];

        h0 = fmaf(__expf(dl * Ar0), h0, dx * Bv.x);
        h1 = fmaf(__expf(dl * Ar1), h1, dx * Bv.y);
        h2 = fmaf(__expf(dl * Ar2), h2, dx * Bv.z);
        h3 = fmaf(__expf(dl * Ar3), h3, dx * Bv.w);
        sdl += dl;
    }

    size_t o = (((size_t)c * Bb + b) * DI + d) * Nst + nq * 4;
    *(float4*)&Pbuf[o] = (float4){__expf(sdl * Ar0), __expf(sdl * Ar1),
                                  __expf(sdl * Ar2), __expf(sdl * Ar3)};
    *(float4*)&Sbuf[o] = (float4){h0, h1, h2, h3};
}

__global__ __launch_bounds__(256) void scan_part2(
    const float* __restrict__ delta, const float* __restrict__ xc,
    const unsigned short* __restrict__ xz, const float* __restrict__ proj,
    const float* __restrict__ A_log, const float* __restrict__ Dv,
    const float* __restrict__ Pbuf, const float* __restrict__ Sbuf,
    unsigned short* __restrict__ y)
{
    const int t    = threadIdx.x;
    const int nq   = t & 3;
    const int dloc = t >> 2;
    const int d    = blockIdx.x * 64 + dloc;
    const int b    = blockIdx.y;
    const int c    = blockIdx.z;

    float4 Alq = *(const float4*)&A_log[(size_t)d * Nst + nq * 4];
    float Ar0 = -expf(Alq.x), Ar1 = -expf(Alq.y), Ar2 = -expf(Alq.z), Ar3 = -expf(Alq.w);
    const float Dd = Dv[d];

    float h0 = 0.f, h1 = 0.f, h2 = 0.f, h3 = 0.f;
    for (int cc = 0; cc < c; cc++) {
        size_t o = (((size_t)cc * Bb + b) * DI + d) * Nst + nq * 4;
        float4 Pv = *(const float4*)&Pbuf[o];
        float4 Sv = *(const float4*)&Sbuf[o];
        h0 = fmaf(Pv.x, h0, Sv.x);
        h1 = fmaf(Pv.y, h1, Sv.y);
        h2 = fmaf(Pv.z, h2, Sv.z);
        h3 = fmaf(Pv.w, h3, Sv.w);
    }

    for (int l = c * CL; l < (c + 1) * CL; l++) {
        size_t bl = (size_t)b * Ll + l;
        float dl  = delta[bl * DI + d];
        float xcv = xc[bl * DI + d];
        float zv  = bf2f(xz[bl * (2 * DI) + DI + d]);
        float dx  = dl * xcv;
        const float* p = proj + bl * (DTR + 2 * Nst);
        float4 Bv = *(const float4*)&p[DTR + nq * 4];
        float4 Cv = *(const float4*)&p[DTR + Nst + nq * 4];

        h0 = fmaf(__expf(dl * Ar0), h0, dx * Bv.x);
        h1 = fmaf(__expf(dl * Ar1), h1, dx * Bv.y);
        h2 = fmaf(__expf(dl * Ar2), h2, dx * Bv.z);
        h3 = fmaf(__expf(dl * Ar3), h3, dx * Bv.w);

        float yac = h0 * Cv.x + h1 * Cv.y + h2 * Cv.z + h3 * Cv.w;
        yac += __shfl_xor(yac, 1);
        yac += __shfl_xor(yac, 2);

        if (nq == 0) {
            float yv = yac + Dd * xcv;
            yv *= fast_silu(zv);
            y[bl * DI + d] = f2bf(yv);
        }
    }
}

// ---------------------------------------------------------------------------
// logits[M,16] = out_bf[M,1024] @ W_out[1024,16] + b_out
// R17: vectorized A loads — thread (c=t&15, kgrp=t>>4) loads 8x short8
// (16B contiguous chunks; wave = 4 kgrp-groups x c-broadcast -> coalesced)
// instead of 64 scalar bf16 loads at 32B stride. fp32 reassociation only.
// ---------------------------------------------------------------------------
__global__ __launch_bounds__(256) void gemm_n16(
    const unsigned short* __restrict__ A, const float* __restrict__ W,
    const float* __restrict__ bias, float* __restrict__ C, int Kd)
{
    int m    = blockIdx.x;
    int t    = threadIdx.x;
    int c    = t & 15;
    int kgrp = t >> 4;               // 0..15
    const unsigned short* a = A + (size_t)m * Kd;

    float acc = 0.f;
    #pragma unroll
    for (int j = 0; j < 8; j++) {    // Kd = 1024 = 16 kgrps * 8 j * 8 elems
        int k0 = kgrp * 8 + j * 128;
        short8 v = *(const short8*)&a[k0];
        #pragma unroll
        for (int e = 0; e < 8; e++)
            acc = fmaf(bf2f((unsigned short)v[e]), W[(k0 + e) * NC + c], acc);
    }

    __shared__ float red[256];
    red[t] = acc;
    __syncthreads();
    #pragma unroll
    for (int s = 128; s >= 16; s >>= 1) {
        if (t < s) red[t] += red[t + s];
        __syncthreads();
    }
    if (t < 16) C[(size_t)m * NC + t] = red[t] + bias[t];
}

// ---------------------------------------------------------------------------
extern "C" void kernel_launch(void* const* d_in, const int* in_sizes, int n_in,
                              void* d_out, int out_size, void* d_ws, size_t ws_size,
                              hipStream_t stream) {
    const float* x         = (const float*)d_in[0];
    const float* W_in      = (const float*)d_in[1];
    const float* b_in      = (const float*)d_in[2];
    const float* in_proj_w = (const float*)d_in[3];
    const float* conv_w    = (const float*)d_in[4];
    const float* conv_b    = (const float*)d_in[5];
    const float* x_proj_w  = (const float*)d_in[6];
    const float* dt_proj_w = (const float*)d_in[7];
    const float* dt_proj_b = (const float*)d_in[8];
    const float* A_log     = (const float*)d_in[9];
    const float* Dv        = (const float*)d_in[10];
    const float* out_proj  = (const float*)d_in[11];
    const float* W_out     = (const float*)d_in[12];
    const float* b_out     = (const float*)d_in[13];
    float* logits = (float*)d_out;

    char* base = (char*)d_ws;
    size_t off = 0;
    auto alloc = [&](size_t bytes) {
        char* p = base + off;
        off += (bytes + 255) & ~(size_t)255;
        return p;
    };
    unsigned short* x_bf    = (unsigned short*)alloc((size_t)M * DIN * 2);
    unsigned short* Wt_in   = (unsigned short*)alloc((size_t)Hh * DIN * 2);
    unsigned short* Wt_ip   = (unsigned short*)alloc((size_t)(2 * DI) * Hh * 2);
    unsigned short* Wt_op   = (unsigned short*)alloc((size_t)Hh * DI * 2);
    unsigned short* xpw_t   = (unsigned short*)alloc((size_t)96 * DI * 2);
    unsigned short* dtw_t   = (unsigned short*)alloc((size_t)DI * DTR * 2);
    unsigned short* h_bf    = (unsigned short*)alloc((size_t)M * Hh * 2);
    unsigned short* xz_bf   = (unsigned short*)alloc((size_t)M * 2 * DI * 2);
    float*          xc      = (float*)alloc((size_t)M * DI * 4);       // | P14 alias (13.1MB)
    float*          delta   = (float*)alloc((size_t)M * DI * 4);       // | P8 alias
    unsigned short* xc_bf   = (unsigned short*)alloc((size_t)M * DI * 2);
    float*          proj_f  = (float*)alloc((size_t)M * 96 * 4);
    unsigned short* proj_bf = (unsigned short*)alloc((size_t)M * 96 * 2);
    unsigned short* y_bf    = (unsigned short*)alloc((size_t)M * DI * 2);
    unsigned short* out_bf  = (unsigned short*)alloc((size_t)M * Hh * 2);

    unsigned short* P14 = (unsigned short*)xc;   // bf16 [4][1600][1024] = 13.1MB
    float*          P8  = delta;                 // fp32 [8][1600][96]  = 4.9MB
    float*          Pbuf = (float*)x_bf;         // scan chunk buffers (x_bf dead)
    float*          Sbuf = Pbuf + (size_t)(NCH - 1) * Bb * DI * Nst;

    dim3 blk(256), blk5(512);

    // 0) fused prologue: convert + 5 transposes
    prep_kernel<<<dim3(22208), blk, 0, stream>>>(
        x, x_bf, W_in, Wt_in, in_proj_w, Wt_ip, out_proj, Wt_op,
        x_proj_w, xpw_t, dt_proj_w, dtw_t);

    // 1) h = x @ W_in + b_in   [1600,6144]@[6144,1024], split-K 4 -> 224 blocks
    gemm_deep<true, false, false><<<dim3(7, Hh / 128, 4), blk5, 0, stream>>>(
        x_bf, DIN, Wt_in, DIN, nullptr, nullptr, P14, M, Hh, DIN / 4);
    reduce_split_bf<4, true><<<dim3((M * Hh) / 2048), blk, 0, stream>>>(
        P14, b_in, h_bf, M * Hh, Hh - 1);

    // 2) xz = h @ in_proj_w    [1600,1024]@[1024,4096], 224 blocks, no split
    gemm_deep<false, false, true><<<dim3(7, (2 * DI) / 128, 1), blk5, 0, stream>>>(
        h_bf, Hh, Wt_ip, Hh, nullptr, xz_bf, nullptr, M, 2 * DI, Hh);

    // 3) xc = silu(conv(xm) + conv_b)  -> fp32 + bf16
    conv_silu_kernel<<<dim3((Bb * Ll * DI) / 256), blk, 0, stream>>>(
        xz_bf, conv_w, conv_b, xc, xc_bf);

    // 4) proj = xc @ x_proj_w  [1600,2048]@[2048,96], split-K 8 -> 104 blocks
    gemm_mfma<true, false, false, 0, false, false><<<dim3(13, 1, 8), blk, 0, stream>>>(
        xc_bf, DI, xpw_t, DI, nullptr, nullptr, nullptr, P8, M, 96, DI / 8);
    reduce_split<8, false, 0, true, true><<<dim3((M * 96) / 1024), blk, 0, stream>>>(
        P8, nullptr, proj_f, proj_bf, M * 96, 0);

    // 5) delta = softplus(proj[:,:64] @ dt_proj_w + dt_proj_b)  [1600,64]@[64,2048]
    gemm_mfma<false, false, true, 1, true, false><<<dim3(13, DI / 128, 1), blk, 0, stream>>>(
        proj_bf, 96, dtw_t, DTR, dt_proj_b, delta, nullptr, nullptr, M, DI, DTR);

    // 6) chunked selective scan: pass1 (chunks 0..2) then pass2 (all 4)
    scan_part1<<<dim3(DI / 64, Bb, NCH - 1), blk, 0, stream>>>(
        delta, xc, proj_f, A_log, Pbuf, Sbuf);
    scan_part2<<<dim3(DI / 64, Bb, NCH), blk, 0, stream>>>(
        delta, xc, xz_bf, proj_f, A_log, Dv, Pbuf, Sbuf, y_bf);

    // 7) out = y @ out_proj_w  [1600,2048]@[2048,1024], split-K 4 -> 224 blocks
    gemm_deep<true, false, false><<<dim3(7, Hh / 128, 4), blk5, 0, stream>>>(
        y_bf, DI, Wt_op, DI, nullptr, nullptr, P14, M, Hh, DI / 4);
    reduce_split_bf<4, false><<<dim3((M * Hh) / 2048), blk, 0, stream>>>(
        P14, nullptr, out_bf, M * Hh, 0);

    // 8) logits = out @ W_out + b_out  [1600,1024]@[1024,16]
    gemm_n16<<<dim3(M), blk, 0, stream>>>(out_bf, W_out, b_out, logits, Hh);
}

// Round 18
// 213.608 us; speedup vs baseline: 1.3420x; 1.0504x over previous
//
#include <hip/hip_runtime.h>
#include <hip/hip_bf16.h>
#include <stdint.h>

// Problem constants
constexpr int Bb  = 16;
constexpr int Ll  = 100;
constexpr int DIN = 6144;
constexpr int Hh  = 1024;
constexpr int DI  = 2048;
constexpr int Nst = 16;
constexpr int DTR = 64;
constexpr int Kc  = 4;
constexpr int NC  = 16;
constexpr int M   = Bb * Ll;   // 1600 tokens
constexpr int NCH = 4;         // scan L-chunks
constexpr int CL  = Ll / NCH;  // 25

typedef __attribute__((ext_vector_type(8))) short short8;
typedef __attribute__((ext_vector_type(4))) float floatx4;

__device__ __forceinline__ float bf2f(unsigned short u) {
    union { uint32_t b; float f; } x; x.b = ((uint32_t)u) << 16; return x.f;
}
__device__ __forceinline__ unsigned short f2bf(float f) {
    union { float f; uint32_t b; } x; x.f = f;
    uint32_t r = x.b + 0x7FFF + ((x.b >> 16) & 1);   // RNE
    return (unsigned short)(r >> 16);
}
__device__ __forceinline__ float fast_silu(float x) {
    return x / (1.f + __expf(-x));
}

// ---------------------------------------------------------------------------
// Fused prologue: one kernel, sectioned grid (saves serial launch gaps).
// R18: + conv_w transpose section [DI][4] -> [4][DI] (32 blocks).
// ---------------------------------------------------------------------------
__global__ __launch_bounds__(256) void prep_kernel(
    const float* __restrict__ x, unsigned short* __restrict__ x_bf,
    const float* __restrict__ W_in, unsigned short* __restrict__ Wt_in,
    const float* __restrict__ W_ip, unsigned short* __restrict__ Wt_ip,
    const float* __restrict__ W_op, unsigned short* __restrict__ Wt_op,
    const float* __restrict__ xpw,  unsigned short* __restrict__ xpw_t,
    const float* __restrict__ dtw,  unsigned short* __restrict__ dtw_t,
    const float* __restrict__ cw,   float* __restrict__ cw_t)
{
    __shared__ float t[32][33];
    int b = blockIdx.x;

    if (b < 9600) {                       // convert x
        int i = (b * 256 + threadIdx.x) * 4;
        float4 v = *(const float4*)&x[i];
        x_bf[i + 0] = f2bf(v.x);
        x_bf[i + 1] = f2bf(v.y);
        x_bf[i + 2] = f2bf(v.z);
        x_bf[i + 3] = f2bf(v.w);
        return;
    }
    if (b >= 22208) {                     // conv_w transpose [DI][4] -> [4][DI]
        int idx = (b - 22208) * 256 + threadIdx.x;   // 8192 elems
        int k = idx >> 11, d = idx & (DI - 1);
        cw_t[k * DI + d] = cw[d * Kc + k];
        return;
    }
    const float* in; unsigned short* out; int K, N, bid;
    if      (b < 15744) { in = W_in; out = Wt_in; K = DIN; N = Hh;     bid = b - 9600;  }
    else if (b < 19840) { in = W_ip; out = Wt_ip; K = Hh;  N = 2 * DI; bid = b - 15744; }
    else if (b < 21888) { in = W_op; out = Wt_op; K = DI;  N = Hh;     bid = b - 19840; }
    else if (b < 22080) { in = xpw;  out = xpw_t; K = DI;  N = 96;     bid = b - 21888; }
    else                { in = dtw;  out = dtw_t; K = DTR; N = DI;     bid = b - 22080; }

    int kx = bid % (K / 32), ny = bid / (K / 32);
    int k0 = kx * 32, n0 = ny * 32;
    int tx = threadIdx.x & 31, ty = threadIdx.x >> 5;
    #pragma unroll
    for (int i = 0; i < 4; i++)
        t[ty + i * 8][tx] = in[(size_t)(k0 + ty + i * 8) * N + n0 + tx];
    __syncthreads();
    #pragma unroll
    for (int i = 0; i < 4; i++)
        out[(size_t)(n0 + ty + i * 8) * K + k0 + tx] = f2bf(t[tx][ty + i * 8]);
}

// ---------------------------------------------------------------------------
// Deep-pipelined bf16 MFMA GEMM (big GEMMs 1/2/7): BM=256, BN=128, BK=64;
// 512 thr = 8 waves (4m x 2n), wave tile 64x64. 3-buffer LDS ring (144 KB),
// 2-deep counted-vmcnt prefetch, swizzled staging (R11), LDS-staged
// coalesced epilogue, early buffer release (R13-proven config).
// ---------------------------------------------------------------------------
template<bool SPLIT, bool BIAS, bool W16>
__global__ __launch_bounds__(512) void gemm_deep(
    const unsigned short* __restrict__ A, int lda,    // [Md x lda]
    const unsigned short* __restrict__ Bt, int ldb,   // [Nd x ldb]
    const float* __restrict__ bias,                   // [Nd]
    unsigned short* __restrict__ C16,                 // final bf16 out
    unsigned short* __restrict__ Cpart,               // bf16 partials
    int Md, int Nd, int Kslab)
{
    __shared__ short As[3 * 256 * 64];   // 96 KB
    __shared__ short Bs[3 * 128 * 64];   // 48 KB

    // XCD-aware block remap
    const int nx = gridDim.x, ny = gridDim.y, nz = gridDim.z;
    const int nb = nx * ny * nz;
    int id = blockIdx.x + nx * (blockIdx.y + ny * blockIdx.z);
    int bx, by, bz;
    if ((nb & 7) == 0) {
        int swz = (id & 7) * (nb >> 3) + (id >> 3);
        bx = swz % nx;
        int rem = swz / nx;
        by = rem % ny;
        bz = rem / ny;
    } else {
        bx = blockIdx.x; by = blockIdx.y; bz = blockIdx.z;
    }

    const int tid  = threadIdx.x;
    const int lane = tid & 63;
    const int wid  = tid >> 6;      // 0..7
    const int wr   = wid >> 1;      // 0..3 (m)
    const int wc   = wid & 1;       // 0..1 (n)
    const int l15  = lane & 15;
    const int kg   = lane >> 4;
    const int gsw  = l15 & 7;       // ds_read swizzle term
    const int m0   = bx * 256;
    const int n0   = by * 128;
    const int kbeg = SPLIT ? bz * Kslab : 0;

    floatx4 acc[4][4];
    #pragma unroll
    for (int m = 0; m < 4; m++)
        #pragma unroll
        for (int n = 0; n < 4; n++)
            acc[m][n] = (floatx4){0.f, 0.f, 0.f, 0.f};

    auto stage = [&](int buf, int k0) {
        // A: 2048 cells (256 rows x 8 g-chunks of 16B), swizzled source
        #pragma unroll
        for (int j = 0; j < 4; j++) {
            int c = j * 512 + tid;
            int row = c >> 3, gl = c & 7;
            int gg = gl ^ (row & 7);
            int grow = m0 + row; grow = grow < Md ? grow : Md - 1;
            const __attribute__((address_space(1))) short* src =
                (const __attribute__((address_space(1))) short*)(A + (size_t)grow * lda + k0 + gg * 8);
            __builtin_amdgcn_global_load_lds(
                (const __attribute__((address_space(1))) void*)src,
                (__attribute__((address_space(3))) void*)&As[(buf * 2048 + c) * 8], 16, 0, 0);
        }
        // B: 1024 cells (128 rows x 8 g-chunks)
        #pragma unroll
        for (int j = 0; j < 2; j++) {
            int c = j * 512 + tid;
            int row = c >> 3, gl = c & 7;
            int gg = gl ^ (row & 7);
            int brow = n0 + row; brow = brow < Nd ? brow : Nd - 1;
            const __attribute__((address_space(1))) short* src =
                (const __attribute__((address_space(1))) short*)(Bt + (size_t)brow * ldb + k0 + gg * 8);
            __builtin_amdgcn_global_load_lds(
                (const __attribute__((address_space(1))) void*)src,
                (__attribute__((address_space(3))) void*)&Bs[(buf * 1024 + c) * 8], 16, 0, 0);
        }
    };

    const int nt = Kslab >> 6;
    stage(0, kbeg);
    stage(1, kbeg + 64);

    for (int t = 0; t < nt; t++) {
        const int cur = t % 3;
        if (t + 2 < nt) {
            stage((t + 2) % 3, kbeg + (t + 2) * 64);
            asm volatile("s_waitcnt vmcnt(12)" ::: "memory");  // tile t landed
        } else if (t + 1 < nt) {
            asm volatile("s_waitcnt vmcnt(6)" ::: "memory");
        } else {
            asm volatile("s_waitcnt vmcnt(0)" ::: "memory");
        }
        __builtin_amdgcn_s_barrier();       // tile t staged (all waves)
        __builtin_amdgcn_sched_barrier(0);

        short8 a[2][4], bfr[2][4];
        #pragma unroll
        for (int kk = 0; kk < 2; kk++) {
            #pragma unroll
            for (int m = 0; m < 4; m++) {
                int row = wr * 64 + m * 16 + l15;
                int gs  = (kk * 4 + kg) ^ gsw;
                a[kk][m] = *(const short8*)&As[(cur * 2048 + row * 8 + gs) * 8];
            }
            #pragma unroll
            for (int n = 0; n < 4; n++) {
                int row = wc * 64 + n * 16 + l15;
                int gs  = (kk * 4 + kg) ^ gsw;
                bfr[kk][n] = *(const short8*)&Bs[(cur * 1024 + row * 8 + gs) * 8];
            }
        }
        asm volatile("s_waitcnt lgkmcnt(0)" ::: "memory");   // reads in regs
        __builtin_amdgcn_sched_barrier(0);
        __builtin_amdgcn_s_barrier();       // buffer cur free for stage(t+3)
        __builtin_amdgcn_sched_barrier(0);

        __builtin_amdgcn_s_setprio(1);
        #pragma unroll
        for (int kk = 0; kk < 2; kk++)
            #pragma unroll
            for (int m = 0; m < 4; m++)
                #pragma unroll
                for (int n = 0; n < 4; n++)
                    acc[m][n] = __builtin_amdgcn_mfma_f32_16x16x32_bf16(a[kk][m], bfr[kk][n], acc[m][n], 0, 0, 0);
        __builtin_amdgcn_s_setprio(0);
    }

    // ---- LDS-staged coalesced epilogue ----
    unsigned short* Cs = (unsigned short*)As;   // [256][136] bf16 = 69.6 KB
    #pragma unroll
    for (int n = 0; n < 4; n++) {
        int col = wc * 64 + n * 16 + l15;
        float bv = BIAS ? bias[n0 + col] : 0.f;
        #pragma unroll
        for (int m = 0; m < 4; m++) {
            #pragma unroll
            for (int q = 0; q < 4; q++) {
                int row = wr * 64 + m * 16 + kg * 4 + q;
                Cs[row * 136 + col] = f2bf(acc[m][n][q] + bv);
            }
        }
    }
    __syncthreads();
    #pragma unroll
    for (int j = 0; j < 8; j++) {
        int c = j * 512 + tid;          // 16B cell; 16 cells/row
        int row = c >> 4, cc = c & 15;
        int grow = m0 + row;
        if (grow >= Md) continue;
        short8 v = *(const short8*)&Cs[row * 136 + cc * 8];
        if (SPLIT)
            *(short8*)&Cpart[(size_t)bz * Md * Nd + (size_t)grow * Nd + n0 + cc * 8] = v;
        else if (W16)
            *(short8*)&C16[(size_t)grow * Nd + n0 + cc * 8] = v;
    }
}

// ---------------------------------------------------------------------------
// Swizzled 128x128 BK=64 dbuf MFMA GEMM — small GEMMs (proj, delta).
// ---------------------------------------------------------------------------
template<bool SPLIT, bool PARTBF, bool BIAS, int ACT, bool W32, bool W16>
__global__ __launch_bounds__(256) void gemm_mfma(
    const unsigned short* __restrict__ A, int lda,
    const unsigned short* __restrict__ Bt, int ldb,
    const float* __restrict__ bias,
    float* __restrict__ C32,
    unsigned short* __restrict__ C16,
    void* __restrict__ Cpart,
    int Md, int Nd, int Kslab)
{
    __shared__ short As[2][128 * 64];
    __shared__ short Bs[2][128 * 64];

    const int nx = gridDim.x, ny = gridDim.y, nz = gridDim.z;
    const int nb = nx * ny * nz;
    int id = blockIdx.x + nx * (blockIdx.y + ny * blockIdx.z);
    int bx, by, bz;
    if ((nb & 7) == 0) {
        int swz = (id & 7) * (nb >> 3) + (id >> 3);
        bx = swz % nx;
        int rem = swz / nx;
        by = rem % ny;
        bz = rem / ny;
    } else {
        bx = blockIdx.x; by = blockIdx.y; bz = blockIdx.z;
    }

    const int tid  = threadIdx.x;
    const int lane = tid & 63;
    const int wid  = tid >> 6;
    const int wr   = wid >> 1;
    const int wc   = wid & 1;
    const int l15  = lane & 15;
    const int kg   = lane >> 4;
    const int gsw  = l15 & 7;
    const int m0   = bx * 128;
    const int n0   = by * 128;
    const int kbeg = SPLIT ? bz * Kslab : 0;

    floatx4 acc[4][4];
    #pragma unroll
    for (int m = 0; m < 4; m++)
        #pragma unroll
        for (int n = 0; n < 4; n++)
            acc[m][n] = (floatx4){0.f, 0.f, 0.f, 0.f};

    auto stage = [&](int buf, int k0) {
        #pragma unroll
        for (int j = 0; j < 4; j++) {
            int c = j * 256 + tid;
            int row = c >> 3, gl = c & 7;
            int gg = gl ^ (row & 7);
            int grow = m0 + row; grow = grow < Md ? grow : Md - 1;
            const __attribute__((address_space(1))) short* src =
                (const __attribute__((address_space(1))) short*)(A + (size_t)grow * lda + k0 + gg * 8);
            __builtin_amdgcn_global_load_lds(
                (const __attribute__((address_space(1))) void*)src,
                (__attribute__((address_space(3))) void*)&As[buf][c * 8], 16, 0, 0);
        }
        #pragma unroll
        for (int j = 0; j < 4; j++) {
            int c = j * 256 + tid;
            int row = c >> 3, gl = c & 7;
            int gg = gl ^ (row & 7);
            int brow = n0 + row; brow = brow < Nd ? brow : Nd - 1;
            const __attribute__((address_space(1))) short* src =
                (const __attribute__((address_space(1))) short*)(Bt + (size_t)brow * ldb + k0 + gg * 8);
            __builtin_amdgcn_global_load_lds(
                (const __attribute__((address_space(1))) void*)src,
                (__attribute__((address_space(3))) void*)&Bs[buf][c * 8], 16, 0, 0);
        }
    };

    stage(0, kbeg);
    asm volatile("s_waitcnt vmcnt(0)" ::: "memory");
    __builtin_amdgcn_s_barrier();
    __builtin_amdgcn_sched_barrier(0);

    const int nt = Kslab >> 6;
    for (int t = 0; t < nt; t++) {
        const int cur = t & 1;
        if (t + 1 < nt) {
            stage(cur ^ 1, kbeg + (t + 1) * 64);
            asm volatile("s_waitcnt vmcnt(8)" ::: "memory");
        } else {
            asm volatile("s_waitcnt vmcnt(0)" ::: "memory");
        }
        __builtin_amdgcn_s_barrier();
        __builtin_amdgcn_sched_barrier(0);

        short8 a[2][4], bfr[2][4];
        #pragma unroll
        for (int kk = 0; kk < 2; kk++) {
            #pragma unroll
            for (int m = 0; m < 4; m++) {
                int row = wr * 64 + m * 16 + l15;
                int gs  = (kk * 4 + kg) ^ gsw;
                a[kk][m] = *(const short8*)&As[cur][(row * 8 + gs) * 8];
            }
            #pragma unroll
            for (int n = 0; n < 4; n++) {
                int row = wc * 64 + n * 16 + l15;
                int gs  = (kk * 4 + kg) ^ gsw;
                bfr[kk][n] = *(const short8*)&Bs[cur][(row * 8 + gs) * 8];
            }
        }
        __builtin_amdgcn_s_setprio(1);
        #pragma unroll
        for (int kk = 0; kk < 2; kk++)
            #pragma unroll
            for (int m = 0; m < 4; m++)
                #pragma unroll
                for (int n = 0; n < 4; n++)
                    acc[m][n] = __builtin_amdgcn_mfma_f32_16x16x32_bf16(a[kk][m], bfr[kk][n], acc[m][n], 0, 0, 0);
        __builtin_amdgcn_s_setprio(0);
        __builtin_amdgcn_sched_barrier(0);
        __builtin_amdgcn_s_barrier();
    }

    if (SPLIT) {
        #pragma unroll
        for (int n = 0; n < 4; n++) {
            int col = n0 + wc * 64 + n * 16 + l15;
            if (col >= Nd) continue;
            #pragma unroll
            for (int m = 0; m < 4; m++)
                #pragma unroll
                for (int q = 0; q < 4; q++) {
                    int row = m0 + wr * 64 + m * 16 + kg * 4 + q;
                    if (row >= Md) continue;
                    size_t ix = (size_t)bz * Md * Nd + (size_t)row * Nd + col;
                    if (PARTBF) ((unsigned short*)Cpart)[ix] = f2bf(acc[m][n][q]);
                    else        ((float*)Cpart)[ix] = acc[m][n][q];
                }
        }
    } else {
        #pragma unroll
        for (int n = 0; n < 4; n++) {
            int col = n0 + wc * 64 + n * 16 + l15;
            if (col >= Nd) continue;
            float bv = BIAS ? bias[col] : 0.f;
            #pragma unroll
            for (int m = 0; m < 4; m++)
                #pragma unroll
                for (int q = 0; q < 4; q++) {
                    int row = m0 + wr * 64 + m * 16 + kg * 4 + q;
                    if (row >= Md) continue;
                    float v = acc[m][n][q] + bv;
                    if (ACT == 1) v = fmaxf(v, 0.f) + log1pf(expf(-fabsf(v)));  // softplus
                    if (W32) C32[(size_t)row * Nd + col] = v;
                    if (W16) C16[(size_t)row * Nd + col] = f2bf(v);
                }
        }
    }
}

// ---------------------------------------------------------------------------
// Sum S fp32 split-K partials + bias/act -> fp32/bf16. total % 1024 == 0.
// ---------------------------------------------------------------------------
template<int S, bool BIAS, int ACT, bool W32, bool W16>
__global__ __launch_bounds__(256) void reduce_split(
    const float* __restrict__ P, const float* __restrict__ bias,
    float* __restrict__ C32, unsigned short* __restrict__ C16,
    int total, int nmask)
{
    int i = (blockIdx.x * 256 + threadIdx.x) * 4;
    float4 v = *(const float4*)&P[i];
    #pragma unroll
    for (int s = 1; s < S; s++) {
        float4 p = *(const float4*)&P[(size_t)s * total + i];
        v.x += p.x; v.y += p.y; v.z += p.z; v.w += p.w;
    }
    float r[4] = {v.x, v.y, v.z, v.w};
    #pragma unroll
    for (int j = 0; j < 4; j++) {
        float t = r[j];
        if (BIAS) t += bias[(i + j) & nmask];
        if (ACT == 1) t = fmaxf(t, 0.f) + log1pf(expf(-fabsf(t)));
        if (W32) C32[i + j] = t;
        if (W16) C16[i + j] = f2bf(t);
    }
}

// ---------------------------------------------------------------------------
// Sum S bf16 split-K partials + bias -> bf16. total % 2048 == 0.
// ---------------------------------------------------------------------------
template<int S, bool BIAS>
__global__ __launch_bounds__(256) void reduce_split_bf(
    const unsigned short* __restrict__ P, const float* __restrict__ bias,
    unsigned short* __restrict__ C16, int total, int nmask)
{
    int i = (blockIdx.x * 256 + threadIdx.x) * 8;
    float r[8] = {};
    #pragma unroll
    for (int s = 0; s < S; s++) {
        short8 p = *(const short8*)&P[(size_t)s * total + i];
        #pragma unroll
        for (int j = 0; j < 8; j++) r[j] += bf2f((unsigned short)p[j]);
    }
    short8 o;
    #pragma unroll
    for (int j = 0; j < 8; j++) {
        float t = r[j];
        if (BIAS) t += bias[(i + j) & nmask];
        o[j] = (short)f2bf(t);
    }
    *(short8*)&C16[i] = o;
}

// ---------------------------------------------------------------------------
// Causal depthwise conv (K=4) + bias + SiLU, vectorized (R18):
// 8 d-channels/thread; each tap = one short8 (16B) load; weights from the
// prep-transposed [4][DI] layout as float4 pairs. Same per-element FMA
// order as before -> bit-identical numerics.
// ---------------------------------------------------------------------------
__global__ __launch_bounds__(256) void conv_silu_kernel(
    const unsigned short* __restrict__ xz, const float* __restrict__ cw_t,
    const float* __restrict__ conv_b, float* __restrict__ xc,
    unsigned short* __restrict__ xc_bf)
{
    int idx = blockIdx.x * 256 + threadIdx.x;   // over B*L*DI/8
    int i8  = idx * 8;
    int d0  = i8 & (DI - 1);
    int bl  = i8 >> 11;
    int l   = bl % Ll;

    float acc[8];
    {
        float4 b0 = *(const float4*)&conv_b[d0];
        float4 b1 = *(const float4*)&conv_b[d0 + 4];
        acc[0] = b0.x; acc[1] = b0.y; acc[2] = b0.z; acc[3] = b0.w;
        acc[4] = b1.x; acc[5] = b1.y; acc[6] = b1.z; acc[7] = b1.w;
    }
    #pragma unroll
    for (int k = 0; k < Kc; k++) {
        int ls = l + k - (Kc - 1);
        if (ls >= 0) {
            short8 v = *(const short8*)&xz[(size_t)(bl + k - (Kc - 1)) * (2 * DI) + d0];
            float4 w0 = *(const float4*)&cw_t[k * DI + d0];
            float4 w1 = *(const float4*)&cw_t[k * DI + d0 + 4];
            float w[8] = {w0.x, w0.y, w0.z, w0.w, w1.x, w1.y, w1.z, w1.w};
            #pragma unroll
            for (int e = 0; e < 8; e++)
                acc[e] = fmaf(w[e], bf2f((unsigned short)v[e]), acc[e]);
        }
    }

    float4 o0, o1; short8 ob;
    #pragma unroll
    for (int e = 0; e < 8; e++) {
        float s = fast_silu(acc[e]);
        if (e < 4) ((float*)&o0)[e] = s; else ((float*)&o1)[e - 4] = s;
        ob[e] = (short)f2bf(s);
    }
    *(float4*)&xc[i8]     = o0;
    *(float4*)&xc[i8 + 4] = o1;
    *(short8*)&xc_bf[i8]  = ob;
}

// ---------------------------------------------------------------------------
// Chunked selective scan, 2-pass (R13-proven): part1 chunks 0..2 (P/S only,
// light), part2 all 4 chunks (h_start fold + recurrence + y emit).
// ---------------------------------------------------------------------------
__global__ __launch_bounds__(256) void scan_part1(
    const float* __restrict__ delta, const float* __restrict__ xc,
    const float* __restrict__ proj,  const float* __restrict__ A_log,
    float* __restrict__ Pbuf, float* __restrict__ Sbuf)
{
    const int t    = threadIdx.x;
    const int nq   = t & 3;
    const int dloc = t >> 2;
    const int d    = blockIdx.x * 64 + dloc;
    const int b    = blockIdx.y;
    const int c    = blockIdx.z;

    float4 Alq = *(const float4*)&A_log[(size_t)d * Nst + nq * 4];
    float Ar0 = -expf(Alq.x), Ar1 = -expf(Alq.y), Ar2 = -expf(Alq.z), Ar3 = -expf(Alq.w);

    float h0 = 0.f, h1 = 0.f, h2 = 0.f, h3 = 0.f;
    float sdl = 0.f;

    for (int l = c * CL; l < (c + 1) * CL; l++) {
        size_t bl = (size_t)b * Ll + l;
        float dl  = delta[bl * DI + d];
        float xcv = xc[bl * DI + d];
        float dx  = dl * xcv;
        float4 Bv = *(const float4*)&proj[bl * (DTR + 2 * Nst) + DTR + nq * 4];

        h0 = fmaf(__expf(dl * Ar0), h0, dx * Bv.x);
        h1 = fmaf(__expf(dl * Ar1), h1, dx * Bv.y);
        h2 = fmaf(__expf(dl * Ar2), h2, dx * Bv.z);
        h3 = fmaf(__expf(dl * Ar3), h3, dx * Bv.w);
        sdl += dl;
    }

    size_t o = (((size_t)c * Bb + b) * DI + d) * Nst + nq * 4;
    *(float4*)&Pbuf[o] = (float4){__expf(sdl * Ar0), __expf(sdl * Ar1),
                                  __expf(sdl * Ar2), __expf(sdl * Ar3)};
    *(float4*)&Sbuf[o] = (float4){h0, h1, h2, h3};
}

__global__ __launch_bounds__(256) void scan_part2(
    const float* __restrict__ delta, const float* __restrict__ xc,
    const unsigned short* __restrict__ xz, const float* __restrict__ proj,
    const float* __restrict__ A_log, const float* __restrict__ Dv,
    const float* __restrict__ Pbuf, const float* __restrict__ Sbuf,
    unsigned short* __restrict__ y)
{
    const int t    = threadIdx.x;
    const int nq   = t & 3;
    const int dloc = t >> 2;
    const int d    = blockIdx.x * 64 + dloc;
    const int b    = blockIdx.y;
    const int c    = blockIdx.z;

    float4 Alq = *(const float4*)&A_log[(size_t)d * Nst + nq * 4];
    float Ar0 = -expf(Alq.x), Ar1 = -expf(Alq.y), Ar2 = -expf(Alq.z), Ar3 = -expf(Alq.w);
    const float Dd = Dv[d];

    float h0 = 0.f, h1 = 0.f, h2 = 0.f, h3 = 0.f;
    for (int cc = 0; cc < c; cc++) {
        size_t o = (((size_t)cc * Bb + b) * DI + d) * Nst + nq * 4;
        float4 Pv = *(const float4*)&Pbuf[o];
        float4 Sv = *(const float4*)&Sbuf[o];
        h0 = fmaf(Pv.x, h0, Sv.x);
        h1 = fmaf(Pv.y, h1, Sv.y);
        h2 = fmaf(Pv.z, h2, Sv.z);
        h3 = fmaf(Pv.w, h3, Sv.w);
    }

    for (int l = c * CL; l < (c + 1) * CL; l++) {
        size_t bl = (size_t)b * Ll + l;
        float dl  = delta[bl * DI + d];
        float xcv = xc[bl * DI + d];
        float zv  = bf2f(xz[bl * (2 * DI) + DI + d]);
        float dx  = dl * xcv;
        const float* p = proj + bl * (DTR + 2 * Nst);
        float4 Bv = *(const float4*)&p[DTR + nq * 4];
        float4 Cv = *(const float4*)&p[DTR + Nst + nq * 4];

        h0 = fmaf(__expf(dl * Ar0), h0, dx * Bv.x);
        h1 = fmaf(__expf(dl * Ar1), h1, dx * Bv.y);
        h2 = fmaf(__expf(dl * Ar2), h2, dx * Bv.z);
        h3 = fmaf(__expf(dl * Ar3), h3, dx * Bv.w);

        float yac = h0 * Cv.x + h1 * Cv.y + h2 * Cv.z + h3 * Cv.w;
        yac += __shfl_xor(yac, 1);
        yac += __shfl_xor(yac, 2);

        if (nq == 0) {
            float yv = yac + Dd * xcv;
            yv *= fast_silu(zv);
            y[bl * DI + d] = f2bf(yv);
        }
    }
}

// ---------------------------------------------------------------------------
// logits[M,16] = out_bf[M,1024] @ W_out[1024,16] + b_out (R17 vectorized)
// ---------------------------------------------------------------------------
__global__ __launch_bounds__(256) void gemm_n16(
    const unsigned short* __restrict__ A, const float* __restrict__ W,
    const float* __restrict__ bias, float* __restrict__ C, int Kd)
{
    int m    = blockIdx.x;
    int t    = threadIdx.x;
    int c    = t & 15;
    int kgrp = t >> 4;               // 0..15
    const unsigned short* a = A + (size_t)m * Kd;

    float acc = 0.f;
    #pragma unroll
    for (int j = 0; j < 8; j++) {    // Kd = 1024 = 16 kgrps * 8 j * 8 elems
        int k0 = kgrp * 8 + j * 128;
        short8 v = *(const short8*)&a[k0];
        #pragma unroll
        for (int e = 0; e < 8; e++)
            acc = fmaf(bf2f((unsigned short)v[e]), W[(k0 + e) * NC + c], acc);
    }

    __shared__ float red[256];
    red[t] = acc;
    __syncthreads();
    #pragma unroll
    for (int s = 128; s >= 16; s >>= 1) {
        if (t < s) red[t] += red[t + s];
        __syncthreads();
    }
    if (t < 16) C[(size_t)m * NC + t] = red[t] + bias[t];
}

// ---------------------------------------------------------------------------
extern "C" void kernel_launch(void* const* d_in, const int* in_sizes, int n_in,
                              void* d_out, int out_size, void* d_ws, size_t ws_size,
                              hipStream_t stream) {
    const float* x         = (const float*)d_in[0];
    const float* W_in      = (const float*)d_in[1];
    const float* b_in      = (const float*)d_in[2];
    const float* in_proj_w = (const float*)d_in[3];
    const float* conv_w    = (const float*)d_in[4];
    const float* conv_b    = (const float*)d_in[5];
    const float* x_proj_w  = (const float*)d_in[6];
    const float* dt_proj_w = (const float*)d_in[7];
    const float* dt_proj_b = (const float*)d_in[8];
    const float* A_log     = (const float*)d_in[9];
    const float* Dv        = (const float*)d_in[10];
    const float* out_proj  = (const float*)d_in[11];
    const float* W_out     = (const float*)d_in[12];
    const float* b_out     = (const float*)d_in[13];
    float* logits = (float*)d_out;

    char* base = (char*)d_ws;
    size_t off = 0;
    auto alloc = [&](size_t bytes) {
        char* p = base + off;
        off += (bytes + 255) & ~(size_t)255;
        return p;
    };
    unsigned short* x_bf    = (unsigned short*)alloc((size_t)M * DIN * 2);
    unsigned short* Wt_in   = (unsigned short*)alloc((size_t)Hh * DIN * 2);
    unsigned short* Wt_ip   = (unsigned short*)alloc((size_t)(2 * DI) * Hh * 2);
    unsigned short* Wt_op   = (unsigned short*)alloc((size_t)Hh * DI * 2);
    unsigned short* xpw_t   = (unsigned short*)alloc((size_t)96 * DI * 2);
    unsigned short* dtw_t   = (unsigned short*)alloc((size_t)DI * DTR * 2);
    float*          cw_t    = (float*)alloc((size_t)Kc * DI * 4);
    unsigned short* h_bf    = (unsigned short*)alloc((size_t)M * Hh * 2);
    unsigned short* xz_bf   = (unsigned short*)alloc((size_t)M * 2 * DI * 2);
    float*          xc      = (float*)alloc((size_t)M * DI * 4);       // | P14 alias (13.1MB)
    float*          delta   = (float*)alloc((size_t)M * DI * 4);       // | P8 alias
    unsigned short* xc_bf   = (unsigned short*)alloc((size_t)M * DI * 2);
    float*          proj_f  = (float*)alloc((size_t)M * 96 * 4);
    unsigned short* proj_bf = (unsigned short*)alloc((size_t)M * 96 * 2);
    unsigned short* y_bf    = (unsigned short*)alloc((size_t)M * DI * 2);
    unsigned short* out_bf  = (unsigned short*)alloc((size_t)M * Hh * 2);

    unsigned short* P14 = (unsigned short*)xc;   // bf16 [4][1600][1024] = 13.1MB
    float*          P8  = delta;                 // fp32 [8][1600][96]  = 4.9MB
    float*          Pbuf = (float*)x_bf;         // scan chunk buffers (x_bf dead)
    float*          Sbuf = Pbuf + (size_t)(NCH - 1) * Bb * DI * Nst;

    dim3 blk(256), blk5(512);

    // 0) fused prologue: convert + 5 transposes + conv_w transpose
    prep_kernel<<<dim3(22240), blk, 0, stream>>>(
        x, x_bf, W_in, Wt_in, in_proj_w, Wt_ip, out_proj, Wt_op,
        x_proj_w, xpw_t, dt_proj_w, dtw_t, conv_w, cw_t);

    // 1) h = x @ W_in + b_in   [1600,6144]@[6144,1024], split-K 4 -> 224 blocks
    gemm_deep<true, false, false><<<dim3(7, Hh / 128, 4), blk5, 0, stream>>>(
        x_bf, DIN, Wt_in, DIN, nullptr, nullptr, P14, M, Hh, DIN / 4);
    reduce_split_bf<4, true><<<dim3((M * Hh) / 2048), blk, 0, stream>>>(
        P14, b_in, h_bf, M * Hh, Hh - 1);

    // 2) xz = h @ in_proj_w    [1600,1024]@[1024,4096], 224 blocks, no split
    gemm_deep<false, false, true><<<dim3(7, (2 * DI) / 128, 1), blk5, 0, stream>>>(
        h_bf, Hh, Wt_ip, Hh, nullptr, xz_bf, nullptr, M, 2 * DI, Hh);

    // 3) xc = silu(conv(xm) + conv_b)  -> fp32 + bf16 (vectorized, 1600 blocks)
    conv_silu_kernel<<<dim3((Bb * Ll * DI) / 2048), blk, 0, stream>>>(
        xz_bf, cw_t, conv_b, xc, xc_bf);

    // 4) proj = xc @ x_proj_w  [1600,2048]@[2048,96], split-K 8 -> 104 blocks
    gemm_mfma<true, false, false, 0, false, false><<<dim3(13, 1, 8), blk, 0, stream>>>(
        xc_bf, DI, xpw_t, DI, nullptr, nullptr, nullptr, P8, M, 96, DI / 8);
    reduce_split<8, false, 0, true, true><<<dim3((M * 96) / 1024), blk, 0, stream>>>(
        P8, nullptr, proj_f, proj_bf, M * 96, 0);

    // 5) delta = softplus(proj[:,:64] @ dt_proj_w + dt_proj_b)  [1600,64]@[64,2048]
    gemm_mfma<false, false, true, 1, true, false><<<dim3(13, DI / 128, 1), blk, 0, stream>>>(
        proj_bf, 96, dtw_t, DTR, dt_proj_b, delta, nullptr, nullptr, M, DI, DTR);

    // 6) chunked selective scan: pass1 (chunks 0..2) then pass2 (all 4)
    scan_part1<<<dim3(DI / 64, Bb, NCH - 1), blk, 0, stream>>>(
        delta, xc, proj_f, A_log, Pbuf, Sbuf);
    scan_part2<<<dim3(DI / 64, Bb, NCH), blk, 0, stream>>>(
        delta, xc, xz_bf, proj_f, A_log, Dv, Pbuf, Sbuf, y_bf);

    // 7) out = y @ out_proj_w  [1600,2048]@[2048,1024], split-K 4 -> 224 blocks
    gemm_deep<true, false, false><<<dim3(7, Hh / 128, 4), blk5, 0, stream>>>(
        y_bf, DI, Wt_op, DI, nullptr, nullptr, P14, M, Hh, DI / 4);
    reduce_split_bf<4, false><<<dim3((M * Hh) / 2048), blk, 0, stream>>>(
        P14, nullptr, out_bf, M * Hh, 0);

    // 8) logits = out @ W_out + b_out  [1600,1024]@[1024,16]
    gemm_n16<<<dim3(M), blk, 0, stream>>>(out_bf, W_out, b_out, logits, Hh);
}

// Round 19
// 209.631 us; speedup vs baseline: 1.3675x; 1.0190x over previous
//
#include <hip/hip_runtime.h>
#include <hip/hip_bf16.h>
#include <stdint.h>

// Problem constants
constexpr int Bb  = 16;
constexpr int Ll  = 100;
constexpr int DIN = 6144;
constexpr int Hh  = 1024;
constexpr int DI  = 2048;
constexpr int Nst = 16;
constexpr int DTR = 64;
constexpr int Kc  = 4;
constexpr int NC  = 16;
constexpr int M   = Bb * Ll;   // 1600 tokens
constexpr int NCH = 4;         // scan L-chunks
constexpr int CL  = Ll / NCH;  // 25

typedef __attribute__((ext_vector_type(8))) short short8;
typedef __attribute__((ext_vector_type(4))) float floatx4;

__device__ __forceinline__ float bf2f(unsigned short u) {
    union { uint32_t b; float f; } x; x.b = ((uint32_t)u) << 16; return x.f;
}
__device__ __forceinline__ unsigned short f2bf(float f) {
    union { float f; uint32_t b; } x; x.f = f;
    uint32_t r = x.b + 0x7FFF + ((x.b >> 16) & 1);   // RNE
    return (unsigned short)(r >> 16);
}
__device__ __forceinline__ float fast_silu(float x) {
    return x / (1.f + __expf(-x));
}

// ---------------------------------------------------------------------------
// Fused prologue: one kernel, sectioned grid.
// ---------------------------------------------------------------------------
__global__ __launch_bounds__(256) void prep_kernel(
    const float* __restrict__ x, unsigned short* __restrict__ x_bf,
    const float* __restrict__ W_in, unsigned short* __restrict__ Wt_in,
    const float* __restrict__ W_ip, unsigned short* __restrict__ Wt_ip,
    const float* __restrict__ W_op, unsigned short* __restrict__ Wt_op,
    const float* __restrict__ xpw,  unsigned short* __restrict__ xpw_t,
    const float* __restrict__ dtw,  unsigned short* __restrict__ dtw_t,
    const float* __restrict__ cw,   float* __restrict__ cw_t)
{
    __shared__ float t[32][33];
    int b = blockIdx.x;

    if (b < 9600) {                       // convert x
        int i = (b * 256 + threadIdx.x) * 4;
        float4 v = *(const float4*)&x[i];
        x_bf[i + 0] = f2bf(v.x);
        x_bf[i + 1] = f2bf(v.y);
        x_bf[i + 2] = f2bf(v.z);
        x_bf[i + 3] = f2bf(v.w);
        return;
    }
    if (b >= 22208) {                     // conv_w transpose [DI][4] -> [4][DI]
        int idx = (b - 22208) * 256 + threadIdx.x;   // 8192 elems
        int k = idx >> 11, d = idx & (DI - 1);
        cw_t[k * DI + d] = cw[d * Kc + k];
        return;
    }
    const float* in; unsigned short* out; int K, N, bid;
    if      (b < 15744) { in = W_in; out = Wt_in; K = DIN; N = Hh;     bid = b - 9600;  }
    else if (b < 19840) { in = W_ip; out = Wt_ip; K = Hh;  N = 2 * DI; bid = b - 15744; }
    else if (b < 21888) { in = W_op; out = Wt_op; K = DI;  N = Hh;     bid = b - 19840; }
    else if (b < 22080) { in = xpw;  out = xpw_t; K = DI;  N = 96;     bid = b - 21888; }
    else                { in = dtw;  out = dtw_t; K = DTR; N = DI;     bid = b - 22080; }

    int kx = bid % (K / 32), ny = bid / (K / 32);
    int k0 = kx * 32, n0 = ny * 32;
    int tx = threadIdx.x & 31, ty = threadIdx.x >> 5;
    #pragma unroll
    for (int i = 0; i < 4; i++)
        t[ty + i * 8][tx] = in[(size_t)(k0 + ty + i * 8) * N + n0 + tx];
    __syncthreads();
    #pragma unroll
    for (int i = 0; i < 4; i++)
        out[(size_t)(n0 + ty + i * 8) * K + k0 + tx] = f2bf(t[tx][ty + i * 8]);
}

// ---------------------------------------------------------------------------
// Deep-pipelined bf16 MFMA GEMM (big GEMMs 1/2/7): BM=256, BN=128, BK=64;
// 512 thr = 8 waves (4m x 2n), wave tile 64x64. 3-buffer LDS ring (144 KB),
// 2-deep counted-vmcnt prefetch, swizzled staging (R11), LDS-staged
// coalesced epilogue, early buffer release (R13-proven config).
// ---------------------------------------------------------------------------
template<bool SPLIT, bool BIAS, bool W16>
__global__ __launch_bounds__(512) void gemm_deep(
    const unsigned short* __restrict__ A, int lda,    // [Md x lda]
    const unsigned short* __restrict__ Bt, int ldb,   // [Nd x ldb]
    const float* __restrict__ bias,                   // [Nd]
    unsigned short* __restrict__ C16,                 // final bf16 out
    unsigned short* __restrict__ Cpart,               // bf16 partials
    int Md, int Nd, int Kslab)
{
    __shared__ short As[3 * 256 * 64];   // 96 KB
    __shared__ short Bs[3 * 128 * 64];   // 48 KB

    // XCD-aware block remap
    const int nx = gridDim.x, ny = gridDim.y, nz = gridDim.z;
    const int nb = nx * ny * nz;
    int id = blockIdx.x + nx * (blockIdx.y + ny * blockIdx.z);
    int bx, by, bz;
    if ((nb & 7) == 0) {
        int swz = (id & 7) * (nb >> 3) + (id >> 3);
        bx = swz % nx;
        int rem = swz / nx;
        by = rem % ny;
        bz = rem / ny;
    } else {
        bx = blockIdx.x; by = blockIdx.y; bz = blockIdx.z;
    }

    const int tid  = threadIdx.x;
    const int lane = tid & 63;
    const int wid  = tid >> 6;      // 0..7
    const int wr   = wid >> 1;      // 0..3 (m)
    const int wc   = wid & 1;       // 0..1 (n)
    const int l15  = lane & 15;
    const int kg   = lane >> 4;
    const int gsw  = l15 & 7;       // ds_read swizzle term
    const int m0   = bx * 256;
    const int n0   = by * 128;
    const int kbeg = SPLIT ? bz * Kslab : 0;

    floatx4 acc[4][4];
    #pragma unroll
    for (int m = 0; m < 4; m++)
        #pragma unroll
        for (int n = 0; n < 4; n++)
            acc[m][n] = (floatx4){0.f, 0.f, 0.f, 0.f};

    auto stage = [&](int buf, int k0) {
        // A: 2048 cells (256 rows x 8 g-chunks of 16B), swizzled source
        #pragma unroll
        for (int j = 0; j < 4; j++) {
            int c = j * 512 + tid;
            int row = c >> 3, gl = c & 7;
            int gg = gl ^ (row & 7);
            int grow = m0 + row; grow = grow < Md ? grow : Md - 1;
            const __attribute__((address_space(1))) short* src =
                (const __attribute__((address_space(1))) short*)(A + (size_t)grow * lda + k0 + gg * 8);
            __builtin_amdgcn_global_load_lds(
                (const __attribute__((address_space(1))) void*)src,
                (__attribute__((address_space(3))) void*)&As[(buf * 2048 + c) * 8], 16, 0, 0);
        }
        // B: 1024 cells (128 rows x 8 g-chunks)
        #pragma unroll
        for (int j = 0; j < 2; j++) {
            int c = j * 512 + tid;
            int row = c >> 3, gl = c & 7;
            int gg = gl ^ (row & 7);
            int brow = n0 + row; brow = brow < Nd ? brow : Nd - 1;
            const __attribute__((address_space(1))) short* src =
                (const __attribute__((address_space(1))) short*)(Bt + (size_t)brow * ldb + k0 + gg * 8);
            __builtin_amdgcn_global_load_lds(
                (const __attribute__((address_space(1))) void*)src,
                (__attribute__((address_space(3))) void*)&Bs[(buf * 1024 + c) * 8], 16, 0, 0);
        }
    };

    const int nt = Kslab >> 6;
    stage(0, kbeg);
    stage(1, kbeg + 64);

    for (int t = 0; t < nt; t++) {
        const int cur = t % 3;
        if (t + 2 < nt) {
            stage((t + 2) % 3, kbeg + (t + 2) * 64);
            asm volatile("s_waitcnt vmcnt(12)" ::: "memory");  // tile t landed
        } else if (t + 1 < nt) {
            asm volatile("s_waitcnt vmcnt(6)" ::: "memory");
        } else {
            asm volatile("s_waitcnt vmcnt(0)" ::: "memory");
        }
        __builtin_amdgcn_s_barrier();       // tile t staged (all waves)
        __builtin_amdgcn_sched_barrier(0);

        short8 a[2][4], bfr[2][4];
        #pragma unroll
        for (int kk = 0; kk < 2; kk++) {
            #pragma unroll
            for (int m = 0; m < 4; m++) {
                int row = wr * 64 + m * 16 + l15;
                int gs  = (kk * 4 + kg) ^ gsw;
                a[kk][m] = *(const short8*)&As[(cur * 2048 + row * 8 + gs) * 8];
            }
            #pragma unroll
            for (int n = 0; n < 4; n++) {
                int row = wc * 64 + n * 16 + l15;
                int gs  = (kk * 4 + kg) ^ gsw;
                bfr[kk][n] = *(const short8*)&Bs[(cur * 1024 + row * 8 + gs) * 8];
            }
        }
        asm volatile("s_waitcnt lgkmcnt(0)" ::: "memory");   // reads in regs
        __builtin_amdgcn_sched_barrier(0);
        __builtin_amdgcn_s_barrier();       // buffer cur free for stage(t+3)
        __builtin_amdgcn_sched_barrier(0);

        __builtin_amdgcn_s_setprio(1);
        #pragma unroll
        for (int kk = 0; kk < 2; kk++)
            #pragma unroll
            for (int m = 0; m < 4; m++)
                #pragma unroll
                for (int n = 0; n < 4; n++)
                    acc[m][n] = __builtin_amdgcn_mfma_f32_16x16x32_bf16(a[kk][m], bfr[kk][n], acc[m][n], 0, 0, 0);
        __builtin_amdgcn_s_setprio(0);
    }

    // ---- LDS-staged coalesced epilogue ----
    unsigned short* Cs = (unsigned short*)As;   // [256][136] bf16 = 69.6 KB
    #pragma unroll
    for (int n = 0; n < 4; n++) {
        int col = wc * 64 + n * 16 + l15;
        float bv = BIAS ? bias[n0 + col] : 0.f;
        #pragma unroll
        for (int m = 0; m < 4; m++) {
            #pragma unroll
            for (int q = 0; q < 4; q++) {
                int row = wr * 64 + m * 16 + kg * 4 + q;
                Cs[row * 136 + col] = f2bf(acc[m][n][q] + bv);
            }
        }
    }
    __syncthreads();
    #pragma unroll
    for (int j = 0; j < 8; j++) {
        int c = j * 512 + tid;          // 16B cell; 16 cells/row
        int row = c >> 4, cc = c & 15;
        int grow = m0 + row;
        if (grow >= Md) continue;
        short8 v = *(const short8*)&Cs[row * 136 + cc * 8];
        if (SPLIT)
            *(short8*)&Cpart[(size_t)bz * Md * Nd + (size_t)grow * Nd + n0 + cc * 8] = v;
        else if (W16)
            *(short8*)&C16[(size_t)grow * Nd + n0 + cc * 8] = v;
    }
}

// ---------------------------------------------------------------------------
// Swizzled 128x128 BK=64 dbuf MFMA GEMM — small GEMMs (proj, delta).
// ---------------------------------------------------------------------------
template<bool SPLIT, bool PARTBF, bool BIAS, int ACT, bool W32, bool W16>
__global__ __launch_bounds__(256) void gemm_mfma(
    const unsigned short* __restrict__ A, int lda,
    const unsigned short* __restrict__ Bt, int ldb,
    const float* __restrict__ bias,
    float* __restrict__ C32,
    unsigned short* __restrict__ C16,
    void* __restrict__ Cpart,
    int Md, int Nd, int Kslab)
{
    __shared__ short As[2][128 * 64];
    __shared__ short Bs[2][128 * 64];

    const int nx = gridDim.x, ny = gridDim.y, nz = gridDim.z;
    const int nb = nx * ny * nz;
    int id = blockIdx.x + nx * (blockIdx.y + ny * blockIdx.z);
    int bx, by, bz;
    if ((nb & 7) == 0) {
        int swz = (id & 7) * (nb >> 3) + (id >> 3);
        bx = swz % nx;
        int rem = swz / nx;
        by = rem % ny;
        bz = rem / ny;
    } else {
        bx = blockIdx.x; by = blockIdx.y; bz = blockIdx.z;
    }

    const int tid  = threadIdx.x;
    const int lane = tid & 63;
    const int wid  = tid >> 6;
    const int wr   = wid >> 1;
    const int wc   = wid & 1;
    const int l15  = lane & 15;
    const int kg   = lane >> 4;
    const int gsw  = l15 & 7;
    const int m0   = bx * 128;
    const int n0   = by * 128;
    const int kbeg = SPLIT ? bz * Kslab : 0;

    floatx4 acc[4][4];
    #pragma unroll
    for (int m = 0; m < 4; m++)
        #pragma unroll
        for (int n = 0; n < 4; n++)
            acc[m][n] = (floatx4){0.f, 0.f, 0.f, 0.f};

    auto stage = [&](int buf, int k0) {
        #pragma unroll
        for (int j = 0; j < 4; j++) {
            int c = j * 256 + tid;
            int row = c >> 3, gl = c & 7;
            int gg = gl ^ (row & 7);
            int grow = m0 + row; grow = grow < Md ? grow : Md - 1;
            const __attribute__((address_space(1))) short* src =
                (const __attribute__((address_space(1))) short*)(A + (size_t)grow * lda + k0 + gg * 8);
            __builtin_amdgcn_global_load_lds(
                (const __attribute__((address_space(1))) void*)src,
                (__attribute__((address_space(3))) void*)&As[buf][c * 8], 16, 0, 0);
        }
        #pragma unroll
        for (int j = 0; j < 4; j++) {
            int c = j * 256 + tid;
            int row = c >> 3, gl = c & 7;
            int gg = gl ^ (row & 7);
            int brow = n0 + row; brow = brow < Nd ? brow : Nd - 1;
            const __attribute__((address_space(1))) short* src =
                (const __attribute__((address_space(1))) short*)(Bt + (size_t)brow * ldb + k0 + gg * 8);
            __builtin_amdgcn_global_load_lds(
                (const __attribute__((address_space(1))) void*)src,
                (__attribute__((address_space(3))) void*)&Bs[buf][c * 8], 16, 0, 0);
        }
    };

    stage(0, kbeg);
    asm volatile("s_waitcnt vmcnt(0)" ::: "memory");
    __builtin_amdgcn_s_barrier();
    __builtin_amdgcn_sched_barrier(0);

    const int nt = Kslab >> 6;
    for (int t = 0; t < nt; t++) {
        const int cur = t & 1;
        if (t + 1 < nt) {
            stage(cur ^ 1, kbeg + (t + 1) * 64);
            asm volatile("s_waitcnt vmcnt(8)" ::: "memory");
        } else {
            asm volatile("s_waitcnt vmcnt(0)" ::: "memory");
        }
        __builtin_amdgcn_s_barrier();
        __builtin_amdgcn_sched_barrier(0);

        short8 a[2][4], bfr[2][4];
        #pragma unroll
        for (int kk = 0; kk < 2; kk++) {
            #pragma unroll
            for (int m = 0; m < 4; m++) {
                int row = wr * 64 + m * 16 + l15;
                int gs  = (kk * 4 + kg) ^ gsw;
                a[kk][m] = *(const short8*)&As[cur][(row * 8 + gs) * 8];
            }
            #pragma unroll
            for (int n = 0; n < 4; n++) {
                int row = wc * 64 + n * 16 + l15;
                int gs  = (kk * 4 + kg) ^ gsw;
                bfr[kk][n] = *(const short8*)&Bs[cur][(row * 8 + gs) * 8];
            }
        }
        __builtin_amdgcn_s_setprio(1);
        #pragma unroll
        for (int kk = 0; kk < 2; kk++)
            #pragma unroll
            for (int m = 0; m < 4; m++)
                #pragma unroll
                for (int n = 0; n < 4; n++)
                    acc[m][n] = __builtin_amdgcn_mfma_f32_16x16x32_bf16(a[kk][m], bfr[kk][n], acc[m][n], 0, 0, 0);
        __builtin_amdgcn_s_setprio(0);
        __builtin_amdgcn_sched_barrier(0);
        __builtin_amdgcn_s_barrier();
    }

    if (SPLIT) {
        #pragma unroll
        for (int n = 0; n < 4; n++) {
            int col = n0 + wc * 64 + n * 16 + l15;
            if (col >= Nd) continue;
            #pragma unroll
            for (int m = 0; m < 4; m++)
                #pragma unroll
                for (int q = 0; q < 4; q++) {
                    int row = m0 + wr * 64 + m * 16 + kg * 4 + q;
                    if (row >= Md) continue;
                    size_t ix = (size_t)bz * Md * Nd + (size_t)row * Nd + col;
                    if (PARTBF) ((unsigned short*)Cpart)[ix] = f2bf(acc[m][n][q]);
                    else        ((float*)Cpart)[ix] = acc[m][n][q];
                }
        }
    } else {
        #pragma unroll
        for (int n = 0; n < 4; n++) {
            int col = n0 + wc * 64 + n * 16 + l15;
            if (col >= Nd) continue;
            float bv = BIAS ? bias[col] : 0.f;
            #pragma unroll
            for (int m = 0; m < 4; m++)
                #pragma unroll
                for (int q = 0; q < 4; q++) {
                    int row = m0 + wr * 64 + m * 16 + kg * 4 + q;
                    if (row >= Md) continue;
                    float v = acc[m][n][q] + bv;
                    if (ACT == 1) v = fmaxf(v, 0.f) + log1pf(expf(-fabsf(v)));  // softplus
                    if (W32) C32[(size_t)row * Nd + col] = v;
                    if (W16) C16[(size_t)row * Nd + col] = f2bf(v);
                }
        }
    }
}

// ---------------------------------------------------------------------------
// Sum S fp32 split-K partials + bias/act -> fp32/bf16. total % 1024 == 0.
// ---------------------------------------------------------------------------
template<int S, bool BIAS, int ACT, bool W32, bool W16>
__global__ __launch_bounds__(256) void reduce_split(
    const float* __restrict__ P, const float* __restrict__ bias,
    float* __restrict__ C32, unsigned short* __restrict__ C16,
    int total, int nmask)
{
    int i = (blockIdx.x * 256 + threadIdx.x) * 4;
    float4 v = *(const float4*)&P[i];
    #pragma unroll
    for (int s = 1; s < S; s++) {
        float4 p = *(const float4*)&P[(size_t)s * total + i];
        v.x += p.x; v.y += p.y; v.z += p.z; v.w += p.w;
    }
    float r[4] = {v.x, v.y, v.z, v.w};
    #pragma unroll
    for (int j = 0; j < 4; j++) {
        float t = r[j];
        if (BIAS) t += bias[(i + j) & nmask];
        if (ACT == 1) t = fmaxf(t, 0.f) + log1pf(expf(-fabsf(t)));
        if (W32) C32[i + j] = t;
        if (W16) C16[i + j] = f2bf(t);
    }
}

// ---------------------------------------------------------------------------
// Sum S bf16 split-K partials + bias -> bf16. total % 2048 == 0.
// ---------------------------------------------------------------------------
template<int S, bool BIAS>
__global__ __launch_bounds__(256) void reduce_split_bf(
    const unsigned short* __restrict__ P, const float* __restrict__ bias,
    unsigned short* __restrict__ C16, int total, int nmask)
{
    int i = (blockIdx.x * 256 + threadIdx.x) * 8;
    float r[8] = {};
    #pragma unroll
    for (int s = 0; s < S; s++) {
        short8 p = *(const short8*)&P[(size_t)s * total + i];
        #pragma unroll
        for (int j = 0; j < 8; j++) r[j] += bf2f((unsigned short)p[j]);
    }
    short8 o;
    #pragma unroll
    for (int j = 0; j < 8; j++) {
        float t = r[j];
        if (BIAS) t += bias[(i + j) & nmask];
        o[j] = (short)f2bf(t);
    }
    *(short8*)&C16[i] = o;
}

// ---------------------------------------------------------------------------
// Causal depthwise conv (K=4) + bias + SiLU, vectorized. R19: bf16-only
// output (the fp32 xc copy is no longer consumed anywhere).
// ---------------------------------------------------------------------------
__global__ __launch_bounds__(256) void conv_silu_kernel(
    const unsigned short* __restrict__ xz, const float* __restrict__ cw_t,
    const float* __restrict__ conv_b,
    unsigned short* __restrict__ xc_bf)
{
    int idx = blockIdx.x * 256 + threadIdx.x;   // over B*L*DI/8
    int i8  = idx * 8;
    int d0  = i8 & (DI - 1);
    int bl  = i8 >> 11;
    int l   = bl % Ll;

    float acc[8];
    {
        float4 b0 = *(const float4*)&conv_b[d0];
        float4 b1 = *(const float4*)&conv_b[d0 + 4];
        acc[0] = b0.x; acc[1] = b0.y; acc[2] = b0.z; acc[3] = b0.w;
        acc[4] = b1.x; acc[5] = b1.y; acc[6] = b1.z; acc[7] = b1.w;
    }
    #pragma unroll
    for (int k = 0; k < Kc; k++) {
        int ls = l + k - (Kc - 1);
        if (ls >= 0) {
            short8 v = *(const short8*)&xz[(size_t)(bl + k - (Kc - 1)) * (2 * DI) + d0];
            float4 w0 = *(const float4*)&cw_t[k * DI + d0];
            float4 w1 = *(const float4*)&cw_t[k * DI + d0 + 4];
            float w[8] = {w0.x, w0.y, w0.z, w0.w, w1.x, w1.y, w1.z, w1.w};
            #pragma unroll
            for (int e = 0; e < 8; e++)
                acc[e] = fmaf(w[e], bf2f((unsigned short)v[e]), acc[e]);
        }
    }

    short8 ob;
    #pragma unroll
    for (int e = 0; e < 8; e++)
        ob[e] = (short)f2bf(fast_silu(acc[e]));
    *(short8*)&xc_bf[i8] = ob;
}

// ---------------------------------------------------------------------------
// Chunked selective scan, 2-pass. R19: reads xc and delta as bf16
// (halves scan-side HBM traffic; bf16 rounding within accuracy margin).
// ---------------------------------------------------------------------------
__global__ __launch_bounds__(256) void scan_part1(
    const unsigned short* __restrict__ delta_bf,
    const unsigned short* __restrict__ xc_bf,
    const float* __restrict__ proj,  const float* __restrict__ A_log,
    float* __restrict__ Pbuf, float* __restrict__ Sbuf)
{
    const int t    = threadIdx.x;
    const int nq   = t & 3;
    const int dloc = t >> 2;
    const int d    = blockIdx.x * 64 + dloc;
    const int b    = blockIdx.y;
    const int c    = blockIdx.z;

    float4 Alq = *(const float4*)&A_log[(size_t)d * Nst + nq * 4];
    float Ar0 = -expf(Alq.x), Ar1 = -expf(Alq.y), Ar2 = -expf(Alq.z), Ar3 = -expf(Alq.w);

    float h0 = 0.f, h1 = 0.f, h2 = 0.f, h3 = 0.f;
    float sdl = 0.f;

    for (int l = c * CL; l < (c + 1) * CL; l++) {
        size_t bl = (size_t)b * Ll + l;
        float dl  = bf2f(delta_bf[bl * DI + d]);
        float xcv = bf2f(xc_bf[bl * DI + d]);
        float dx  = dl * xcv;
        float4 Bv = *(const float4*)&proj[bl * (DTR + 2 * Nst) + DTR + nq * 4];

        h0 = fmaf(__expf(dl * Ar0), h0, dx * Bv.x);
        h1 = fmaf(__expf(dl * Ar1), h1, dx * Bv.y);
        h2 = fmaf(__expf(dl * Ar2), h2, dx * Bv.z);
        h3 = fmaf(__expf(dl * Ar3), h3, dx * Bv.w);
        sdl += dl;
    }

    size_t o = (((size_t)c * Bb + b) * DI + d) * Nst + nq * 4;
    *(float4*)&Pbuf[o] = (float4){__expf(sdl * Ar0), __expf(sdl * Ar1),
                                  __expf(sdl * Ar2), __expf(sdl * Ar3)};
    *(float4*)&Sbuf[o] = (float4){h0, h1, h2, h3};
}

__global__ __launch_bounds__(256) void scan_part2(
    const unsigned short* __restrict__ delta_bf,
    const unsigned short* __restrict__ xc_bf,
    const unsigned short* __restrict__ xz, const float* __restrict__ proj,
    const float* __restrict__ A_log, const float* __restrict__ Dv,
    const float* __restrict__ Pbuf, const float* __restrict__ Sbuf,
    unsigned short* __restrict__ y)
{
    const int t    = threadIdx.x;
    const int nq   = t & 3;
    const int dloc = t >> 2;
    const int d    = blockIdx.x * 64 + dloc;
    const int b    = blockIdx.y;
    const int c    = blockIdx.z;

    float4 Alq = *(const float4*)&A_log[(size_t)d * Nst + nq * 4];
    float Ar0 = -expf(Alq.x), Ar1 = -expf(Alq.y), Ar2 = -expf(Alq.z), Ar3 = -expf(Alq.w);
    const float Dd = Dv[d];

    float h0 = 0.f, h1 = 0.f, h2 = 0.f, h3 = 0.f;
    for (int cc = 0; cc < c; cc++) {
        size_t o = (((size_t)cc * Bb + b) * DI + d) * Nst + nq * 4;
        float4 Pv = *(const float4*)&Pbuf[o];
        float4 Sv = *(const float4*)&Sbuf[o];
        h0 = fmaf(Pv.x, h0, Sv.x);
        h1 = fmaf(Pv.y, h1, Sv.y);
        h2 = fmaf(Pv.z, h2, Sv.z);
        h3 = fmaf(Pv.w, h3, Sv.w);
    }

    for (int l = c * CL; l < (c + 1) * CL; l++) {
        size_t bl = (size_t)b * Ll + l;
        float dl  = bf2f(delta_bf[bl * DI + d]);
        float xcv = bf2f(xc_bf[bl * DI + d]);
        float zv  = bf2f(xz[bl * (2 * DI) + DI + d]);
        float dx  = dl * xcv;
        const float* p = proj + bl * (DTR + 2 * Nst);
        float4 Bv = *(const float4*)&p[DTR + nq * 4];
        float4 Cv = *(const float4*)&p[DTR + Nst + nq * 4];

        h0 = fmaf(__expf(dl * Ar0), h0, dx * Bv.x);
        h1 = fmaf(__expf(dl * Ar1), h1, dx * Bv.y);
        h2 = fmaf(__expf(dl * Ar2), h2, dx * Bv.z);
        h3 = fmaf(__expf(dl * Ar3), h3, dx * Bv.w);

        float yac = h0 * Cv.x + h1 * Cv.y + h2 * Cv.z + h3 * Cv.w;
        yac += __shfl_xor(yac, 1);
        yac += __shfl_xor(yac, 2);

        if (nq == 0) {
            float yv = yac + Dd * xcv;
            yv *= fast_silu(zv);
            y[bl * DI + d] = f2bf(yv);
        }
    }
}

// ---------------------------------------------------------------------------
// logits[M,16] = out_bf[M,1024] @ W_out[1024,16] + b_out (R17 vectorized)
// ---------------------------------------------------------------------------
__global__ __launch_bounds__(256) void gemm_n16(
    const unsigned short* __restrict__ A, const float* __restrict__ W,
    const float* __restrict__ bias, float* __restrict__ C, int Kd)
{
    int m    = blockIdx.x;
    int t    = threadIdx.x;
    int c    = t & 15;
    int kgrp = t >> 4;               // 0..15
    const unsigned short* a = A + (size_t)m * Kd;

    float acc = 0.f;
    #pragma unroll
    for (int j = 0; j < 8; j++) {    // Kd = 1024 = 16 kgrps * 8 j * 8 elems
        int k0 = kgrp * 8 + j * 128;
        short8 v = *(const short8*)&a[k0];
        #pragma unroll
        for (int e = 0; e < 8; e++)
            acc = fmaf(bf2f((unsigned short)v[e]), W[(k0 + e) * NC + c], acc);
    }

    __shared__ float red[256];
    red[t] = acc;
    __syncthreads();
    #pragma unroll
    for (int s = 128; s >= 16; s >>= 1) {
        if (t < s) red[t] += red[t + s];
        __syncthreads();
    }
    if (t < 16) C[(size_t)m * NC + t] = red[t] + bias[t];
}

// ---------------------------------------------------------------------------
extern "C" void kernel_launch(void* const* d_in, const int* in_sizes, int n_in,
                              void* d_out, int out_size, void* d_ws, size_t ws_size,
                              hipStream_t stream) {
    const float* x         = (const float*)d_in[0];
    const float* W_in      = (const float*)d_in[1];
    const float* b_in      = (const float*)d_in[2];
    const float* in_proj_w = (const float*)d_in[3];
    const float* conv_w    = (const float*)d_in[4];
    const float* conv_b    = (const float*)d_in[5];
    const float* x_proj_w  = (const float*)d_in[6];
    const float* dt_proj_w = (const float*)d_in[7];
    const float* dt_proj_b = (const float*)d_in[8];
    const float* A_log     = (const float*)d_in[9];
    const float* Dv        = (const float*)d_in[10];
    const float* out_proj  = (const float*)d_in[11];
    const float* W_out     = (const float*)d_in[12];
    const float* b_out     = (const float*)d_in[13];
    float* logits = (float*)d_out;

    char* base = (char*)d_ws;
    size_t off = 0;
    auto alloc = [&](size_t bytes) {
        char* p = base + off;
        off += (bytes + 255) & ~(size_t)255;
        return p;
    };
    unsigned short* x_bf    = (unsigned short*)alloc((size_t)M * DIN * 2);
    unsigned short* Wt_in   = (unsigned short*)alloc((size_t)Hh * DIN * 2);
    unsigned short* Wt_ip   = (unsigned short*)alloc((size_t)(2 * DI) * Hh * 2);
    unsigned short* Wt_op   = (unsigned short*)alloc((size_t)Hh * DI * 2);
    unsigned short* xpw_t   = (unsigned short*)alloc((size_t)96 * DI * 2);
    unsigned short* dtw_t   = (unsigned short*)alloc((size_t)DI * DTR * 2);
    float*          cw_t    = (float*)alloc((size_t)Kc * DI * 4);
    unsigned short* h_bf    = (unsigned short*)alloc((size_t)M * Hh * 2);
    unsigned short* xz_bf   = (unsigned short*)alloc((size_t)M * 2 * DI * 2);
    float*          xc      = (float*)alloc((size_t)M * DI * 4);       // P14 alias (scratch)
    float*          delta   = (float*)alloc((size_t)M * DI * 4);       // P8 + delta_bf region
    unsigned short* xc_bf   = (unsigned short*)alloc((size_t)M * DI * 2);
    float*          proj_f  = (float*)alloc((size_t)M * 96 * 4);
    unsigned short* proj_bf = (unsigned short*)alloc((size_t)M * 96 * 2);
    unsigned short* y_bf    = (unsigned short*)alloc((size_t)M * DI * 2);
    unsigned short* out_bf  = (unsigned short*)alloc((size_t)M * Hh * 2);

    unsigned short* P14 = (unsigned short*)xc;   // bf16 [4][1600][1024] = 13.1MB
    float*          P8  = delta;                 // fp32 [8][1600][96]  = 4.9MB
    // delta_bf (6.55MB) lives after P8's extent inside the delta region:
    // region is 13.1MB, P8 uses first 4.92MB; no temporal overlap (P8 consumed
    // by reduce before the delta GEMM writes delta_bf).
    unsigned short* delta_bf = (unsigned short*)(delta + (size_t)8 * M * 96);
    float*          Pbuf = (float*)x_bf;         // scan chunk buffers (x_bf dead)
    float*          Sbuf = Pbuf + (size_t)(NCH - 1) * Bb * DI * Nst;

    dim3 blk(256), blk5(512);

    // 0) fused prologue: convert + 5 transposes + conv_w transpose
    prep_kernel<<<dim3(22240), blk, 0, stream>>>(
        x, x_bf, W_in, Wt_in, in_proj_w, Wt_ip, out_proj, Wt_op,
        x_proj_w, xpw_t, dt_proj_w, dtw_t, conv_w, cw_t);

    // 1) h = x @ W_in + b_in   [1600,6144]@[6144,1024], split-K 4 -> 224 blocks
    gemm_deep<true, false, false><<<dim3(7, Hh / 128, 4), blk5, 0, stream>>>(
        x_bf, DIN, Wt_in, DIN, nullptr, nullptr, P14, M, Hh, DIN / 4);
    reduce_split_bf<4, true><<<dim3((M * Hh) / 2048), blk, 0, stream>>>(
        P14, b_in, h_bf, M * Hh, Hh - 1);

    // 2) xz = h @ in_proj_w    [1600,1024]@[1024,4096], 224 blocks, no split
    gemm_deep<false, false, true><<<dim3(7, (2 * DI) / 128, 1), blk5, 0, stream>>>(
        h_bf, Hh, Wt_ip, Hh, nullptr, xz_bf, nullptr, M, 2 * DI, Hh);

    // 3) xc = silu(conv(xm) + conv_b)  -> bf16 only (vectorized)
    conv_silu_kernel<<<dim3((Bb * Ll * DI) / 2048), blk, 0, stream>>>(
        xz_bf, cw_t, conv_b, xc_bf);

    // 4) proj = xc @ x_proj_w  [1600,2048]@[2048,96], split-K 8 -> 104 blocks
    gemm_mfma<true, false, false, 0, false, false><<<dim3(13, 1, 8), blk, 0, stream>>>(
        xc_bf, DI, xpw_t, DI, nullptr, nullptr, nullptr, P8, M, 96, DI / 8);
    reduce_split<8, false, 0, true, true><<<dim3((M * 96) / 1024), blk, 0, stream>>>(
        P8, nullptr, proj_f, proj_bf, M * 96, 0);

    // 5) delta = softplus(proj[:,:64] @ dt_proj_w + dt_proj_b) -> bf16
    gemm_mfma<false, false, true, 1, false, true><<<dim3(13, DI / 128, 1), blk, 0, stream>>>(
        proj_bf, 96, dtw_t, DTR, dt_proj_b, nullptr, delta_bf, nullptr, M, DI, DTR);

    // 6) chunked selective scan (bf16 delta/xc): pass1 (chunks 0..2), pass2 (all 4)
    scan_part1<<<dim3(DI / 64, Bb, NCH - 1), blk, 0, stream>>>(
        delta_bf, xc_bf, proj_f, A_log, Pbuf, Sbuf);
    scan_part2<<<dim3(DI / 64, Bb, NCH), blk, 0, stream>>>(
        delta_bf, xc_bf, xz_bf, proj_f, A_log, Dv, Pbuf, Sbuf, y_bf);

    // 7) out = y @ out_proj_w  [1600,2048]@[2048,1024], split-K 4 -> 224 blocks
    gemm_deep<true, false, false><<<dim3(7, Hh / 128, 4), blk5, 0, stream>>>(
        y_bf, DI, Wt_op, DI, nullptr, nullptr, P14, M, Hh, DI / 4);
    reduce_split_bf<4, false><<<dim3((M * Hh) / 2048), blk, 0, stream>>>(
        P14, nullptr, out_bf, M * Hh, 0);

    // 8) logits = out @ W_out + b_out  [1600,1024]@[1024,16]
    gemm_n16<<<dim3(M), blk, 0, stream>>>(out_bf, W_out, b_out, logits, Hh);
}